// Round 9
// baseline (909.262 us; speedup 1.0000x reference)
//
#include <hip/hip_runtime.h>
#include <cstdint>
#include <cstddef>

// ---------------------------------------------------------------------------
// GatedDeltaNet forward, MI355X/gfx950.
//  1. cast hs -> bf16 ; transpose weights -> bf16 [N][K]
//  2. GEMM1 (256x256/BK64, proven single-phase counted-vmcnt pipeline, T1/T2/T4/T5)
//  3. causal conv(K=4)+SiLU -> QKV bf16 ; beta/g
//  4. INTRA (chunk-parallel): A build + solve -> w,u ; attn
//  5. SEQ: state recurrence, MFMA, T14 cross-chunk prefetch + wave-local g-scan
//  6. gate + RMS-norm ; GEMM2 (128x256, 256 WGs = 1/CU): out = NRM @ W_out
// ---------------------------------------------------------------------------

#define ROWS  4096
#define SEQ   2048
#define HIDN  2048
#define CONVD 8192
#define NWP   12544     // 8192 qkv + 4096 z + 32 b + 32 a + 192 pad (49*256)
#define NUMV  32

using bf16x8 = __attribute__((ext_vector_type(8))) short;
using f32x4v = __attribute__((ext_vector_type(4))) float;

__device__ __forceinline__ float bf2f(unsigned short u) {
  union { unsigned int i; float f; } x; x.i = ((unsigned int)u) << 16; return x.f;
}
__device__ __forceinline__ unsigned short f2bf(float f) {
  union { float f; unsigned int u; } x; x.f = f;
  unsigned int u = x.u;
  unsigned int r = (u + 0x7FFFu + ((u >> 16) & 1u)) >> 16;  // RNE
  return (unsigned short)r;
}

typedef const __attribute__((address_space(1))) unsigned int GU32;
typedef __attribute__((address_space(3))) unsigned int LU32;
__device__ __forceinline__ void gld_lds16(const void* g, void* l) {
  GU32* gp = (GU32*)(unsigned long long)(uintptr_t)g;
  LU32* lp = (LU32*)(unsigned int)(uintptr_t)l;  // flat-LDS low32 = LDS offset
  __builtin_amdgcn_global_load_lds(gp, lp, 16, 0, 0);
}
// counted VMEM wait — asm with "memory" clobber (compiler-level fence)
template <int N>
__device__ __forceinline__ void waitcnt_vm() {
  asm volatile("s_waitcnt vmcnt(%0)" ::"i"(N) : "memory");
}

// ---------------------------------------------------------------- cast fp32->bf16
__global__ __launch_bounds__(256) void cast_kernel(const float* __restrict__ in,
                                                   unsigned short* __restrict__ out, int n4) {
  int i = blockIdx.x * 256 + threadIdx.x;
  if (i >= n4) return;
  float4 v = ((const float4*)in)[i];
  ushort4 o;
  o.x = f2bf(v.x); o.y = f2bf(v.y); o.z = f2bf(v.z); o.w = f2bf(v.w);
  ((ushort4*)out)[i] = o;
}

// ------------------------------------------------- transpose W[K][N] -> WT[roff+N][K] bf16
__global__ __launch_bounds__(256) void transpose_kernel(const float* __restrict__ W,
                                                        unsigned short* __restrict__ WT,
                                                        int K, int N, int ld, int roff) {
  __shared__ float tile[64][65];
  const int t = threadIdx.x;
  const int kb = blockIdx.y * 64, nb = blockIdx.x * 64;
  const int r = t >> 2, c0 = (t & 3) * 16;
#pragma unroll
  for (int i = 0; i < 16; ++i) {
    int c = c0 + i;
    float v = 0.f;
    if (nb + c < N) v = W[(size_t)(kb + r) * N + nb + c];
    tile[r][c] = v;
  }
  __syncthreads();
  const int bn = t >> 2;
  if (nb + bn < N) {
#pragma unroll
    for (int i = 0; i < 16; ++i)
      WT[(size_t)(roff + nb + bn) * ld + kb + c0 + i] = f2bf(tile[c0 + i][bn]);
  }
}

// ---------------------------------------------------------------- tiled bf16 GEMM (B^T input)
// R5-proven single-phase schedule (full-tile residency invariant). See R8 notes.
template <int BM, int BN, int OUT_BF16>
__global__ __launch_bounds__(512) void gemm_s_kernel(const unsigned short* __restrict__ Ag,
                                                     const unsigned short* __restrict__ Bg,
                                                     void* __restrict__ Cg, int M, int N, int K) {
  constexpr int PM = BM / 2, PN = BN / 4;
  constexpr int MT = PM / 16, NTF = PN / 16;
  constexpr int LA = BM / 64, LB = BN / 64;
  constexpr int SL = LA + LB;
  constexpr int BUF = (BM + BN) * 128;
  extern __shared__ char lds[];
  const int t = threadIdx.x;
  const int lane = t & 63, wid = t >> 6;
  const int wm = wid >> 2, wn = wid & 3;
  const int rlo = lane & 15, khi = lane >> 4;

  const int gx = gridDim.x, nwg = gx * gridDim.y;
  int id = blockIdx.y * gx + blockIdx.x;
  int sid = (id & 7) * (nwg >> 3) + (id >> 3);
  const int m0 = (sid / gx) * BM, n0 = (sid % gx) * BN;

  const int NT = K >> 6;

  const int srow = t >> 3;
  const int scb = ((t & 7) * 16) ^ ((srow & 7) << 4);
  const char* Abase = (const char*)Ag + ((size_t)(m0 + srow) * K) * 2 + scb;
  const char* Bbase = (const char*)Bg + ((size_t)(n0 + srow) * K) * 2 + scb;
  const size_t rstride = (size_t)64 * K * 2;

  int offA[MT][2], offB[NTF][2];
#pragma unroll
  for (int mi = 0; mi < MT; ++mi)
#pragma unroll
    for (int ks = 0; ks < 2; ++ks) {
      int o = (wm * PM + mi * 16 + rlo) * 128 + ks * 64 + khi * 16;
      o ^= ((o >> 7) & 7) << 4;
      offA[mi][ks] = o;
    }
#pragma unroll
  for (int ni = 0; ni < NTF; ++ni)
#pragma unroll
    for (int ks = 0; ks < 2; ++ks) {
      int o = (wn * PN + ni * 16 + rlo) * 128 + ks * 64 + khi * 16;
      o ^= ((o >> 7) & 7) << 4;
      offB[ni][ks] = o + BM * 128;
    }

  f32x4v acc[MT][NTF];
#pragma unroll
  for (int mi = 0; mi < MT; ++mi)
#pragma unroll
    for (int ni = 0; ni < NTF; ++ni) acc[mi][ni] = (f32x4v){0.f, 0.f, 0.f, 0.f};

#define STAGE(KT, P)                                                        \
  do {                                                                      \
    const char* a_ = Abase + (size_t)(KT) * 128;                            \
    const char* b_ = Bbase + (size_t)(KT) * 128;                            \
    char* da_ = lds + (P) * BUF + t * 16;                                   \
    char* db_ = lds + (P) * BUF + BM * 128 + t * 16;                        \
    _Pragma("unroll") for (int i_ = 0; i_ < LA; ++i_)                       \
        gld_lds16(a_ + i_ * rstride, da_ + i_ * 8192);                      \
    _Pragma("unroll") for (int i_ = 0; i_ < LB; ++i_)                       \
        gld_lds16(b_ + i_ * rstride, db_ + i_ * 8192);                      \
  } while (0)

  STAGE(0, 0);
  STAGE(1, 1);
  waitcnt_vm<SL>();
  __builtin_amdgcn_s_barrier();
  __builtin_amdgcn_sched_barrier(0);

#pragma unroll 1
  for (int kt = 0; kt < NT; ++kt) {
    const char* base = lds + (kt & 1) * BUF;
#pragma unroll
    for (int ks = 0; ks < 2; ++ks) {
      bf16x8 af[MT], bv[NTF];
#pragma unroll
      for (int mi = 0; mi < MT; ++mi) af[mi] = *(const bf16x8*)(base + offA[mi][ks]);
#pragma unroll
      for (int ni = 0; ni < NTF; ++ni) bv[ni] = *(const bf16x8*)(base + offB[ni][ks]);
      __builtin_amdgcn_s_setprio(1);
#pragma unroll
      for (int mi = 0; mi < MT; ++mi)
#pragma unroll
        for (int ni = 0; ni < NTF; ++ni)
          acc[mi][ni] = __builtin_amdgcn_mfma_f32_16x16x32_bf16(af[mi], bv[ni], acc[mi][ni], 0, 0, 0);
      __builtin_amdgcn_s_setprio(0);
    }
    if (kt + 1 < NT) {
      __builtin_amdgcn_s_barrier();
      if (kt + 2 < NT) {
        STAGE(kt + 2, kt & 1);
        waitcnt_vm<SL>();
      } else {
        waitcnt_vm<0>();
      }
      __builtin_amdgcn_s_barrier();
      __builtin_amdgcn_sched_barrier(0);
    }
  }
#undef STAGE
  waitcnt_vm<0>();

  const int mrb = khi * 4;
#pragma unroll
  for (int mi = 0; mi < MT; ++mi)
#pragma unroll
    for (int ni = 0; ni < NTF; ++ni)
#pragma unroll
      for (int r = 0; r < 4; ++r) {
        int mm = m0 + wm * PM + mi * 16 + mrb + r;
        int nn = n0 + wn * PN + ni * 16 + rlo;
        float v = acc[mi][ni][r];
        if (OUT_BF16) ((unsigned short*)Cg)[(size_t)mm * N + nn] = f2bf(v);
        else          ((float*)Cg)[(size_t)mm * N + nn] = v;
      }
}

// ---------------------------------------------------------------- causal conv K=4 + SiLU
__global__ __launch_bounds__(256) void conv_silu_kernel(const unsigned short* __restrict__ C1,
                                                        const float* __restrict__ conv_w,
                                                        unsigned short* __restrict__ QKV) {
  int idx = blockIdx.x * 256 + threadIdx.x;
  int row = idx >> 11;
  int c4 = (idx & 2047) << 2;
  int s = row & 2047;
  float4 w0 = *(const float4*)(conv_w + (size_t)(c4 + 0) * 4);
  float4 w1 = *(const float4*)(conv_w + (size_t)(c4 + 1) * 4);
  float4 w2 = *(const float4*)(conv_w + (size_t)(c4 + 2) * 4);
  float4 w3 = *(const float4*)(conv_w + (size_t)(c4 + 3) * 4);
  const float* pw0 = (const float*)&w0;
  const float* pw1 = (const float*)&w1;
  const float* pw2 = (const float*)&w2;
  const float* pw3 = (const float*)&w3;
  float a0 = 0.f, a1 = 0.f, a2 = 0.f, a3 = 0.f;
#pragma unroll
  for (int j = 0; j < 4; ++j) {
    int sr = s - 3 + j;
    if (sr < 0) continue;
    ushort4 mv = *(const ushort4*)(C1 + (size_t)(row - 3 + j) * NWP + c4);
    a0 += bf2f(mv.x) * pw0[j];
    a1 += bf2f(mv.y) * pw1[j];
    a2 += bf2f(mv.z) * pw2[j];
    a3 += bf2f(mv.w) * pw3[j];
  }
  ushort4 o;
  o.x = f2bf(a0 / (1.f + __expf(-a0)));
  o.y = f2bf(a1 / (1.f + __expf(-a1)));
  o.z = f2bf(a2 / (1.f + __expf(-a2)));
  o.w = f2bf(a3 / (1.f + __expf(-a3)));
  *(ushort4*)(QKV + (size_t)row * CONVD + c4) = o;
}

// ---------------------------------------------------------------- beta / g
__global__ __launch_bounds__(256) void gbeta_kernel(const unsigned short* __restrict__ C1,
                                                    const float* __restrict__ dt_bias,
                                                    const float* __restrict__ A_log,
                                                    float* __restrict__ G, float* __restrict__ BETA) {
  int idx = blockIdx.x * 256 + threadIdx.x;
  int row = idx >> 5, h = idx & 31;
  float bp = bf2f(C1[(size_t)row * NWP + 12288 + h]);
  float ap = bf2f(C1[(size_t)row * NWP + 12320 + h]);
  BETA[idx] = 1.f / (1.f + __expf(-bp));
  float x = ap + dt_bias[h];
  float sp = (x > 15.f) ? x : log1pf(__expf(x));
  G[idx] = -__expf(A_log[h]) * sp;
}

// ---------------------------------------------------------------- INTRA: per-chunk solve
#define INTRA_SMEM 70144
__global__ __launch_bounds__(256) void intra_kernel(const unsigned short* __restrict__ QKV,
                                                    const float* __restrict__ G,
                                                    const float* __restrict__ BETA,
                                                    unsigned short* __restrict__ WU,
                                                    unsigned short* __restrict__ ATTN) {
  extern __shared__ char smem[];
  unsigned short* ktb = (unsigned short*)smem;        // [64][136]
  float* Amat = (float*)(smem + 17408);               // [64][68]
  float* Xt   = (float*)(smem + 34816);               // [128][68]
  unsigned short* qb = (unsigned short*)Xt;           // [64][136] alias
  float* gc  = (float*)(smem + 69632);                // [64]
  float* bet = gc + 64;                               // [64]

  const int t = threadIdx.x;
  const int lane = t & 63, w = t >> 6;
  const int rlo = lane & 15, khi = lane >> 4;
  const int cix = blockIdx.x & 31;
  const int h = (blockIdx.x >> 5) & 31;
  const int b = blockIdx.x >> 10;
  const int hq = h >> 1;
  const int row0 = cix * 64;
  const size_t rowbase = (size_t)b * SEQ;

  if (t < 64) {
    float gv = G[(rowbase + row0 + t) * NUMV + h];
    bet[t] = BETA[(rowbase + row0 + t) * NUMV + h];
#pragma unroll
    for (int off = 1; off < 64; off <<= 1) {
      float u = __shfl_up(gv, off, 64);
      if (t >= off) gv += u;
    }
    gc[t] = gv;
  }
  __syncthreads();

  const int r = t >> 2, q4 = t & 3;
  const size_t grow = (rowbase + row0 + r) * (size_t)CONVD;

  {
    const unsigned short* kp = QKV + grow + 2048 + hq * 128 + q4 * 32;
    float kv[32]; float ssk = 0.f;
#pragma unroll
    for (int j = 0; j < 32; j += 4) {
      ushort4 km = *(const ushort4*)(kp + j);
      kv[j] = bf2f(km.x); kv[j + 1] = bf2f(km.y); kv[j + 2] = bf2f(km.z); kv[j + 3] = bf2f(km.w);
      ssk += kv[j]*kv[j] + kv[j+1]*kv[j+1] + kv[j+2]*kv[j+2] + kv[j+3]*kv[j+3];
    }
    ssk += __shfl_xor(ssk, 1, 64);
    ssk += __shfl_xor(ssk, 2, 64);
    const float rk = rsqrtf(ssk + 1e-6f);
    const float ekr = __expf(gc[r]) * bet[r];
#pragma unroll
    for (int j = 0; j < 32; ++j) {
      float kn = kv[j] * rk;
      ktb[r * 136 + q4 * 32 + j] = f2bf(kn);
      Xt[(q4 * 32 + j) * 68 + r] = kn * ekr;
    }
  }
  __syncthreads();

  {
    static const signed char SJ[10][2] = {{0,0},{1,0},{1,1},{2,0},{2,1},{2,2},{3,0},{3,1},{3,2},{3,3}};
    static const signed char SB[5] = {0, 4, 7, 9, 10};
    for (int sj = SB[w]; sj < SB[w + 1]; ++sj) {
      const int mt = SJ[sj][0], nt = SJ[sj][1];
      f32x4v acc = (f32x4v){0.f, 0.f, 0.f, 0.f};
#pragma unroll
      for (int ks = 0; ks < 4; ++ks) {
        bf16x8 af = *(const bf16x8*)&ktb[(mt * 16 + rlo) * 136 + ks * 32 + khi * 8];
        bf16x8 bf_ = *(const bf16x8*)&ktb[(nt * 16 + rlo) * 136 + ks * 32 + khi * 8];
        acc = __builtin_amdgcn_mfma_f32_16x16x32_bf16(af, bf_, acc, 0, 0, 0);
      }
      const int j = nt * 16 + rlo;
#pragma unroll
      for (int r2 = 0; r2 < 4; ++r2) {
        const int i = mt * 16 + khi * 4 + r2;
        if (j < i) Amat[i * 68 + j] = -bet[i] * __expf(gc[i] - gc[j]) * acc[r2];
      }
    }
  }
  __syncthreads();

#pragma unroll 1
  for (int ib = 0; ib < 8; ++ib) {
    const int i0 = ib * 8;
    if (t < 128) {
      float* Xc = Xt + t * 68;
      float p[8] = {0, 0, 0, 0, 0, 0, 0, 0};
      for (int j = 0; j < i0; j += 4) {
        f32x4v xj = *(const f32x4v*)&Xc[j];
#pragma unroll
        for (int r2 = 0; r2 < 8; ++r2) {
          f32x4v ar = *(const f32x4v*)&Amat[(i0 + r2) * 68 + j];
          p[r2] += ar[0] * xj[0] + ar[1] * xj[1] + ar[2] * xj[2] + ar[3] * xj[3];
        }
      }
      float xi[8];
#pragma unroll
      for (int r2 = 0; r2 < 8; ++r2) {
        float v = Xc[i0 + r2] + p[r2];
#pragma unroll
        for (int r3 = 0; r3 < r2; ++r3) v += Amat[(i0 + r2) * 68 + i0 + r3] * xi[r3];
        xi[r2] = v;
        Xc[i0 + r2] = v;
      }
    }
    __syncthreads();
  }

  {
    unsigned short* wdst = WU + (rowbase + row0 + r) * (size_t)NWP + h * 128 + q4 * 32;
#pragma unroll
    for (int j = 0; j < 32; ++j) wdst[j] = f2bf(Xt[(q4 * 32 + j) * 68 + r]);
    const unsigned short* vp = QKV + grow + 4096 + h * 128 + q4 * 32;
    const float brow = bet[r];
#pragma unroll
    for (int j = 0; j < 32; j += 4) {
      ushort4 vm = *(const ushort4*)(vp + j);
      Xt[(q4 * 32 + j + 0) * 68 + r] = bf2f(vm.x) * brow;
      Xt[(q4 * 32 + j + 1) * 68 + r] = bf2f(vm.y) * brow;
      Xt[(q4 * 32 + j + 2) * 68 + r] = bf2f(vm.z) * brow;
      Xt[(q4 * 32 + j + 3) * 68 + r] = bf2f(vm.w) * brow;
    }
  }
  __syncthreads();

#pragma unroll 1
  for (int ib = 0; ib < 8; ++ib) {
    const int i0 = ib * 8;
    if (t < 128) {
      float* Xc = Xt + t * 68;
      float p[8] = {0, 0, 0, 0, 0, 0, 0, 0};
      for (int j = 0; j < i0; j += 4) {
        f32x4v xj = *(const f32x4v*)&Xc[j];
#pragma unroll
        for (int r2 = 0; r2 < 8; ++r2) {
          f32x4v ar = *(const f32x4v*)&Amat[(i0 + r2) * 68 + j];
          p[r2] += ar[0] * xj[0] + ar[1] * xj[1] + ar[2] * xj[2] + ar[3] * xj[3];
        }
      }
      float xi[8];
#pragma unroll
      for (int r2 = 0; r2 < 8; ++r2) {
        float v = Xc[i0 + r2] + p[r2];
#pragma unroll
        for (int r3 = 0; r3 < r2; ++r3) v += Amat[(i0 + r2) * 68 + i0 + r3] * xi[r3];
        xi[r2] = v;
        Xc[i0 + r2] = v;
      }
    }
    __syncthreads();
  }

  {
    unsigned short* udst = WU + (rowbase + row0 + r) * (size_t)NWP + 4096 + h * 128 + q4 * 32;
#pragma unroll
    for (int j = 0; j < 32; ++j) udst[j] = f2bf(Xt[(q4 * 32 + j) * 68 + r]);
  }
  __syncthreads();

  {
    const unsigned short* qp = QKV + grow + hq * 128 + q4 * 32;
    float qv[32]; float ssq = 0.f;
#pragma unroll
    for (int j = 0; j < 32; j += 4) {
      ushort4 qm = *(const ushort4*)(qp + j);
      qv[j] = bf2f(qm.x); qv[j + 1] = bf2f(qm.y); qv[j + 2] = bf2f(qm.z); qv[j + 3] = bf2f(qm.w);
      ssq += qv[j]*qv[j] + qv[j+1]*qv[j+1] + qv[j+2]*qv[j+2] + qv[j+3]*qv[j+3];
    }
    ssq += __shfl_xor(ssq, 1, 64);
    ssq += __shfl_xor(ssq, 2, 64);
    const float rq = rsqrtf(ssq + 1e-6f) * 0.08838834764831845f;
#pragma unroll
    for (int j = 0; j < 32; ++j) qb[r * 136 + q4 * 32 + j] = f2bf(qv[j] * rq);
  }
  __syncthreads();

  {
    const size_t abase = (((size_t)b * 32 + h) * 32 + cix) * 4096;
#pragma unroll 1
    for (int nt = 0; nt < 4; ++nt) {
      const int j = nt * 16 + rlo;
      float vals[4] = {0.f, 0.f, 0.f, 0.f};
      if (nt <= w) {
        f32x4v acc = (f32x4v){0.f, 0.f, 0.f, 0.f};
#pragma unroll
        for (int ks = 0; ks < 4; ++ks) {
          bf16x8 af = *(const bf16x8*)&qb[(w * 16 + rlo) * 136 + ks * 32 + khi * 8];
          bf16x8 bf_ = *(const bf16x8*)&ktb[(nt * 16 + rlo) * 136 + ks * 32 + khi * 8];
          acc = __builtin_amdgcn_mfma_f32_16x16x32_bf16(af, bf_, acc, 0, 0, 0);
        }
#pragma unroll
        for (int r2 = 0; r2 < 4; ++r2) {
          const int i = w * 16 + khi * 4 + r2;
          if (j <= i) vals[r2] = __expf(gc[i] - gc[j]) * acc[r2];
        }
      }
#pragma unroll
      for (int r2 = 0; r2 < 4; ++r2)
        ATTN[abase + (w * 16 + khi * 4 + r2) * 64 + j] = f2bf(vals[r2]);
    }
  }
}

// ---------------------------------------------------------------- SEQ: state recurrence
// T14: all of chunk ncb+1's global loads issue at the top of iteration ncb into
// a second register set (static-indexed only, rule #20); consumed next iter.
// g-scan is wave-local (all 4 waves compute the identical 64-lane scan in regs;
// gc[i]/edec[i]/egl come from __shfl+exp at use) -> P0 phase + 1 barrier removed.
#define SEQ_SMEM 70400
struct SeqRegs {
  ushort4 k[8];
  uint4 w[4];
  uint4 a[2];
  ushort4 qa[4], qb[4];
  unsigned short u[4];
  float gv;
};

__device__ __forceinline__ void seq_load(SeqRegs& R, const unsigned short* __restrict__ QKV,
                                         const float* __restrict__ G,
                                         const unsigned short* __restrict__ WU,
                                         const unsigned short* __restrict__ ATTN,
                                         size_t rowbase, size_t ahead, int ncb, int h, int hq,
                                         int vq, int t, int w, int rlo, int khi) {
  const int row0 = ncb * 64;
  const int r = t >> 2, q4 = t & 3;
  const size_t grow = (rowbase + row0 + r) * (size_t)CONVD;
  const unsigned short* kp = QKV + grow + 2048 + hq * 128 + q4 * 32;
#pragma unroll
  for (int j = 0; j < 8; ++j) R.k[j] = *(const ushort4*)(kp + j * 4);
  const unsigned short* wsrc = WU + (rowbase + row0 + r) * (size_t)NWP + h * 128 + q4 * 32;
#pragma unroll
  for (int j = 0; j < 4; ++j) R.w[j] = *(const uint4*)(wsrc + j * 8);
  const unsigned short* asrc = ATTN + (ahead + ncb) * 4096 + r * 64 + q4 * 16;
  R.a[0] = *(const uint4*)(asrc);
  R.a[1] = *(const uint4*)(asrc + 8);
  const unsigned short* qsrc = QKV + (rowbase + row0 + w * 16 + rlo) * (size_t)CONVD + hq * 128 + khi * 8;
#pragma unroll
  for (int ks = 0; ks < 4; ++ks) {
    R.qa[ks] = *(const ushort4*)(qsrc + ks * 32);
    R.qb[ks] = *(const ushort4*)(qsrc + ks * 32 + 4);
  }
#pragma unroll
  for (int r2 = 0; r2 < 4; ++r2) {
    const int i = w * 16 + khi * 4 + r2;
    R.u[r2] = WU[(rowbase + row0 + i) * (size_t)NWP + 4096 + h * 128 + vq * 16 + rlo];
  }
  R.gv = G[(rowbase + row0 + (t & 63)) * NUMV + h];
}

__global__ __launch_bounds__(256) void seq_kernel(const unsigned short* __restrict__ QKV,
                                                  const float* __restrict__ G,
                                                  const unsigned short* __restrict__ WU,
                                                  const unsigned short* __restrict__ ATTN,
                                                  unsigned short* __restrict__ CORE) {
  extern __shared__ char smem[];
  unsigned short* ktT    = (unsigned short*)smem;            // [128][88]
  unsigned short* wb     = (unsigned short*)(smem + 22528);  // [64][136]
  unsigned short* attnb  = (unsigned short*)(smem + 39936);  // [64][88]
  float* stateT          = (float*)(smem + 51200);           // [16][136]
  unsigned short* stateTb = (unsigned short*)(smem + 59904); // [16][136]
  unsigned short* vnTb   = (unsigned short*)(smem + 64256);  // [16][88]
  unsigned short* vdTb   = (unsigned short*)(smem + 67072);  // [16][88]

  const int t = threadIdx.x;
  const int lane = t & 63, w = t >> 6;
  const int rlo = lane & 15, khi = lane >> 4;
  const int vq = blockIdx.x & 7;
  const int h = (blockIdx.x >> 3) & 31;
  const int b = blockIdx.x >> 8;
  const int hq = h >> 1;
  const size_t rowbase = (size_t)b * SEQ;
  const size_t ahead = ((size_t)b * 32 + h) * 32;

  for (int i = t; i < 16 * 136; i += 256) { stateT[i] = 0.f; stateTb[i] = 0; }

  SeqRegs cur, nxt;
  seq_load(cur, QKV, G, WU, ATTN, rowbase, ahead, 0, h, hq, vq, t, w, rlo, khi);
  __syncthreads();

  bf16x8 qf[4];

#pragma unroll 1
  for (int ncb = 0; ncb < 32; ++ncb) {
    const int ncb2 = (ncb + 1 < 32) ? ncb + 1 : 31;
    seq_load(nxt, QKV, G, WU, ATTN, rowbase, ahead, ncb2, h, hq, vq, t, w, rlo, khi);

    // wave-local g scan (identical across waves; lane = row)
    float gv = cur.gv;
#pragma unroll
    for (int off = 1; off < 64; off <<= 1) {
      float uph = __shfl_up(gv, off, 64);
      if (lane >= off) gv += uph;
    }
    const float gtot = __shfl(gv, 63, 64);

    // P1: k-norm -> ktT ; w/attn copies ; q-norm -> qf regs
    {
      const int r = t >> 2, q4 = t & 3;
      float kv[32]; float ssk = 0.f;
#pragma unroll
      for (int j = 0; j < 8; ++j) {
        ushort4 km = cur.k[j];
        kv[j*4]   = bf2f(km.x); kv[j*4+1] = bf2f(km.y);
        kv[j*4+2] = bf2f(km.z); kv[j*4+3] = bf2f(km.w);
        ssk += kv[j*4]*kv[j*4] + kv[j*4+1]*kv[j*4+1] + kv[j*4+2]*kv[j*4+2] + kv[j*4+3]*kv[j*4+3];
      }
      ssk += __shfl_xor(ssk, 1, 64);
      ssk += __shfl_xor(ssk, 2, 64);
      const float rk = rsqrtf(ssk + 1e-6f);
#pragma unroll
      for (int j = 0; j < 32; ++j) ktT[(q4 * 32 + j) * 88 + r] = f2bf(kv[j] * rk);
#pragma unroll
      for (int j = 0; j < 4; ++j) *(uint4*)&wb[r * 136 + q4 * 32 + j * 8] = cur.w[j];
      *(uint4*)&attnb[r * 88 + q4 * 16] = cur.a[0];
      *(uint4*)&attnb[r * 88 + q4 * 16 + 8] = cur.a[1];
      float qv[32]; float ssq = 0.f;
#pragma unroll
      for (int ks = 0; ks < 4; ++ks) {
        ushort4 qa = cur.qa[ks];
        ushort4 qb2 = cur.qb[ks];
        qv[ks*8+0] = bf2f(qa.x); qv[ks*8+1] = bf2f(qa.y); qv[ks*8+2] = bf2f(qa.z); qv[ks*8+3] = bf2f(qa.w);
        qv[ks*8+4] = bf2f(qb2.x); qv[ks*8+5] = bf2f(qb2.y); qv[ks*8+6] = bf2f(qb2.z); qv[ks*8+7] = bf2f(qb2.w);
#pragma unroll
        for (int e = 0; e < 8; ++e) ssq += qv[ks*8+e] * qv[ks*8+e];
      }
      ssq += __shfl_xor(ssq, 16, 64);
      ssq += __shfl_xor(ssq, 32, 64);
      const float rq = rsqrtf(ssq + 1e-6f) * 0.08838834764831845f;
#pragma unroll
      for (int ks = 0; ks < 4; ++ks) {
        bf16x8 tv;
#pragma unroll
        for (int e = 0; e < 8; ++e) tv[e] = (short)f2bf(qv[ks*8+e] * rq);
        qf[ks] = tv;
      }
    }
    __syncthreads();

    // P2: pacc = w@S^T, oacc = q@S^T ; v_new = u - pacc ; oacc *= e^gc
    f32x4v oacc;
    {
      f32x4v pacc = (f32x4v){0.f, 0.f, 0.f, 0.f};
      oacc = (f32x4v){0.f, 0.f, 0.f, 0.f};
#pragma unroll
      for (int ks = 0; ks < 4; ++ks) {
        bf16x8 aw = *(const bf16x8*)&wb[(w * 16 + rlo) * 136 + ks * 32 + khi * 8];
        bf16x8 bs = *(const bf16x8*)&stateTb[rlo * 136 + ks * 32 + khi * 8];
        pacc = __builtin_amdgcn_mfma_f32_16x16x32_bf16(aw, bs, pacc, 0, 0, 0);
        oacc = __builtin_amdgcn_mfma_f32_16x16x32_bf16(qf[ks], bs, oacc, 0, 0, 0);
      }
#pragma unroll
      for (int r2 = 0; r2 < 4; ++r2) {
        const int i = w * 16 + khi * 4 + r2;
        const float gci = __shfl(gv, i, 64);
        float uv = bf2f(cur.u[r2]);
        float vn = uv - pacc[r2];
        vnTb[rlo * 88 + i] = f2bf(vn);
        vdTb[rlo * 88 + i] = f2bf(vn * __expf(gtot - gci));
        oacc[r2] *= __expf(gci);
      }
    }
    __syncthreads();

    // P3: oacc += attn@vn^T ; store CORE ; state update
    {
#pragma unroll
      for (int ks = 0; ks < 2; ++ks) {
        bf16x8 aa = *(const bf16x8*)&attnb[(w * 16 + rlo) * 88 + ks * 32 + khi * 8];
        bf16x8 bv = *(const bf16x8*)&vnTb[rlo * 88 + ks * 32 + khi * 8];
        oacc = __builtin_amdgcn_mfma_f32_16x16x32_bf16(aa, bv, oacc, 0, 0, 0);
      }
      const int col = h * 128 + vq * 16 + rlo;
      const int row0 = ncb * 64;
#pragma unroll
      for (int r2 = 0; r2 < 4; ++r2) {
        const int i = w * 16 + khi * 4 + r2;
        CORE[(rowbase + row0 + i) * (size_t)4096 + col] = f2bf(oacc[r2]);
      }
      const float egl = __expf(gtot);
#pragma unroll
      for (int n2 = 0; n2 < 2; ++n2) {
        const int dt = w * 2 + n2;
        f32x4v sacc = (f32x4v){0.f, 0.f, 0.f, 0.f};
#pragma unroll
        for (int ks = 0; ks < 2; ++ks) {
          bf16x8 ak = *(const bf16x8*)&ktT[(dt * 16 + rlo) * 88 + ks * 32 + khi * 8];
          bf16x8 bv2 = *(const bf16x8*)&vdTb[rlo * 88 + ks * 32 + khi * 8];
          sacc = __builtin_amdgcn_mfma_f32_16x16x32_bf16(ak, bv2, sacc, 0, 0, 0);
        }
#pragma unroll
        for (int r2 = 0; r2 < 4; ++r2) {
          const int d = dt * 16 + khi * 4 + r2;
          float ns = stateT[rlo * 136 + d] * egl + sacc[r2];
          stateT[rlo * 136 + d] = ns;
          stateTb[rlo * 136 + d] = f2bf(ns);
        }
      }
    }
    __syncthreads();

    cur = nxt;
  }
}

// ---------------------------------------------------------------- gate * silu(z) + RMS-norm
__global__ __launch_bounds__(256) void gatenorm_kernel(const unsigned short* __restrict__ CORE,
                                                       const unsigned short* __restrict__ C1,
                                                       const float* __restrict__ norm_w,
                                                       unsigned short* __restrict__ NRM) {
  const int wid = blockIdx.x * 4 + (threadIdx.x >> 6);
  const int lane = threadIdx.x & 63;
  const int row = wid >> 5, h = wid & 31;
  const int c = lane * 2;
  const size_t cidx = (size_t)row * 4096 + h * 128 + c;
  const size_t zidx = (size_t)row * NWP + 8192 + h * 128 + c;
  float g0 = bf2f(CORE[cidx]), g1 = bf2f(CORE[cidx + 1]);
  float z0 = bf2f(C1[zidx]), z1 = bf2f(C1[zidx + 1]);
  g0 *= z0 / (1.f + __expf(-z0));
  g1 *= z1 / (1.f + __expf(-z1));
  float ss = g0 * g0 + g1 * g1;
#pragma unroll
  for (int m = 1; m < 64; m <<= 1) ss += __shfl_xor(ss, m, 64);
  const float rr = rsqrtf(ss * (1.f / 128.f) + 1e-6f);
  unsigned int o = ((unsigned int)f2bf(g1 * rr * norm_w[c + 1]) << 16) | (unsigned int)f2bf(g0 * rr * norm_w[c]);
  *(unsigned int*)(NRM + cidx) = o;
}

// ---------------------------------------------------------------------------
extern "C" void kernel_launch(void* const* d_in, const int* in_sizes, int n_in,
                              void* d_out, int out_size, void* d_ws, size_t ws_size,
                              hipStream_t stream) {
  const float* hs      = (const float*)d_in[0];
  const float* W_qkv   = (const float*)d_in[1];
  const float* W_z     = (const float*)d_in[2];
  const float* W_b     = (const float*)d_in[3];
  const float* W_a     = (const float*)d_in[4];
  const float* conv_w  = (const float*)d_in[5];
  const float* dt_bias = (const float*)d_in[6];
  const float* A_log   = (const float*)d_in[7];
  const float* norm_w  = (const float*)d_in[8];
  const float* W_out   = (const float*)d_in[9];
  float* out = (float*)d_out;
  char* ws = (char*)d_ws;

  const size_t OFF_HSB = 0;                                     // hs bf16; later ATTN
  const size_t OFF_WT  = OFF_HSB + (size_t)ROWS * HIDN * 2;     // WT; later CORE
  const size_t OFF_WOT = OFF_WT + (size_t)NWP * HIDN * 2;
  const size_t OFF_C1  = OFF_WOT + (size_t)HIDN * 4096 * 2;     // C1; cols [0,8192) -> w,u after conv
  const size_t OFF_QKV = OFF_C1 + (size_t)ROWS * NWP * 2;       // QKV; later NRM
  const size_t OFF_G   = OFF_QKV + (size_t)ROWS * CONVD * 2;
  const size_t OFF_B   = OFF_G + (size_t)ROWS * NUMV * 4;

  unsigned short* hsb = (unsigned short*)(ws + OFF_HSB);
  unsigned short* WT  = (unsigned short*)(ws + OFF_WT);
  unsigned short* WoT = (unsigned short*)(ws + OFF_WOT);
  unsigned short* C1  = (unsigned short*)(ws + OFF_C1);
  unsigned short* QKV = (unsigned short*)(ws + OFF_QKV);
  float* Gb = (float*)(ws + OFF_G);
  float* Bb = (float*)(ws + OFF_B);
  unsigned short* ATTNb = (unsigned short*)(ws + OFF_HSB);
  unsigned short* COREb = (unsigned short*)(ws + OFF_WT);
  unsigned short* NRMb  = (unsigned short*)(ws + OFF_QKV);

  cast_kernel<<<ROWS * HIDN / 4 / 256, 256, 0, stream>>>(hs, hsb, ROWS * HIDN / 4);
  transpose_kernel<<<dim3(8192 / 64, 2048 / 64), 256, 0, stream>>>(W_qkv, WT, 2048, 8192, HIDN, 0);
  transpose_kernel<<<dim3(4096 / 64, 2048 / 64), 256, 0, stream>>>(W_z, WT, 2048, 4096, HIDN, 8192);
  transpose_kernel<<<dim3(1, 2048 / 64), 256, 0, stream>>>(W_b, WT, 2048, 32, HIDN, 12288);
  transpose_kernel<<<dim3(1, 2048 / 64), 256, 0, stream>>>(W_a, WT, 2048, 32, HIDN, 12320);
  hipMemsetAsync(ws + OFF_WT + (size_t)12352 * HIDN * 2, 0, (size_t)192 * HIDN * 2, stream);
  transpose_kernel<<<dim3(2048 / 64, 4096 / 64), 256, 0, stream>>>(W_out, WoT, 4096, 2048, 4096, 0);

  void (*g1p)(const unsigned short*, const unsigned short*, void*, int, int, int) = gemm_s_kernel<256, 256, 1>;
  void (*g0p)(const unsigned short*, const unsigned short*, void*, int, int, int) = gemm_s_kernel<128, 256, 0>;
  hipFuncSetAttribute((const void*)g1p, hipFuncAttributeMaxDynamicSharedMemorySize, (256 + 256) * 128 * 2);
  hipFuncSetAttribute((const void*)g0p, hipFuncAttributeMaxDynamicSharedMemorySize, (128 + 256) * 128 * 2);

  gemm_s_kernel<256, 256, 1><<<dim3(NWP / 256, ROWS / 256), 512, (256 + 256) * 128 * 2, stream>>>(
      hsb, WT, C1, ROWS, NWP, HIDN);
  conv_silu_kernel<<<ROWS * (CONVD / 4) / 256, 256, 0, stream>>>(C1, conv_w, QKV);
  gbeta_kernel<<<ROWS * NUMV / 256, 256, 0, stream>>>(C1, dt_bias, A_log, Gb, Bb);

  hipFuncSetAttribute((const void*)intra_kernel, hipFuncAttributeMaxDynamicSharedMemorySize,
                      INTRA_SMEM);
  intra_kernel<<<2048, 256, INTRA_SMEM, stream>>>(QKV, Gb, Bb, C1, ATTNb);

  hipFuncSetAttribute((const void*)seq_kernel, hipFuncAttributeMaxDynamicSharedMemorySize,
                      SEQ_SMEM);
  seq_kernel<<<512, 256, SEQ_SMEM, stream>>>(QKV, Gb, C1, ATTNb, COREb);

  gatenorm_kernel<<<ROWS * NUMV / 4, 256, 0, stream>>>(COREb, C1, norm_w, NRMb);
  gemm_s_kernel<128, 256, 0><<<dim3(2048 / 256, ROWS / 128), 512, (128 + 256) * 128 * 2, stream>>>(
      NRMb, WoT, out, ROWS, 2048, 4096);
}

// Round 10
// 886.743 us; speedup vs baseline: 1.0254x; 1.0254x over previous
//
#include <hip/hip_runtime.h>
#include <cstdint>
#include <cstddef>

// ---------------------------------------------------------------------------
// GatedDeltaNet forward, MI355X/gfx950.
//  1. cast hs -> bf16 ; transpose weights -> bf16 [N][K]
//  2. GEMM1 (256x256/BK64, K-split sub-phase pipeline: wave-uniform residency)
//  3. causal conv(K=4)+SiLU -> QKV bf16 ; beta/g
//  4. INTRA (chunk-parallel): A build + solve -> w,u ; attn
//  5. SEQ: state recurrence, MFMA
//  6. gate + RMS-norm ; GEMM2 (128x256, 256 WGs = 1/CU, R8-proven schedule)
// ---------------------------------------------------------------------------

#define ROWS  4096
#define SEQ   2048
#define HIDN  2048
#define CONVD 8192
#define NWP   12544     // 8192 qkv + 4096 z + 32 b + 32 a + 192 pad (49*256)
#define NUMV  32

using bf16x8 = __attribute__((ext_vector_type(8))) short;
using f32x4v = __attribute__((ext_vector_type(4))) float;

__device__ __forceinline__ float bf2f(unsigned short u) {
  union { unsigned int i; float f; } x; x.i = ((unsigned int)u) << 16; return x.f;
}
__device__ __forceinline__ unsigned short f2bf(float f) {
  union { float f; unsigned int u; } x; x.f = f;
  unsigned int u = x.u;
  unsigned int r = (u + 0x7FFFu + ((u >> 16) & 1u)) >> 16;  // RNE
  return (unsigned short)r;
}

typedef const __attribute__((address_space(1))) unsigned int GU32;
typedef __attribute__((address_space(3))) unsigned int LU32;
__device__ __forceinline__ void gld_lds16(const void* g, void* l) {
  GU32* gp = (GU32*)(unsigned long long)(uintptr_t)g;
  LU32* lp = (LU32*)(unsigned int)(uintptr_t)l;  // flat-LDS low32 = LDS offset
  __builtin_amdgcn_global_load_lds(gp, lp, 16, 0, 0);
}
// counted VMEM wait — asm with "memory" clobber (compiler-level fence)
template <int N>
__device__ __forceinline__ void waitcnt_vm() {
  asm volatile("s_waitcnt vmcnt(%0)" ::"i"(N) : "memory");
}

// ---------------------------------------------------------------- cast fp32->bf16
__global__ __launch_bounds__(256) void cast_kernel(const float* __restrict__ in,
                                                   unsigned short* __restrict__ out, int n4) {
  int i = blockIdx.x * 256 + threadIdx.x;
  if (i >= n4) return;
  float4 v = ((const float4*)in)[i];
  ushort4 o;
  o.x = f2bf(v.x); o.y = f2bf(v.y); o.z = f2bf(v.z); o.w = f2bf(v.w);
  ((ushort4*)out)[i] = o;
}

// ------------------------------------------------- transpose W[K][N] -> WT[roff+N][K] bf16
__global__ __launch_bounds__(256) void transpose_kernel(const float* __restrict__ W,
                                                        unsigned short* __restrict__ WT,
                                                        int K, int N, int ld, int roff) {
  __shared__ float tile[64][65];
  const int t = threadIdx.x;
  const int kb = blockIdx.y * 64, nb = blockIdx.x * 64;
  const int r = t >> 2, c0 = (t & 3) * 16;
#pragma unroll
  for (int i = 0; i < 16; ++i) {
    int c = c0 + i;
    float v = 0.f;
    if (nb + c < N) v = W[(size_t)(kb + r) * N + nb + c];
    tile[r][c] = v;
  }
  __syncthreads();
  const int bn = t >> 2;
  if (nb + bn < N) {
#pragma unroll
    for (int i = 0; i < 16; ++i)
      WT[(size_t)(roff + nb + bn) * ld + kb + c0 + i] = f2bf(tile[c0 + i][bn]);
  }
}

// ---------------------------------------------------------------- GEMM1: K-split sub-phase
// 512 threads = 8 waves (2M x 4N). BM=BN=256, BK=64 split into 2 ks-halves.
// 4 LDS regions of 32KB (A[256][32] + B[256][32] bf16, 64B rows, swizzled).
// Phase p: {12 ds_reads region(p&3); stage region((p+3)&3) <- content(p+3) [4 gld_lds];
//           32 MFMA; vmcnt(8); barrier}. Wave-UNIFORM residency: every wave reads the
// same ks-half (all rows) -> per-phase ledger holds for all waves (fixes R6/R7 race).
// vmcnt(8) at end of phase q proves stage(q-2) = content(q+1) landed.
// Swizzle for 64B rows: o ^= ((o>>7)&3)<<4 (row>>1 into slot bits; 2 lanes/bank = free).
#define G1_LDS 131072
template <int OUT_BF16>
__global__ __launch_bounds__(512) void gemm_ks_kernel(const unsigned short* __restrict__ Ag,
                                                      const unsigned short* __restrict__ Bg,
                                                      void* __restrict__ Cg, int M, int N, int K) {
  constexpr int PM = 128, PN = 64;
  constexpr int MT = 8, NTF = 4;
  constexpr int REG = 32768;              // bytes per region
  extern __shared__ char lds[];
  const int t = threadIdx.x;
  const int lane = t & 63, wid = t >> 6;
  const int wm = wid >> 2, wn = wid & 3;
  const int rlo = lane & 15, khi = lane >> 4;

  // T1: bijective XCD swizzle (grid multiple of 8)
  const int gx = gridDim.x, nwg = gx * gridDim.y;
  int id = blockIdx.y * gx + blockIdx.x;
  int sid = (id & 7) * (nwg >> 3) + (id >> 3);
  const int m0 = (sid / gx) * 256, n0 = (sid % gx) * 256;

  const int NT = K >> 6;
  const int NPH = NT * 2;

  // staging: thread t covers row (i*128 + (t>>2)) of the 256-row panel, 16B slot (t&3),
  // source col pre-swizzled with the same involution the reads use.
  const int srow = t >> 2;
  const int scs = ((t & 3) * 16) ^ (((t >> 3) & 3) << 4);
  const char* As0 = (const char*)Ag + (size_t)(m0 + srow) * K * 2 + scs;
  const char* As1 = (const char*)Ag + (size_t)(m0 + 128 + srow) * K * 2 + scs;
  const char* Bs0 = (const char*)Bg + (size_t)(n0 + srow) * K * 2 + scs;
  const char* Bs1 = (const char*)Bg + (size_t)(n0 + 128 + srow) * K * 2 + scs;
  char* dst = lds + t * 16;

  // region-relative swizzled read offsets
  int offA[MT], offB[NTF];
#pragma unroll
  for (int mi = 0; mi < MT; ++mi) {
    int row = wm * PM + mi * 16 + rlo;
    int o = row * 64 + khi * 16;
    o ^= ((o >> 7) & 3) << 4;
    offA[mi] = o;
  }
#pragma unroll
  for (int ni = 0; ni < NTF; ++ni) {
    int row = wn * PN + ni * 16 + rlo;
    int o = row * 64 + khi * 16;
    o ^= ((o >> 7) & 3) << 4;
    offB[ni] = o + 16384;
  }

  f32x4v acc[MT][NTF];
#pragma unroll
  for (int mi = 0; mi < MT; ++mi)
#pragma unroll
    for (int ni = 0; ni < NTF; ++ni) acc[mi][ni] = (f32x4v){0.f, 0.f, 0.f, 0.f};

#define STG(PS)                                                              \
  do {                                                                       \
    int kts_ = ((PS) >> 1 < NT) ? ((PS) >> 1) : NT - 1;                      \
    size_t co_ = (size_t)kts_ * 128 + (size_t)((PS) & 1) * 64;               \
    char* d_ = dst + (((PS) & 3) * REG);                                     \
    gld_lds16(As0 + co_, d_);                                                \
    gld_lds16(As1 + co_, d_ + 8192);                                         \
    gld_lds16(Bs0 + co_, d_ + 16384);                                        \
    gld_lds16(Bs1 + co_, d_ + 24576);                                        \
  } while (0)

  // prologue: contents for phases 0,1,2 -> regions 0,1,2 (12 loads)
  STG(0); STG(1); STG(2);
  waitcnt_vm<8>();                    // content(0) landed; (1),(2) in flight
  __builtin_amdgcn_s_barrier();
  __builtin_amdgcn_sched_barrier(0);

#pragma unroll 1
  for (int p = 0; p < NPH; ++p) {
    const char* rb = lds + (p & 3) * REG;
    bf16x8 af[MT], bv[NTF];
#pragma unroll
    for (int mi = 0; mi < MT; ++mi) af[mi] = *(const bf16x8*)(rb + offA[mi]);
#pragma unroll
    for (int ni = 0; ni < NTF; ++ni) bv[ni] = *(const bf16x8*)(rb + offB[ni]);
    STG(p + 3);                       // region((p+3)&3): last read at p-1, freed
    __builtin_amdgcn_s_setprio(1);
#pragma unroll
    for (int mi = 0; mi < MT; ++mi)
#pragma unroll
      for (int ni = 0; ni < NTF; ++ni)
        acc[mi][ni] = __builtin_amdgcn_mfma_f32_16x16x32_bf16(af[mi], bv[ni], acc[mi][ni], 0, 0, 0);
    __builtin_amdgcn_s_setprio(0);
    waitcnt_vm<8>();                  // stage(p-2) = content(p+1) proven resident
    __builtin_amdgcn_s_barrier();
    __builtin_amdgcn_sched_barrier(0);
  }
#undef STG
  waitcnt_vm<0>();                    // drain clamped stages before exit

  // epilogue: C/D map col=lane&15 (N), row=4*(lane>>4)+reg (M)
  const int mrb = khi * 4;
#pragma unroll
  for (int mi = 0; mi < MT; ++mi)
#pragma unroll
    for (int ni = 0; ni < NTF; ++ni)
#pragma unroll
      for (int r = 0; r < 4; ++r) {
        int mm = m0 + wm * PM + mi * 16 + mrb + r;
        int nn = n0 + wn * PN + ni * 16 + rlo;
        float v = acc[mi][ni][r];
        if (OUT_BF16) ((unsigned short*)Cg)[(size_t)mm * N + nn] = f2bf(v);
        else          ((float*)Cg)[(size_t)mm * N + nn] = v;
      }
}

// ---------------------------------------------------------------- tiled bf16 GEMM (B^T input)
// R5/R8-proven single-phase schedule (full-tile residency invariant). Used for GEMM2.
template <int BM, int BN, int OUT_BF16>
__global__ __launch_bounds__(512) void gemm_s_kernel(const unsigned short* __restrict__ Ag,
                                                     const unsigned short* __restrict__ Bg,
                                                     void* __restrict__ Cg, int M, int N, int K) {
  constexpr int PM = BM / 2, PN = BN / 4;
  constexpr int MT = PM / 16, NTF = PN / 16;
  constexpr int LA = BM / 64, LB = BN / 64;
  constexpr int SL = LA + LB;
  constexpr int BUF = (BM + BN) * 128;
  extern __shared__ char lds[];
  const int t = threadIdx.x;
  const int lane = t & 63, wid = t >> 6;
  const int wm = wid >> 2, wn = wid & 3;
  const int rlo = lane & 15, khi = lane >> 4;

  const int gx = gridDim.x, nwg = gx * gridDim.y;
  int id = blockIdx.y * gx + blockIdx.x;
  int sid = (id & 7) * (nwg >> 3) + (id >> 3);
  const int m0 = (sid / gx) * BM, n0 = (sid % gx) * BN;

  const int NT = K >> 6;

  const int srow = t >> 3;
  const int scb = ((t & 7) * 16) ^ ((srow & 7) << 4);
  const char* Abase = (const char*)Ag + ((size_t)(m0 + srow) * K) * 2 + scb;
  const char* Bbase = (const char*)Bg + ((size_t)(n0 + srow) * K) * 2 + scb;
  const size_t rstride = (size_t)64 * K * 2;

  int offA[MT][2], offB[NTF][2];
#pragma unroll
  for (int mi = 0; mi < MT; ++mi)
#pragma unroll
    for (int ks = 0; ks < 2; ++ks) {
      int o = (wm * PM + mi * 16 + rlo) * 128 + ks * 64 + khi * 16;
      o ^= ((o >> 7) & 7) << 4;
      offA[mi][ks] = o;
    }
#pragma unroll
  for (int ni = 0; ni < NTF; ++ni)
#pragma unroll
    for (int ks = 0; ks < 2; ++ks) {
      int o = (wn * PN + ni * 16 + rlo) * 128 + ks * 64 + khi * 16;
      o ^= ((o >> 7) & 7) << 4;
      offB[ni][ks] = o + BM * 128;
    }

  f32x4v acc[MT][NTF];
#pragma unroll
  for (int mi = 0; mi < MT; ++mi)
#pragma unroll
    for (int ni = 0; ni < NTF; ++ni) acc[mi][ni] = (f32x4v){0.f, 0.f, 0.f, 0.f};

#define STAGE(KT, P)                                                        \
  do {                                                                      \
    const char* a_ = Abase + (size_t)(KT) * 128;                            \
    const char* b_ = Bbase + (size_t)(KT) * 128;                            \
    char* da_ = lds + (P) * BUF + t * 16;                                   \
    char* db_ = lds + (P) * BUF + BM * 128 + t * 16;                        \
    _Pragma("unroll") for (int i_ = 0; i_ < LA; ++i_)                       \
        gld_lds16(a_ + i_ * rstride, da_ + i_ * 8192);                      \
    _Pragma("unroll") for (int i_ = 0; i_ < LB; ++i_)                       \
        gld_lds16(b_ + i_ * rstride, db_ + i_ * 8192);                      \
  } while (0)

  STAGE(0, 0);
  STAGE(1, 1);
  waitcnt_vm<SL>();
  __builtin_amdgcn_s_barrier();
  __builtin_amdgcn_sched_barrier(0);

#pragma unroll 1
  for (int kt = 0; kt < NT; ++kt) {
    const char* base = lds + (kt & 1) * BUF;
#pragma unroll
    for (int ks = 0; ks < 2; ++ks) {
      bf16x8 af[MT], bv[NTF];
#pragma unroll
      for (int mi = 0; mi < MT; ++mi) af[mi] = *(const bf16x8*)(base + offA[mi][ks]);
#pragma unroll
      for (int ni = 0; ni < NTF; ++ni) bv[ni] = *(const bf16x8*)(base + offB[ni][ks]);
      __builtin_amdgcn_s_setprio(1);
#pragma unroll
      for (int mi = 0; mi < MT; ++mi)
#pragma unroll
        for (int ni = 0; ni < NTF; ++ni)
          acc[mi][ni] = __builtin_amdgcn_mfma_f32_16x16x32_bf16(af[mi], bv[ni], acc[mi][ni], 0, 0, 0);
      __builtin_amdgcn_s_setprio(0);
    }
    if (kt + 1 < NT) {
      __builtin_amdgcn_s_barrier();
      if (kt + 2 < NT) {
        STAGE(kt + 2, kt & 1);
        waitcnt_vm<SL>();
      } else {
        waitcnt_vm<0>();
      }
      __builtin_amdgcn_s_barrier();
      __builtin_amdgcn_sched_barrier(0);
    }
  }
#undef STAGE
  waitcnt_vm<0>();

  const int mrb = khi * 4;
#pragma unroll
  for (int mi = 0; mi < MT; ++mi)
#pragma unroll
    for (int ni = 0; ni < NTF; ++ni)
#pragma unroll
      for (int r = 0; r < 4; ++r) {
        int mm = m0 + wm * PM + mi * 16 + mrb + r;
        int nn = n0 + wn * PN + ni * 16 + rlo;
        float v = acc[mi][ni][r];
        if (OUT_BF16) ((unsigned short*)Cg)[(size_t)mm * N + nn] = f2bf(v);
        else          ((float*)Cg)[(size_t)mm * N + nn] = v;
      }
}

// ---------------------------------------------------------------- causal conv K=4 + SiLU
__global__ __launch_bounds__(256) void conv_silu_kernel(const unsigned short* __restrict__ C1,
                                                        const float* __restrict__ conv_w,
                                                        unsigned short* __restrict__ QKV) {
  int idx = blockIdx.x * 256 + threadIdx.x;
  int row = idx >> 11;
  int c4 = (idx & 2047) << 2;
  int s = row & 2047;
  float4 w0 = *(const float4*)(conv_w + (size_t)(c4 + 0) * 4);
  float4 w1 = *(const float4*)(conv_w + (size_t)(c4 + 1) * 4);
  float4 w2 = *(const float4*)(conv_w + (size_t)(c4 + 2) * 4);
  float4 w3 = *(const float4*)(conv_w + (size_t)(c4 + 3) * 4);
  const float* pw0 = (const float*)&w0;
  const float* pw1 = (const float*)&w1;
  const float* pw2 = (const float*)&w2;
  const float* pw3 = (const float*)&w3;
  float a0 = 0.f, a1 = 0.f, a2 = 0.f, a3 = 0.f;
#pragma unroll
  for (int j = 0; j < 4; ++j) {
    int sr = s - 3 + j;
    if (sr < 0) continue;
    ushort4 mv = *(const ushort4*)(C1 + (size_t)(row - 3 + j) * NWP + c4);
    a0 += bf2f(mv.x) * pw0[j];
    a1 += bf2f(mv.y) * pw1[j];
    a2 += bf2f(mv.z) * pw2[j];
    a3 += bf2f(mv.w) * pw3[j];
  }
  ushort4 o;
  o.x = f2bf(a0 / (1.f + __expf(-a0)));
  o.y = f2bf(a1 / (1.f + __expf(-a1)));
  o.z = f2bf(a2 / (1.f + __expf(-a2)));
  o.w = f2bf(a3 / (1.f + __expf(-a3)));
  *(ushort4*)(QKV + (size_t)row * CONVD + c4) = o;
}

// ---------------------------------------------------------------- beta / g
__global__ __launch_bounds__(256) void gbeta_kernel(const unsigned short* __restrict__ C1,
                                                    const float* __restrict__ dt_bias,
                                                    const float* __restrict__ A_log,
                                                    float* __restrict__ G, float* __restrict__ BETA) {
  int idx = blockIdx.x * 256 + threadIdx.x;
  int row = idx >> 5, h = idx & 31;
  float bp = bf2f(C1[(size_t)row * NWP + 12288 + h]);
  float ap = bf2f(C1[(size_t)row * NWP + 12320 + h]);
  BETA[idx] = 1.f / (1.f + __expf(-bp));
  float x = ap + dt_bias[h];
  float sp = (x > 15.f) ? x : log1pf(__expf(x));
  G[idx] = -__expf(A_log[h]) * sp;
}

// ---------------------------------------------------------------- INTRA: per-chunk solve
#define INTRA_SMEM 70144
__global__ __launch_bounds__(256) void intra_kernel(const unsigned short* __restrict__ QKV,
                                                    const float* __restrict__ G,
                                                    const float* __restrict__ BETA,
                                                    unsigned short* __restrict__ WU,
                                                    unsigned short* __restrict__ ATTN) {
  extern __shared__ char smem[];
  unsigned short* ktb = (unsigned short*)smem;        // [64][136]
  float* Amat = (float*)(smem + 17408);               // [64][68]
  float* Xt   = (float*)(smem + 34816);               // [128][68]
  unsigned short* qb = (unsigned short*)Xt;           // [64][136] alias
  float* gc  = (float*)(smem + 69632);                // [64]
  float* bet = gc + 64;                               // [64]

  const int t = threadIdx.x;
  const int lane = t & 63, w = t >> 6;
  const int rlo = lane & 15, khi = lane >> 4;
  const int cix = blockIdx.x & 31;
  const int h = (blockIdx.x >> 5) & 31;
  const int b = blockIdx.x >> 10;
  const int hq = h >> 1;
  const int row0 = cix * 64;
  const size_t rowbase = (size_t)b * SEQ;

  if (t < 64) {
    float gv = G[(rowbase + row0 + t) * NUMV + h];
    bet[t] = BETA[(rowbase + row0 + t) * NUMV + h];
#pragma unroll
    for (int off = 1; off < 64; off <<= 1) {
      float u = __shfl_up(gv, off, 64);
      if (t >= off) gv += u;
    }
    gc[t] = gv;
  }
  __syncthreads();

  const int r = t >> 2, q4 = t & 3;
  const size_t grow = (rowbase + row0 + r) * (size_t)CONVD;

  {
    const unsigned short* kp = QKV + grow + 2048 + hq * 128 + q4 * 32;
    float kv[32]; float ssk = 0.f;
#pragma unroll
    for (int j = 0; j < 32; j += 4) {
      ushort4 km = *(const ushort4*)(kp + j);
      kv[j] = bf2f(km.x); kv[j + 1] = bf2f(km.y); kv[j + 2] = bf2f(km.z); kv[j + 3] = bf2f(km.w);
      ssk += kv[j]*kv[j] + kv[j+1]*kv[j+1] + kv[j+2]*kv[j+2] + kv[j+3]*kv[j+3];
    }
    ssk += __shfl_xor(ssk, 1, 64);
    ssk += __shfl_xor(ssk, 2, 64);
    const float rk = rsqrtf(ssk + 1e-6f);
    const float ekr = __expf(gc[r]) * bet[r];
#pragma unroll
    for (int j = 0; j < 32; ++j) {
      float kn = kv[j] * rk;
      ktb[r * 136 + q4 * 32 + j] = f2bf(kn);
      Xt[(q4 * 32 + j) * 68 + r] = kn * ekr;
    }
  }
  __syncthreads();

  {
    static const signed char SJ[10][2] = {{0,0},{1,0},{1,1},{2,0},{2,1},{2,2},{3,0},{3,1},{3,2},{3,3}};
    static const signed char SB[5] = {0, 4, 7, 9, 10};
    for (int sj = SB[w]; sj < SB[w + 1]; ++sj) {
      const int mt = SJ[sj][0], nt = SJ[sj][1];
      f32x4v acc = (f32x4v){0.f, 0.f, 0.f, 0.f};
#pragma unroll
      for (int ks = 0; ks < 4; ++ks) {
        bf16x8 af = *(const bf16x8*)&ktb[(mt * 16 + rlo) * 136 + ks * 32 + khi * 8];
        bf16x8 bf_ = *(const bf16x8*)&ktb[(nt * 16 + rlo) * 136 + ks * 32 + khi * 8];
        acc = __builtin_amdgcn_mfma_f32_16x16x32_bf16(af, bf_, acc, 0, 0, 0);
      }
      const int j = nt * 16 + rlo;
#pragma unroll
      for (int r2 = 0; r2 < 4; ++r2) {
        const int i = mt * 16 + khi * 4 + r2;
        if (j < i) Amat[i * 68 + j] = -bet[i] * __expf(gc[i] - gc[j]) * acc[r2];
      }
    }
  }
  __syncthreads();

#pragma unroll 1
  for (int ib = 0; ib < 8; ++ib) {
    const int i0 = ib * 8;
    if (t < 128) {
      float* Xc = Xt + t * 68;
      float p[8] = {0, 0, 0, 0, 0, 0, 0, 0};
      for (int j = 0; j < i0; j += 4) {
        f32x4v xj = *(const f32x4v*)&Xc[j];
#pragma unroll
        for (int r2 = 0; r2 < 8; ++r2) {
          f32x4v ar = *(const f32x4v*)&Amat[(i0 + r2) * 68 + j];
          p[r2] += ar[0] * xj[0] + ar[1] * xj[1] + ar[2] * xj[2] + ar[3] * xj[3];
        }
      }
      float xi[8];
#pragma unroll
      for (int r2 = 0; r2 < 8; ++r2) {
        float v = Xc[i0 + r2] + p[r2];
#pragma unroll
        for (int r3 = 0; r3 < r2; ++r3) v += Amat[(i0 + r2) * 68 + i0 + r3] * xi[r3];
        xi[r2] = v;
        Xc[i0 + r2] = v;
      }
    }
    __syncthreads();
  }

  {
    unsigned short* wdst = WU + (rowbase + row0 + r) * (size_t)NWP + h * 128 + q4 * 32;
#pragma unroll
    for (int j = 0; j < 32; ++j) wdst[j] = f2bf(Xt[(q4 * 32 + j) * 68 + r]);
    const unsigned short* vp = QKV + grow + 4096 + h * 128 + q4 * 32;
    const float brow = bet[r];
#pragma unroll
    for (int j = 0; j < 32; j += 4) {
      ushort4 vm = *(const ushort4*)(vp + j);
      Xt[(q4 * 32 + j + 0) * 68 + r] = bf2f(vm.x) * brow;
      Xt[(q4 * 32 + j + 1) * 68 + r] = bf2f(vm.y) * brow;
      Xt[(q4 * 32 + j + 2) * 68 + r] = bf2f(vm.z) * brow;
      Xt[(q4 * 32 + j + 3) * 68 + r] = bf2f(vm.w) * brow;
    }
  }
  __syncthreads();

#pragma unroll 1
  for (int ib = 0; ib < 8; ++ib) {
    const int i0 = ib * 8;
    if (t < 128) {
      float* Xc = Xt + t * 68;
      float p[8] = {0, 0, 0, 0, 0, 0, 0, 0};
      for (int j = 0; j < i0; j += 4) {
        f32x4v xj = *(const f32x4v*)&Xc[j];
#pragma unroll
        for (int r2 = 0; r2 < 8; ++r2) {
          f32x4v ar = *(const f32x4v*)&Amat[(i0 + r2) * 68 + j];
          p[r2] += ar[0] * xj[0] + ar[1] * xj[1] + ar[2] * xj[2] + ar[3] * xj[3];
        }
      }
      float xi[8];
#pragma unroll
      for (int r2 = 0; r2 < 8; ++r2) {
        float v = Xc[i0 + r2] + p[r2];
#pragma unroll
        for (int r3 = 0; r3 < r2; ++r3) v += Amat[(i0 + r2) * 68 + i0 + r3] * xi[r3];
        xi[r2] = v;
        Xc[i0 + r2] = v;
      }
    }
    __syncthreads();
  }

  {
    unsigned short* udst = WU + (rowbase + row0 + r) * (size_t)NWP + 4096 + h * 128 + q4 * 32;
#pragma unroll
    for (int j = 0; j < 32; ++j) udst[j] = f2bf(Xt[(q4 * 32 + j) * 68 + r]);
  }
  __syncthreads();

  {
    const unsigned short* qp = QKV + grow + hq * 128 + q4 * 32;
    float qv[32]; float ssq = 0.f;
#pragma unroll
    for (int j = 0; j < 32; j += 4) {
      ushort4 qm = *(const ushort4*)(qp + j);
      qv[j] = bf2f(qm.x); qv[j + 1] = bf2f(qm.y); qv[j + 2] = bf2f(qm.z); qv[j + 3] = bf2f(qm.w);
      ssq += qv[j]*qv[j] + qv[j+1]*qv[j+1] + qv[j+2]*qv[j+2] + qv[j+3]*qv[j+3];
    }
    ssq += __shfl_xor(ssq, 1, 64);
    ssq += __shfl_xor(ssq, 2, 64);
    const float rq = rsqrtf(ssq + 1e-6f) * 0.08838834764831845f;
#pragma unroll
    for (int j = 0; j < 32; ++j) qb[r * 136 + q4 * 32 + j] = f2bf(qv[j] * rq);
  }
  __syncthreads();

  {
    const size_t abase = (((size_t)b * 32 + h) * 32 + cix) * 4096;
#pragma unroll 1
    for (int nt = 0; nt < 4; ++nt) {
      const int j = nt * 16 + rlo;
      float vals[4] = {0.f, 0.f, 0.f, 0.f};
      if (nt <= w) {
        f32x4v acc = (f32x4v){0.f, 0.f, 0.f, 0.f};
#pragma unroll
        for (int ks = 0; ks < 4; ++ks) {
          bf16x8 af = *(const bf16x8*)&qb[(w * 16 + rlo) * 136 + ks * 32 + khi * 8];
          bf16x8 bf_ = *(const bf16x8*)&ktb[(nt * 16 + rlo) * 136 + ks * 32 + khi * 8];
          acc = __builtin_amdgcn_mfma_f32_16x16x32_bf16(af, bf_, acc, 0, 0, 0);
        }
#pragma unroll
        for (int r2 = 0; r2 < 4; ++r2) {
          const int i = w * 16 + khi * 4 + r2;
          if (j <= i) vals[r2] = __expf(gc[i] - gc[j]) * acc[r2];
        }
      }
#pragma unroll
      for (int r2 = 0; r2 < 4; ++r2)
        ATTN[abase + (w * 16 + khi * 4 + r2) * 64 + j] = f2bf(vals[r2]);
    }
  }
}

// ---------------------------------------------------------------- SEQ: state recurrence
#define SEQ_SMEM 70400
__global__ __launch_bounds__(256) void seq_kernel(const unsigned short* __restrict__ QKV,
                                                  const float* __restrict__ G,
                                                  const unsigned short* __restrict__ WU,
                                                  const unsigned short* __restrict__ ATTN,
                                                  unsigned short* __restrict__ CORE) {
  extern __shared__ char smem[];
  unsigned short* ktT    = (unsigned short*)smem;            // [128][88]
  unsigned short* wb     = (unsigned short*)(smem + 22528);  // [64][136]
  unsigned short* attnb  = (unsigned short*)(smem + 39936);  // [64][88]
  float* stateT          = (float*)(smem + 51200);           // [16][136]
  unsigned short* stateTb = (unsigned short*)(smem + 59904); // [16][136]
  unsigned short* vnTb   = (unsigned short*)(smem + 64256);  // [16][88]
  unsigned short* vdTb   = (unsigned short*)(smem + 67072);  // [16][88]
  float* gc   = (float*)(smem + 69888);                      // [64]
  float* edec = (float*)(smem + 70144);                      // [64]

  const int t = threadIdx.x;
  const int lane = t & 63, w = t >> 6;
  const int rlo = lane & 15, khi = lane >> 4;
  const int vq = blockIdx.x & 7;
  const int h = (blockIdx.x >> 3) & 31;
  const int b = blockIdx.x >> 8;
  const int hq = h >> 1;
  const size_t rowbase = (size_t)b * SEQ;
  const size_t ahead = ((size_t)b * 32 + h) * 32;

  for (int i = t; i < 16 * 136; i += 256) { stateT[i] = 0.f; stateTb[i] = 0; }
  __syncthreads();

  bf16x8 qf[4];

#pragma unroll 1
  for (int ncb = 0; ncb < 32; ++ncb) {
    const int row0 = ncb * 64;

    if (t < 64) {
      float gv = G[(rowbase + row0 + t) * NUMV + h];
#pragma unroll
      for (int off = 1; off < 64; off <<= 1) {
        float u = __shfl_up(gv, off, 64);
        if (t >= off) gv += u;
      }
      gc[t] = gv;
      float tot = __shfl(gv, 63, 64);
      edec[t] = __expf(tot - gv);
    }
    __syncthreads();

    {
      const int r = t >> 2, q4 = t & 3;
      const size_t grow = (rowbase + row0 + r) * (size_t)CONVD;
      const unsigned short* kp = QKV + grow + 2048 + hq * 128 + q4 * 32;
      float kv[32]; float ssk = 0.f;
#pragma unroll
      for (int j = 0; j < 32; j += 4) {
        ushort4 km = *(const ushort4*)(kp + j);
        kv[j] = bf2f(km.x); kv[j + 1] = bf2f(km.y); kv[j + 2] = bf2f(km.z); kv[j + 3] = bf2f(km.w);
        ssk += kv[j]*kv[j] + kv[j+1]*kv[j+1] + kv[j+2]*kv[j+2] + kv[j+3]*kv[j+3];
      }
      ssk += __shfl_xor(ssk, 1, 64);
      ssk += __shfl_xor(ssk, 2, 64);
      const float rk = rsqrtf(ssk + 1e-6f);
#pragma unroll
      for (int j = 0; j < 32; ++j) ktT[(q4 * 32 + j) * 88 + r] = f2bf(kv[j] * rk);
      const unsigned short* wsrc = WU + (rowbase + row0 + r) * (size_t)NWP + h * 128 + q4 * 32;
#pragma unroll
      for (int u2 = 0; u2 < 4; ++u2)
        *(uint4*)&wb[r * 136 + q4 * 32 + u2 * 8] = *(const uint4*)(wsrc + u2 * 8);
      const unsigned short* asrc = ATTN + (ahead + ncb) * 4096 + r * 64 + q4 * 16;
      *(uint4*)&attnb[r * 88 + q4 * 16] = *(const uint4*)(asrc);
      *(uint4*)&attnb[r * 88 + q4 * 16 + 8] = *(const uint4*)(asrc + 8);
      const unsigned short* qsrc = QKV + (rowbase + row0 + w * 16 + rlo) * (size_t)CONVD + hq * 128 + khi * 8;
      float qv[32]; float ssq = 0.f;
#pragma unroll
      for (int ks = 0; ks < 4; ++ks) {
        ushort4 qa = *(const ushort4*)(qsrc + ks * 32);
        ushort4 qb2 = *(const ushort4*)(qsrc + ks * 32 + 4);
        qv[ks*8+0] = bf2f(qa.x); qv[ks*8+1] = bf2f(qa.y); qv[ks*8+2] = bf2f(qa.z); qv[ks*8+3] = bf2f(qa.w);
        qv[ks*8+4] = bf2f(qb2.x); qv[ks*8+5] = bf2f(qb2.y); qv[ks*8+6] = bf2f(qb2.z); qv[ks*8+7] = bf2f(qb2.w);
#pragma unroll
        for (int e = 0; e < 8; ++e) ssq += qv[ks*8+e] * qv[ks*8+e];
      }
      ssq += __shfl_xor(ssq, 16, 64);
      ssq += __shfl_xor(ssq, 32, 64);
      const float rq = rsqrtf(ssq + 1e-6f) * 0.08838834764831845f;
#pragma unroll
      for (int ks = 0; ks < 4; ++ks) {
        bf16x8 tv;
#pragma unroll
        for (int e = 0; e < 8; ++e) tv[e] = (short)f2bf(qv[ks*8+e] * rq);
        qf[ks] = tv;
      }
    }
    __syncthreads();

    f32x4v oacc;
    {
      f32x4v pacc = (f32x4v){0.f, 0.f, 0.f, 0.f};
      oacc = (f32x4v){0.f, 0.f, 0.f, 0.f};
#pragma unroll
      for (int ks = 0; ks < 4; ++ks) {
        bf16x8 aw = *(const bf16x8*)&wb[(w * 16 + rlo) * 136 + ks * 32 + khi * 8];
        bf16x8 bs = *(const bf16x8*)&stateTb[rlo * 136 + ks * 32 + khi * 8];
        pacc = __builtin_amdgcn_mfma_f32_16x16x32_bf16(aw, bs, pacc, 0, 0, 0);
        oacc = __builtin_amdgcn_mfma_f32_16x16x32_bf16(qf[ks], bs, oacc, 0, 0, 0);
      }
#pragma unroll
      for (int r2 = 0; r2 < 4; ++r2) {
        const int i = w * 16 + khi * 4 + r2;
        float uv = bf2f(WU[(rowbase + row0 + i) * (size_t)NWP + 4096 + h * 128 + vq * 16 + rlo]);
        float vn = uv - pacc[r2];
        vnTb[rlo * 88 + i] = f2bf(vn);
        vdTb[rlo * 88 + i] = f2bf(vn * edec[i]);
        oacc[r2] *= __expf(gc[i]);
      }
    }
    __syncthreads();

    {
#pragma unroll
      for (int ks = 0; ks < 2; ++ks) {
        bf16x8 aa = *(const bf16x8*)&attnb[(w * 16 + rlo) * 88 + ks * 32 + khi * 8];
        bf16x8 bv = *(const bf16x8*)&vnTb[rlo * 88 + ks * 32 + khi * 8];
        oacc = __builtin_amdgcn_mfma_f32_16x16x32_bf16(aa, bv, oacc, 0, 0, 0);
      }
      const int col = h * 128 + vq * 16 + rlo;
#pragma unroll
      for (int r2 = 0; r2 < 4; ++r2) {
        const int i = w * 16 + khi * 4 + r2;
        CORE[(rowbase + row0 + i) * (size_t)4096 + col] = f2bf(oacc[r2]);
      }
      const float egl = __expf(gc[63]);
#pragma unroll
      for (int n2 = 0; n2 < 2; ++n2) {
        const int dt = w * 2 + n2;
        f32x4v sacc = (f32x4v){0.f, 0.f, 0.f, 0.f};
#pragma unroll
        for (int ks = 0; ks < 2; ++ks) {
          bf16x8 ak = *(const bf16x8*)&ktT[(dt * 16 + rlo) * 88 + ks * 32 + khi * 8];
          bf16x8 bv2 = *(const bf16x8*)&vdTb[rlo * 88 + ks * 32 + khi * 8];
          sacc = __builtin_amdgcn_mfma_f32_16x16x32_bf16(ak, bv2, sacc, 0, 0, 0);
        }
#pragma unroll
        for (int r2 = 0; r2 < 4; ++r2) {
          const int d = dt * 16 + khi * 4 + r2;
          float ns = stateT[rlo * 136 + d] * egl + sacc[r2];
          stateT[rlo * 136 + d] = ns;
          stateTb[rlo * 136 + d] = f2bf(ns);
        }
      }
    }
    __syncthreads();
  }
}

// ---------------------------------------------------------------- gate * silu(z) + RMS-norm
__global__ __launch_bounds__(256) void gatenorm_kernel(const unsigned short* __restrict__ CORE,
                                                       const unsigned short* __restrict__ C1,
                                                       const float* __restrict__ norm_w,
                                                       unsigned short* __restrict__ NRM) {
  const int wid = blockIdx.x * 4 + (threadIdx.x >> 6);
  const int lane = threadIdx.x & 63;
  const int row = wid >> 5, h = wid & 31;
  const int c = lane * 2;
  const size_t cidx = (size_t)row * 4096 + h * 128 + c;
  const size_t zidx = (size_t)row * NWP + 8192 + h * 128 + c;
  float g0 = bf2f(CORE[cidx]), g1 = bf2f(CORE[cidx + 1]);
  float z0 = bf2f(C1[zidx]), z1 = bf2f(C1[zidx + 1]);
  g0 *= z0 / (1.f + __expf(-z0));
  g1 *= z1 / (1.f + __expf(-z1));
  float ss = g0 * g0 + g1 * g1;
#pragma unroll
  for (int m = 1; m < 64; m <<= 1) ss += __shfl_xor(ss, m, 64);
  const float rr = rsqrtf(ss * (1.f / 128.f) + 1e-6f);
  unsigned int o = ((unsigned int)f2bf(g1 * rr * norm_w[c + 1]) << 16) | (unsigned int)f2bf(g0 * rr * norm_w[c]);
  *(unsigned int*)(NRM + cidx) = o;
}

// ---------------------------------------------------------------------------
extern "C" void kernel_launch(void* const* d_in, const int* in_sizes, int n_in,
                              void* d_out, int out_size, void* d_ws, size_t ws_size,
                              hipStream_t stream) {
  const float* hs      = (const float*)d_in[0];
  const float* W_qkv   = (const float*)d_in[1];
  const float* W_z     = (const float*)d_in[2];
  const float* W_b     = (const float*)d_in[3];
  const float* W_a     = (const float*)d_in[4];
  const float* conv_w  = (const float*)d_in[5];
  const float* dt_bias = (const float*)d_in[6];
  const float* A_log   = (const float*)d_in[7];
  const float* norm_w  = (const float*)d_in[8];
  const float* W_out   = (const float*)d_in[9];
  float* out = (float*)d_out;
  char* ws = (char*)d_ws;

  const size_t OFF_HSB = 0;                                     // hs bf16; later ATTN
  const size_t OFF_WT  = OFF_HSB + (size_t)ROWS * HIDN * 2;     // WT; later CORE
  const size_t OFF_WOT = OFF_WT + (size_t)NWP * HIDN * 2;
  const size_t OFF_C1  = OFF_WOT + (size_t)HIDN * 4096 * 2;     // C1; cols [0,8192) -> w,u after conv
  const size_t OFF_QKV = OFF_C1 + (size_t)ROWS * NWP * 2;       // QKV; later NRM
  const size_t OFF_G   = OFF_QKV + (size_t)ROWS * CONVD * 2;
  const size_t OFF_B   = OFF_G + (size_t)ROWS * NUMV * 4;

  unsigned short* hsb = (unsigned short*)(ws + OFF_HSB);
  unsigned short* WT  = (unsigned short*)(ws + OFF_WT);
  unsigned short* WoT = (unsigned short*)(ws + OFF_WOT);
  unsigned short* C1  = (unsigned short*)(ws + OFF_C1);
  unsigned short* QKV = (unsigned short*)(ws + OFF_QKV);
  float* Gb = (float*)(ws + OFF_G);
  float* Bb = (float*)(ws + OFF_B);
  unsigned short* ATTNb = (unsigned short*)(ws + OFF_HSB);
  unsigned short* COREb = (unsigned short*)(ws + OFF_WT);
  unsigned short* NRMb  = (unsigned short*)(ws + OFF_QKV);

  cast_kernel<<<ROWS * HIDN / 4 / 256, 256, 0, stream>>>(hs, hsb, ROWS * HIDN / 4);
  transpose_kernel<<<dim3(8192 / 64, 2048 / 64), 256, 0, stream>>>(W_qkv, WT, 2048, 8192, HIDN, 0);
  transpose_kernel<<<dim3(4096 / 64, 2048 / 64), 256, 0, stream>>>(W_z, WT, 2048, 4096, HIDN, 8192);
  transpose_kernel<<<dim3(1, 2048 / 64), 256, 0, stream>>>(W_b, WT, 2048, 32, HIDN, 12288);
  transpose_kernel<<<dim3(1, 2048 / 64), 256, 0, stream>>>(W_a, WT, 2048, 32, HIDN, 12320);
  hipMemsetAsync(ws + OFF_WT + (size_t)12352 * HIDN * 2, 0, (size_t)192 * HIDN * 2, stream);
  transpose_kernel<<<dim3(2048 / 64, 4096 / 64), 256, 0, stream>>>(W_out, WoT, 4096, 2048, 4096, 0);

  void (*g1p)(const unsigned short*, const unsigned short*, void*, int, int, int) = gemm_ks_kernel<1>;
  void (*g0p)(const unsigned short*, const unsigned short*, void*, int, int, int) = gemm_s_kernel<128, 256, 0>;
  hipFuncSetAttribute((const void*)g1p, hipFuncAttributeMaxDynamicSharedMemorySize, G1_LDS);
  hipFuncSetAttribute((const void*)g0p, hipFuncAttributeMaxDynamicSharedMemorySize, (128 + 256) * 128 * 2);

  gemm_ks_kernel<1><<<dim3(NWP / 256, ROWS / 256), 512, G1_LDS, stream>>>(
      hsb, WT, C1, ROWS, NWP, HIDN);
  conv_silu_kernel<<<ROWS * (CONVD / 4) / 256, 256, 0, stream>>>(C1, conv_w, QKV);
  gbeta_kernel<<<ROWS * NUMV / 256, 256, 0, stream>>>(C1, dt_bias, A_log, Gb, Bb);

  hipFuncSetAttribute((const void*)intra_kernel, hipFuncAttributeMaxDynamicSharedMemorySize,
                      INTRA_SMEM);
  intra_kernel<<<2048, 256, INTRA_SMEM, stream>>>(QKV, Gb, Bb, C1, ATTNb);

  hipFuncSetAttribute((const void*)seq_kernel, hipFuncAttributeMaxDynamicSharedMemorySize,
                      SEQ_SMEM);
  seq_kernel<<<512, 256, SEQ_SMEM, stream>>>(QKV, Gb, C1, ATTNb, COREb);

  gatenorm_kernel<<<ROWS * NUMV / 4, 256, 0, stream>>>(COREb, C1, norm_w, NRMb);
  gemm_s_kernel<128, 256, 0><<<dim3(2048 / 256, ROWS / 128), 512, (128 + 256) * 128 * 2, stream>>>(
      NRMb, WoT, out, ROWS, 2048, 4096);
}

// Round 11
// 815.278 us; speedup vs baseline: 1.1153x; 1.0877x over previous
//
#include <hip/hip_runtime.h>
#include <cstdint>
#include <cstddef>

// ---------------------------------------------------------------------------
// GatedDeltaNet forward, MI355X/gfx950.
//  1. cast hs -> bf16 ; transpose weights -> bf16 [N][K]
//  2. GEMM1 = gemm_ks<256,256> (K-split sub-phase pipeline, wave-uniform residency)
//  3. causal conv(K=4)+SiLU -> QKV bf16 ; beta/g
//  4. INTRA: A build + register-resident concurrent dual solve -> w,u ; attn
//  5. SEQ: state recurrence, MFMA
//  6. gate + RMS-norm ; GEMM2 = gemm_ks<128,256> (256 WGs = 1/CU)
// ---------------------------------------------------------------------------

#define ROWS  4096
#define SEQ   2048
#define HIDN  2048
#define CONVD 8192
#define NWP   12544     // 8192 qkv + 4096 z + 32 b + 32 a + 192 pad (49*256)
#define NUMV  32

using bf16x8 = __attribute__((ext_vector_type(8))) short;
using f32x4v = __attribute__((ext_vector_type(4))) float;

__device__ __forceinline__ float bf2f(unsigned short u) {
  union { unsigned int i; float f; } x; x.i = ((unsigned int)u) << 16; return x.f;
}
__device__ __forceinline__ unsigned short f2bf(float f) {
  union { float f; unsigned int u; } x; x.f = f;
  unsigned int u = x.u;
  unsigned int r = (u + 0x7FFFu + ((u >> 16) & 1u)) >> 16;  // RNE
  return (unsigned short)r;
}

typedef const __attribute__((address_space(1))) unsigned int GU32;
typedef __attribute__((address_space(3))) unsigned int LU32;
__device__ __forceinline__ void gld_lds16(const void* g, void* l) {
  GU32* gp = (GU32*)(unsigned long long)(uintptr_t)g;
  LU32* lp = (LU32*)(unsigned int)(uintptr_t)l;  // flat-LDS low32 = LDS offset
  __builtin_amdgcn_global_load_lds(gp, lp, 16, 0, 0);
}
// counted VMEM wait — asm with "memory" clobber (compiler-level fence)
template <int N>
__device__ __forceinline__ void waitcnt_vm() {
  asm volatile("s_waitcnt vmcnt(%0)" ::"i"(N) : "memory");
}

// ---------------------------------------------------------------- cast fp32->bf16
__global__ __launch_bounds__(256) void cast_kernel(const float* __restrict__ in,
                                                   unsigned short* __restrict__ out, int n4) {
  int i = blockIdx.x * 256 + threadIdx.x;
  if (i >= n4) return;
  float4 v = ((const float4*)in)[i];
  ushort4 o;
  o.x = f2bf(v.x); o.y = f2bf(v.y); o.z = f2bf(v.z); o.w = f2bf(v.w);
  ((ushort4*)out)[i] = o;
}

// ------------------------------------------------- transpose W[K][N] -> WT[roff+N][K] bf16
__global__ __launch_bounds__(256) void transpose_kernel(const float* __restrict__ W,
                                                        unsigned short* __restrict__ WT,
                                                        int K, int N, int ld, int roff) {
  __shared__ float tile[64][65];
  const int t = threadIdx.x;
  const int kb = blockIdx.y * 64, nb = blockIdx.x * 64;
  const int r = t >> 2, c0 = (t & 3) * 16;
#pragma unroll
  for (int i = 0; i < 16; ++i) {
    int c = c0 + i;
    float v = 0.f;
    if (nb + c < N) v = W[(size_t)(kb + r) * N + nb + c];
    tile[r][c] = v;
  }
  __syncthreads();
  const int bn = t >> 2;
  if (nb + bn < N) {
#pragma unroll
    for (int i = 0; i < 16; ++i)
      WT[(size_t)(roff + nb + bn) * ld + kb + c0 + i] = f2bf(tile[c0 + i][bn]);
  }
}

// ---------------------------------------------------------------- K-split sub-phase GEMM
// 512 threads = 8 waves (2M x 4N). BK=64 split into 2 ks-halves; 4 LDS regions of
// (BM+BN)*64 B. Phase p: {MT+NTF ds_reads region(p&3); stage region((p+3)&3) [LPS loads];
// MFMA quadrant-K; vmcnt(2*LPS); barrier}. Wave-uniform residency (R10-proven).
// Swizzle (64B rows): o ^= ((o>>7)&3)<<4 ; staging source pre-swizzled (rule #21).
template <int BM, int BN, int OUT_BF16>
__global__ __launch_bounds__(512) void gemm_ks_kernel(const unsigned short* __restrict__ Ag,
                                                      const unsigned short* __restrict__ Bg,
                                                      void* __restrict__ Cg, int M, int N, int K) {
  constexpr int PM = BM / 2, PN = BN / 4;
  constexpr int MT = PM / 16, NTF = PN / 16;
  constexpr int NA = BM / 128, NB = BN / 128;
  constexpr int LPS = NA + NB;
  constexpr int REG = (BM + BN) * 64;       // bytes per region
  extern __shared__ char lds[];
  const int t = threadIdx.x;
  const int lane = t & 63, wid = t >> 6;
  const int wm = wid >> 2, wn = wid & 3;
  const int rlo = lane & 15, khi = lane >> 4;

  // T1: bijective XCD swizzle (grid multiple of 8)
  const int gx = gridDim.x, nwg = gx * gridDim.y;
  int id = blockIdx.y * gx + blockIdx.x;
  int sid = (id & 7) * (nwg >> 3) + (id >> 3);
  const int m0 = (sid / gx) * BM, n0 = (sid % gx) * BN;

  const int NT = K >> 6;
  const int NPH = NT * 2;

  const int srow = t >> 2;                                  // 0..127
  const int scs = ((t & 3) * 16) ^ (((t >> 3) & 3) << 4);   // pre-swizzled 16B slot
  const char* Ap[NA];
  const char* Bp[NB];
#pragma unroll
  for (int i = 0; i < NA; ++i)
    Ap[i] = (const char*)Ag + (size_t)(m0 + i * 128 + srow) * K * 2 + scs;
#pragma unroll
  for (int i = 0; i < NB; ++i)
    Bp[i] = (const char*)Bg + (size_t)(n0 + i * 128 + srow) * K * 2 + scs;
  char* dst = lds + t * 16;

  int offA[MT], offB[NTF];
#pragma unroll
  for (int mi = 0; mi < MT; ++mi) {
    int o = (wm * PM + mi * 16 + rlo) * 64 + khi * 16;
    o ^= ((o >> 7) & 3) << 4;
    offA[mi] = o;
  }
#pragma unroll
  for (int ni = 0; ni < NTF; ++ni) {
    int o = (wn * PN + ni * 16 + rlo) * 64 + khi * 16;
    o ^= ((o >> 7) & 3) << 4;
    offB[ni] = o + BM * 64;
  }

  f32x4v acc[MT][NTF];
#pragma unroll
  for (int mi = 0; mi < MT; ++mi)
#pragma unroll
    for (int ni = 0; ni < NTF; ++ni) acc[mi][ni] = (f32x4v){0.f, 0.f, 0.f, 0.f};

#define STG(PS)                                                              \
  do {                                                                       \
    int kts_ = ((PS) >> 1 < NT) ? ((PS) >> 1) : NT - 1;                      \
    size_t co_ = (size_t)kts_ * 128 + (size_t)((PS) & 1) * 64;               \
    char* d_ = dst + (((PS) & 3) * REG);                                     \
    _Pragma("unroll") for (int i_ = 0; i_ < NA; ++i_)                        \
        gld_lds16(Ap[i_] + co_, d_ + i_ * 8192);                             \
    _Pragma("unroll") for (int i_ = 0; i_ < NB; ++i_)                        \
        gld_lds16(Bp[i_] + co_, d_ + BM * 64 + i_ * 8192);                   \
  } while (0)

  // prologue: contents for phases 0,1,2 -> regions 0,1,2
  STG(0); STG(1); STG(2);
  waitcnt_vm<2 * LPS>();              // content(0) landed; (1),(2) in flight
  __builtin_amdgcn_s_barrier();
  __builtin_amdgcn_sched_barrier(0);

#pragma unroll 1
  for (int p = 0; p < NPH; ++p) {
    const char* rb = lds + (p & 3) * REG;
    bf16x8 af[MT], bv[NTF];
#pragma unroll
    for (int mi = 0; mi < MT; ++mi) af[mi] = *(const bf16x8*)(rb + offA[mi]);
#pragma unroll
    for (int ni = 0; ni < NTF; ++ni) bv[ni] = *(const bf16x8*)(rb + offB[ni]);
    STG(p + 3);                       // region((p+3)&3): last read at p-1, freed
    __builtin_amdgcn_s_setprio(1);
#pragma unroll
    for (int mi = 0; mi < MT; ++mi)
#pragma unroll
      for (int ni = 0; ni < NTF; ++ni)
        acc[mi][ni] = __builtin_amdgcn_mfma_f32_16x16x32_bf16(af[mi], bv[ni], acc[mi][ni], 0, 0, 0);
    __builtin_amdgcn_s_setprio(0);
    waitcnt_vm<2 * LPS>();            // stage(p-2) = content(p+1) proven resident
    __builtin_amdgcn_s_barrier();
    __builtin_amdgcn_sched_barrier(0);
  }
#undef STG
  waitcnt_vm<0>();                    // drain clamped stages before exit

  const int mrb = khi * 4;
#pragma unroll
  for (int mi = 0; mi < MT; ++mi)
#pragma unroll
    for (int ni = 0; ni < NTF; ++ni)
#pragma unroll
      for (int r = 0; r < 4; ++r) {
        int mm = m0 + wm * PM + mi * 16 + mrb + r;
        int nn = n0 + wn * PN + ni * 16 + rlo;
        float v = acc[mi][ni][r];
        if (OUT_BF16) ((unsigned short*)Cg)[(size_t)mm * N + nn] = f2bf(v);
        else          ((float*)Cg)[(size_t)mm * N + nn] = v;
      }
}

// ---------------------------------------------------------------- causal conv K=4 + SiLU
__global__ __launch_bounds__(256) void conv_silu_kernel(const unsigned short* __restrict__ C1,
                                                        const float* __restrict__ conv_w,
                                                        unsigned short* __restrict__ QKV) {
  int idx = blockIdx.x * 256 + threadIdx.x;
  int row = idx >> 11;
  int c4 = (idx & 2047) << 2;
  int s = row & 2047;
  float4 w0 = *(const float4*)(conv_w + (size_t)(c4 + 0) * 4);
  float4 w1 = *(const float4*)(conv_w + (size_t)(c4 + 1) * 4);
  float4 w2 = *(const float4*)(conv_w + (size_t)(c4 + 2) * 4);
  float4 w3 = *(const float4*)(conv_w + (size_t)(c4 + 3) * 4);
  const float* pw0 = (const float*)&w0;
  const float* pw1 = (const float*)&w1;
  const float* pw2 = (const float*)&w2;
  const float* pw3 = (const float*)&w3;
  float a0 = 0.f, a1 = 0.f, a2 = 0.f, a3 = 0.f;
#pragma unroll
  for (int j = 0; j < 4; ++j) {
    int sr = s - 3 + j;
    if (sr < 0) continue;
    ushort4 mv = *(const ushort4*)(C1 + (size_t)(row - 3 + j) * NWP + c4);
    a0 += bf2f(mv.x) * pw0[j];
    a1 += bf2f(mv.y) * pw1[j];
    a2 += bf2f(mv.z) * pw2[j];
    a3 += bf2f(mv.w) * pw3[j];
  }
  ushort4 o;
  o.x = f2bf(a0 / (1.f + __expf(-a0)));
  o.y = f2bf(a1 / (1.f + __expf(-a1)));
  o.z = f2bf(a2 / (1.f + __expf(-a2)));
  o.w = f2bf(a3 / (1.f + __expf(-a3)));
  *(ushort4*)(QKV + (size_t)row * CONVD + c4) = o;
}

// ---------------------------------------------------------------- beta / g
__global__ __launch_bounds__(256) void gbeta_kernel(const unsigned short* __restrict__ C1,
                                                    const float* __restrict__ dt_bias,
                                                    const float* __restrict__ A_log,
                                                    float* __restrict__ G, float* __restrict__ BETA) {
  int idx = blockIdx.x * 256 + threadIdx.x;
  int row = idx >> 5, h = idx & 31;
  float bp = bf2f(C1[(size_t)row * NWP + 12288 + h]);
  float ap = bf2f(C1[(size_t)row * NWP + 12320 + h]);
  BETA[idx] = 1.f / (1.f + __expf(-bp));
  float x = ap + dt_bias[h];
  float sp = (x > 15.f) ? x : log1pf(__expf(x));
  G[idx] = -__expf(A_log[h]) * sp;
}

// ---------------------------------------------------------------- INTRA: per-chunk solve
// A-build (MFMA) -> both triangular solves run CONCURRENTLY in registers:
// t<128 owns kcd column t, t>=128 owns v column t-128 (rhs transposed through Xt),
// fully-unrolled (static indices), zero barriers inside the solve, all lanes busy.
// Results transpose back through Xt for coalesced WU stores.
#define INTRA_SMEM 70144
__global__ __launch_bounds__(256) void intra_kernel(const unsigned short* __restrict__ QKV,
                                                    const float* __restrict__ G,
                                                    const float* __restrict__ BETA,
                                                    unsigned short* __restrict__ WU,
                                                    unsigned short* __restrict__ ATTN) {
  extern __shared__ char smem[];
  unsigned short* ktb = (unsigned short*)smem;        // [64][136]
  float* Amat = (float*)(smem + 17408);               // [64][68]
  float* Xt   = (float*)(smem + 34816);               // [128][68] col-major staging
  unsigned short* qb = (unsigned short*)Xt;           // [64][136] alias (after solves)
  float* gc  = (float*)(smem + 69632);                // [64]
  float* bet = gc + 64;                               // [64]

  const int t = threadIdx.x;
  const int lane = t & 63, w = t >> 6;
  const int rlo = lane & 15, khi = lane >> 4;
  const int cix = blockIdx.x & 31;
  const int h = (blockIdx.x >> 5) & 31;
  const int b = blockIdx.x >> 10;
  const int hq = h >> 1;
  const int row0 = cix * 64;
  const size_t rowbase = (size_t)b * SEQ;

  if (t < 64) {
    float gv = G[(rowbase + row0 + t) * NUMV + h];
    bet[t] = BETA[(rowbase + row0 + t) * NUMV + h];
#pragma unroll
    for (int off = 1; off < 64; off <<= 1) {
      float u = __shfl_up(gv, off, 64);
      if (t >= off) gv += u;
    }
    gc[t] = gv;
  }
  __syncthreads();

  const int r = t >> 2, q4 = t & 3;
  const size_t grow = (rowbase + row0 + r) * (size_t)CONVD;

  // P1: k load + l2norm -> ktb ; k-rhs (kn*e^gc*beta) -> Xt cols
  {
    const unsigned short* kp = QKV + grow + 2048 + hq * 128 + q4 * 32;
    float kv[32]; float ssk = 0.f;
#pragma unroll
    for (int j = 0; j < 32; j += 4) {
      ushort4 km = *(const ushort4*)(kp + j);
      kv[j] = bf2f(km.x); kv[j + 1] = bf2f(km.y); kv[j + 2] = bf2f(km.z); kv[j + 3] = bf2f(km.w);
      ssk += kv[j]*kv[j] + kv[j+1]*kv[j+1] + kv[j+2]*kv[j+2] + kv[j+3]*kv[j+3];
    }
    ssk += __shfl_xor(ssk, 1, 64);
    ssk += __shfl_xor(ssk, 2, 64);
    const float rk = rsqrtf(ssk + 1e-6f);
    const float ekr = __expf(gc[r]) * bet[r];
#pragma unroll
    for (int j = 0; j < 32; ++j) {
      float kn = kv[j] * rk;
      ktb[r * 136 + q4 * 32 + j] = f2bf(kn);
      Xt[(q4 * 32 + j) * 68 + r] = kn * ekr;
    }
  }
  __syncthreads();

  float xr[64];

  // P2: A-build (MFMA) ; t<128 copies its kcd column to regs
  {
    static const signed char SJ[10][2] = {{0,0},{1,0},{1,1},{2,0},{2,1},{2,2},{3,0},{3,1},{3,2},{3,3}};
    static const signed char SB[5] = {0, 4, 7, 9, 10};
    for (int sj = SB[w]; sj < SB[w + 1]; ++sj) {
      const int mt = SJ[sj][0], nt = SJ[sj][1];
      f32x4v acc = (f32x4v){0.f, 0.f, 0.f, 0.f};
#pragma unroll
      for (int ks = 0; ks < 4; ++ks) {
        bf16x8 af = *(const bf16x8*)&ktb[(mt * 16 + rlo) * 136 + ks * 32 + khi * 8];
        bf16x8 bf_ = *(const bf16x8*)&ktb[(nt * 16 + rlo) * 136 + ks * 32 + khi * 8];
        acc = __builtin_amdgcn_mfma_f32_16x16x32_bf16(af, bf_, acc, 0, 0, 0);
      }
      const int j = nt * 16 + rlo;
#pragma unroll
      for (int r2 = 0; r2 < 4; ++r2) {
        const int i = mt * 16 + khi * 4 + r2;
        if (j < i) Amat[i * 68 + j] = -bet[i] * __expf(gc[i] - gc[j]) * acc[r2];
      }
    }
    if (t < 128) {
      const float* Xc = Xt + t * 68;
#pragma unroll
      for (int j = 0; j < 64; j += 4) {
        f32x4v xv = *(const f32x4v*)(Xc + j);
        xr[j] = xv[0]; xr[j + 1] = xv[1]; xr[j + 2] = xv[2]; xr[j + 3] = xv[3];
      }
    }
  }
  __syncthreads();

  // P3: v*beta -> Xt cols (overwrite; k-rhs already captured)
  {
    const unsigned short* vp = QKV + grow + 4096 + h * 128 + q4 * 32;
    const float brow = bet[r];
#pragma unroll
    for (int j = 0; j < 32; j += 4) {
      ushort4 vm = *(const ushort4*)(vp + j);
      Xt[(q4 * 32 + j + 0) * 68 + r] = bf2f(vm.x) * brow;
      Xt[(q4 * 32 + j + 1) * 68 + r] = bf2f(vm.y) * brow;
      Xt[(q4 * 32 + j + 2) * 68 + r] = bf2f(vm.z) * brow;
      Xt[(q4 * 32 + j + 3) * 68 + r] = bf2f(vm.w) * brow;
    }
  }
  __syncthreads();
  if (t >= 128) {
    const float* Xc = Xt + (t - 128) * 68;
#pragma unroll
    for (int j = 0; j < 64; j += 4) {
      f32x4v xv = *(const f32x4v*)(Xc + j);
      xr[j] = xv[0]; xr[j + 1] = xv[1]; xr[j + 2] = xv[2]; xr[j + 3] = xv[3];
    }
  }
  __syncthreads();

  // SOLVE (I-A)x = rhs, in registers, all 256 threads, no barriers.
#pragma unroll
  for (int ib = 0; ib < 8; ++ib) {
    const int i0 = ib * 8;
    float p[8] = {0, 0, 0, 0, 0, 0, 0, 0};
#pragma unroll
    for (int j = 0; j < i0; j += 4) {
#pragma unroll
      for (int r2 = 0; r2 < 8; ++r2) {
        f32x4v ar = *(const f32x4v*)&Amat[(i0 + r2) * 68 + j];
        p[r2] += ar[0] * xr[j] + ar[1] * xr[j + 1] + ar[2] * xr[j + 2] + ar[3] * xr[j + 3];
      }
    }
#pragma unroll
    for (int r2 = 0; r2 < 8; ++r2) {
      float v = xr[i0 + r2] + p[r2];
#pragma unroll
      for (int r3 = 0; r3 < r2; ++r3) v += Amat[(i0 + r2) * 68 + i0 + r3] * xr[i0 + r3];
      xr[i0 + r2] = v;
    }
  }

  // W1: kcd results back to Xt cols ; W2: row-wise coalesced w store
  if (t < 128) {
    float* Xc = Xt + t * 68;
#pragma unroll
    for (int j = 0; j < 64; j += 4) {
      f32x4v xv = {xr[j], xr[j + 1], xr[j + 2], xr[j + 3]};
      *(f32x4v*)(Xc + j) = xv;
    }
  }
  __syncthreads();
  {
    unsigned short* wdst = WU + (rowbase + row0 + r) * (size_t)NWP + h * 128 + q4 * 32;
#pragma unroll
    for (int j = 0; j < 32; ++j) wdst[j] = f2bf(Xt[(q4 * 32 + j) * 68 + r]);
  }
  __syncthreads();
  // W3: v results back to Xt cols ; W4: row-wise u store
  if (t >= 128) {
    float* Xc = Xt + (t - 128) * 68;
#pragma unroll
    for (int j = 0; j < 64; j += 4) {
      f32x4v xv = {xr[j], xr[j + 1], xr[j + 2], xr[j + 3]};
      *(f32x4v*)(Xc + j) = xv;
    }
  }
  __syncthreads();
  {
    unsigned short* udst = WU + (rowbase + row0 + r) * (size_t)NWP + 4096 + h * 128 + q4 * 32;
#pragma unroll
    for (int j = 0; j < 32; ++j) udst[j] = f2bf(Xt[(q4 * 32 + j) * 68 + r]);
  }
  __syncthreads();

  // P5: q load + norm -> qb (aliases Xt; dead after u store barrier)
  {
    const unsigned short* qp = QKV + grow + hq * 128 + q4 * 32;
    float qv[32]; float ssq = 0.f;
#pragma unroll
    for (int j = 0; j < 32; j += 4) {
      ushort4 qm = *(const ushort4*)(qp + j);
      qv[j] = bf2f(qm.x); qv[j + 1] = bf2f(qm.y); qv[j + 2] = bf2f(qm.z); qv[j + 3] = bf2f(qm.w);
      ssq += qv[j]*qv[j] + qv[j+1]*qv[j+1] + qv[j+2]*qv[j+2] + qv[j+3]*qv[j+3];
    }
    ssq += __shfl_xor(ssq, 1, 64);
    ssq += __shfl_xor(ssq, 2, 64);
    const float rq = rsqrtf(ssq + 1e-6f) * 0.08838834764831845f;
#pragma unroll
    for (int j = 0; j < 32; ++j) qb[r * 136 + q4 * 32 + j] = f2bf(qv[j] * rq);
  }
  __syncthreads();

  // P6: attn = (q@k^T)*decay, masked j<=i; store
  {
    const size_t abase = (((size_t)b * 32 + h) * 32 + cix) * 4096;
#pragma unroll 1
    for (int nt = 0; nt < 4; ++nt) {
      const int j = nt * 16 + rlo;
      float vals[4] = {0.f, 0.f, 0.f, 0.f};
      if (nt <= w) {
        f32x4v acc = (f32x4v){0.f, 0.f, 0.f, 0.f};
#pragma unroll
        for (int ks = 0; ks < 4; ++ks) {
          bf16x8 af = *(const bf16x8*)&qb[(w * 16 + rlo) * 136 + ks * 32 + khi * 8];
          bf16x8 bf_ = *(const bf16x8*)&ktb[(nt * 16 + rlo) * 136 + ks * 32 + khi * 8];
          acc = __builtin_amdgcn_mfma_f32_16x16x32_bf16(af, bf_, acc, 0, 0, 0);
        }
#pragma unroll
        for (int r2 = 0; r2 < 4; ++r2) {
          const int i = w * 16 + khi * 4 + r2;
          if (j <= i) vals[r2] = __expf(gc[i] - gc[j]) * acc[r2];
        }
      }
#pragma unroll
      for (int r2 = 0; r2 < 4; ++r2)
        ATTN[abase + (w * 16 + khi * 4 + r2) * 64 + j] = f2bf(vals[r2]);
    }
  }
}

// ---------------------------------------------------------------- SEQ: state recurrence
#define SEQ_SMEM 70400
__global__ __launch_bounds__(256) void seq_kernel(const unsigned short* __restrict__ QKV,
                                                  const float* __restrict__ G,
                                                  const unsigned short* __restrict__ WU,
                                                  const unsigned short* __restrict__ ATTN,
                                                  unsigned short* __restrict__ CORE) {
  extern __shared__ char smem[];
  unsigned short* ktT    = (unsigned short*)smem;            // [128][88]
  unsigned short* wb     = (unsigned short*)(smem + 22528);  // [64][136]
  unsigned short* attnb  = (unsigned short*)(smem + 39936);  // [64][88]
  float* stateT          = (float*)(smem + 51200);           // [16][136]
  unsigned short* stateTb = (unsigned short*)(smem + 59904); // [16][136]
  unsigned short* vnTb   = (unsigned short*)(smem + 64256);  // [16][88]
  unsigned short* vdTb   = (unsigned short*)(smem + 67072);  // [16][88]
  float* gc   = (float*)(smem + 69888);                      // [64]
  float* edec = (float*)(smem + 70144);                      // [64]

  const int t = threadIdx.x;
  const int lane = t & 63, w = t >> 6;
  const int rlo = lane & 15, khi = lane >> 4;
  const int vq = blockIdx.x & 7;
  const int h = (blockIdx.x >> 3) & 31;
  const int b = blockIdx.x >> 8;
  const int hq = h >> 1;
  const size_t rowbase = (size_t)b * SEQ;
  const size_t ahead = ((size_t)b * 32 + h) * 32;

  for (int i = t; i < 16 * 136; i += 256) { stateT[i] = 0.f; stateTb[i] = 0; }
  __syncthreads();

  bf16x8 qf[4];

#pragma unroll 1
  for (int ncb = 0; ncb < 32; ++ncb) {
    const int row0 = ncb * 64;

    if (t < 64) {
      float gv = G[(rowbase + row0 + t) * NUMV + h];
#pragma unroll
      for (int off = 1; off < 64; off <<= 1) {
        float u = __shfl_up(gv, off, 64);
        if (t >= off) gv += u;
      }
      gc[t] = gv;
      float tot = __shfl(gv, 63, 64);
      edec[t] = __expf(tot - gv);
    }
    __syncthreads();

    {
      const int r = t >> 2, q4 = t & 3;
      const size_t grow = (rowbase + row0 + r) * (size_t)CONVD;
      const unsigned short* kp = QKV + grow + 2048 + hq * 128 + q4 * 32;
      float kv[32]; float ssk = 0.f;
#pragma unroll
      for (int j = 0; j < 32; j += 4) {
        ushort4 km = *(const ushort4*)(kp + j);
        kv[j] = bf2f(km.x); kv[j + 1] = bf2f(km.y); kv[j + 2] = bf2f(km.z); kv[j + 3] = bf2f(km.w);
        ssk += kv[j]*kv[j] + kv[j+1]*kv[j+1] + kv[j+2]*kv[j+2] + kv[j+3]*kv[j+3];
      }
      ssk += __shfl_xor(ssk, 1, 64);
      ssk += __shfl_xor(ssk, 2, 64);
      const float rk = rsqrtf(ssk + 1e-6f);
#pragma unroll
      for (int j = 0; j < 32; ++j) ktT[(q4 * 32 + j) * 88 + r] = f2bf(kv[j] * rk);
      const unsigned short* wsrc = WU + (rowbase + row0 + r) * (size_t)NWP + h * 128 + q4 * 32;
#pragma unroll
      for (int u2 = 0; u2 < 4; ++u2)
        *(uint4*)&wb[r * 136 + q4 * 32 + u2 * 8] = *(const uint4*)(wsrc + u2 * 8);
      const unsigned short* asrc = ATTN + (ahead + ncb) * 4096 + r * 64 + q4 * 16;
      *(uint4*)&attnb[r * 88 + q4 * 16] = *(const uint4*)(asrc);
      *(uint4*)&attnb[r * 88 + q4 * 16 + 8] = *(const uint4*)(asrc + 8);
      const unsigned short* qsrc = QKV + (rowbase + row0 + w * 16 + rlo) * (size_t)CONVD + hq * 128 + khi * 8;
      float qv[32]; float ssq = 0.f;
#pragma unroll
      for (int ks = 0; ks < 4; ++ks) {
        ushort4 qa = *(const ushort4*)(qsrc + ks * 32);
        ushort4 qb2 = *(const ushort4*)(qsrc + ks * 32 + 4);
        qv[ks*8+0] = bf2f(qa.x); qv[ks*8+1] = bf2f(qa.y); qv[ks*8+2] = bf2f(qa.z); qv[ks*8+3] = bf2f(qa.w);
        qv[ks*8+4] = bf2f(qb2.x); qv[ks*8+5] = bf2f(qb2.y); qv[ks*8+6] = bf2f(qb2.z); qv[ks*8+7] = bf2f(qb2.w);
#pragma unroll
        for (int e = 0; e < 8; ++e) ssq += qv[ks*8+e] * qv[ks*8+e];
      }
      ssq += __shfl_xor(ssq, 16, 64);
      ssq += __shfl_xor(ssq, 32, 64);
      const float rq = rsqrtf(ssq + 1e-6f) * 0.08838834764831845f;
#pragma unroll
      for (int ks = 0; ks < 4; ++ks) {
        bf16x8 tv;
#pragma unroll
        for (int e = 0; e < 8; ++e) tv[e] = (short)f2bf(qv[ks*8+e] * rq);
        qf[ks] = tv;
      }
    }
    __syncthreads();

    f32x4v oacc;
    {
      f32x4v pacc = (f32x4v){0.f, 0.f, 0.f, 0.f};
      oacc = (f32x4v){0.f, 0.f, 0.f, 0.f};
#pragma unroll
      for (int ks = 0; ks < 4; ++ks) {
        bf16x8 aw = *(const bf16x8*)&wb[(w * 16 + rlo) * 136 + ks * 32 + khi * 8];
        bf16x8 bs = *(const bf16x8*)&stateTb[rlo * 136 + ks * 32 + khi * 8];
        pacc = __builtin_amdgcn_mfma_f32_16x16x32_bf16(aw, bs, pacc, 0, 0, 0);
        oacc = __builtin_amdgcn_mfma_f32_16x16x32_bf16(qf[ks], bs, oacc, 0, 0, 0);
      }
#pragma unroll
      for (int r2 = 0; r2 < 4; ++r2) {
        const int i = w * 16 + khi * 4 + r2;
        float uv = bf2f(WU[(rowbase + row0 + i) * (size_t)NWP + 4096 + h * 128 + vq * 16 + rlo]);
        float vn = uv - pacc[r2];
        vnTb[rlo * 88 + i] = f2bf(vn);
        vdTb[rlo * 88 + i] = f2bf(vn * edec[i]);
        oacc[r2] *= __expf(gc[i]);
      }
    }
    __syncthreads();

    {
#pragma unroll
      for (int ks = 0; ks < 2; ++ks) {
        bf16x8 aa = *(const bf16x8*)&attnb[(w * 16 + rlo) * 88 + ks * 32 + khi * 8];
        bf16x8 bv = *(const bf16x8*)&vnTb[rlo * 88 + ks * 32 + khi * 8];
        oacc = __builtin_amdgcn_mfma_f32_16x16x32_bf16(aa, bv, oacc, 0, 0, 0);
      }
      const int col = h * 128 + vq * 16 + rlo;
#pragma unroll
      for (int r2 = 0; r2 < 4; ++r2) {
        const int i = w * 16 + khi * 4 + r2;
        CORE[(rowbase + row0 + i) * (size_t)4096 + col] = f2bf(oacc[r2]);
      }
      const float egl = __expf(gc[63]);
#pragma unroll
      for (int n2 = 0; n2 < 2; ++n2) {
        const int dt = w * 2 + n2;
        f32x4v sacc = (f32x4v){0.f, 0.f, 0.f, 0.f};
#pragma unroll
        for (int ks = 0; ks < 2; ++ks) {
          bf16x8 ak = *(const bf16x8*)&ktT[(dt * 16 + rlo) * 88 + ks * 32 + khi * 8];
          bf16x8 bv2 = *(const bf16x8*)&vdTb[rlo * 88 + ks * 32 + khi * 8];
          sacc = __builtin_amdgcn_mfma_f32_16x16x32_bf16(ak, bv2, sacc, 0, 0, 0);
        }
#pragma unroll
        for (int r2 = 0; r2 < 4; ++r2) {
          const int d = dt * 16 + khi * 4 + r2;
          float ns = stateT[rlo * 136 + d] * egl + sacc[r2];
          stateT[rlo * 136 + d] = ns;
          stateTb[rlo * 136 + d] = f2bf(ns);
        }
      }
    }
    __syncthreads();
  }
}

// ---------------------------------------------------------------- gate * silu(z) + RMS-norm
__global__ __launch_bounds__(256) void gatenorm_kernel(const unsigned short* __restrict__ CORE,
                                                       const unsigned short* __restrict__ C1,
                                                       const float* __restrict__ norm_w,
                                                       unsigned short* __restrict__ NRM) {
  const int wid = blockIdx.x * 4 + (threadIdx.x >> 6);
  const int lane = threadIdx.x & 63;
  const int row = wid >> 5, h = wid & 31;
  const int c = lane * 2;
  const size_t cidx = (size_t)row * 4096 + h * 128 + c;
  const size_t zidx = (size_t)row * NWP + 8192 + h * 128 + c;
  float g0 = bf2f(CORE[cidx]), g1 = bf2f(CORE[cidx + 1]);
  float z0 = bf2f(C1[zidx]), z1 = bf2f(C1[zidx + 1]);
  g0 *= z0 / (1.f + __expf(-z0));
  g1 *= z1 / (1.f + __expf(-z1));
  float ss = g0 * g0 + g1 * g1;
#pragma unroll
  for (int m = 1; m < 64; m <<= 1) ss += __shfl_xor(ss, m, 64);
  const float rr = rsqrtf(ss * (1.f / 128.f) + 1e-6f);
  unsigned int o = ((unsigned int)f2bf(g1 * rr * norm_w[c + 1]) << 16) | (unsigned int)f2bf(g0 * rr * norm_w[c]);
  *(unsigned int*)(NRM + cidx) = o;
}

// ---------------------------------------------------------------------------
extern "C" void kernel_launch(void* const* d_in, const int* in_sizes, int n_in,
                              void* d_out, int out_size, void* d_ws, size_t ws_size,
                              hipStream_t stream) {
  const float* hs      = (const float*)d_in[0];
  const float* W_qkv   = (const float*)d_in[1];
  const float* W_z     = (const float*)d_in[2];
  const float* W_b     = (const float*)d_in[3];
  const float* W_a     = (const float*)d_in[4];
  const float* conv_w  = (const float*)d_in[5];
  const float* dt_bias = (const float*)d_in[6];
  const float* A_log   = (const float*)d_in[7];
  const float* norm_w  = (const float*)d_in[8];
  const float* W_out   = (const float*)d_in[9];
  float* out = (float*)d_out;
  char* ws = (char*)d_ws;

  const size_t OFF_HSB = 0;                                     // hs bf16; later ATTN
  const size_t OFF_WT  = OFF_HSB + (size_t)ROWS * HIDN * 2;     // WT; later CORE
  const size_t OFF_WOT = OFF_WT + (size_t)NWP * HIDN * 2;
  const size_t OFF_C1  = OFF_WOT + (size_t)HIDN * 4096 * 2;     // C1; cols [0,8192) -> w,u after conv
  const size_t OFF_QKV = OFF_C1 + (size_t)ROWS * NWP * 2;       // QKV; later NRM
  const size_t OFF_G   = OFF_QKV + (size_t)ROWS * CONVD * 2;
  const size_t OFF_B   = OFF_G + (size_t)ROWS * NUMV * 4;

  unsigned short* hsb = (unsigned short*)(ws + OFF_HSB);
  unsigned short* WT  = (unsigned short*)(ws + OFF_WT);
  unsigned short* WoT = (unsigned short*)(ws + OFF_WOT);
  unsigned short* C1  = (unsigned short*)(ws + OFF_C1);
  unsigned short* QKV = (unsigned short*)(ws + OFF_QKV);
  float* Gb = (float*)(ws + OFF_G);
  float* Bb = (float*)(ws + OFF_B);
  unsigned short* ATTNb = (unsigned short*)(ws + OFF_HSB);
  unsigned short* COREb = (unsigned short*)(ws + OFF_WT);
  unsigned short* NRMb  = (unsigned short*)(ws + OFF_QKV);

  cast_kernel<<<ROWS * HIDN / 4 / 256, 256, 0, stream>>>(hs, hsb, ROWS * HIDN / 4);
  transpose_kernel<<<dim3(8192 / 64, 2048 / 64), 256, 0, stream>>>(W_qkv, WT, 2048, 8192, HIDN, 0);
  transpose_kernel<<<dim3(4096 / 64, 2048 / 64), 256, 0, stream>>>(W_z, WT, 2048, 4096, HIDN, 8192);
  transpose_kernel<<<dim3(1, 2048 / 64), 256, 0, stream>>>(W_b, WT, 2048, 32, HIDN, 12288);
  transpose_kernel<<<dim3(1, 2048 / 64), 256, 0, stream>>>(W_a, WT, 2048, 32, HIDN, 12320);
  hipMemsetAsync(ws + OFF_WT + (size_t)12352 * HIDN * 2, 0, (size_t)192 * HIDN * 2, stream);
  transpose_kernel<<<dim3(2048 / 64, 4096 / 64), 256, 0, stream>>>(W_out, WoT, 4096, 2048, 4096, 0);

  void (*g1p)(const unsigned short*, const unsigned short*, void*, int, int, int) = gemm_ks_kernel<256, 256, 1>;
  void (*g0p)(const unsigned short*, const unsigned short*, void*, int, int, int) = gemm_ks_kernel<128, 256, 0>;
  hipFuncSetAttribute((const void*)g1p, hipFuncAttributeMaxDynamicSharedMemorySize, 4 * (256 + 256) * 64);
  hipFuncSetAttribute((const void*)g0p, hipFuncAttributeMaxDynamicSharedMemorySize, 4 * (128 + 256) * 64);

  gemm_ks_kernel<256, 256, 1><<<dim3(NWP / 256, ROWS / 256), 512, 4 * (256 + 256) * 64, stream>>>(
      hsb, WT, C1, ROWS, NWP, HIDN);
  conv_silu_kernel<<<ROWS * (CONVD / 4) / 256, 256, 0, stream>>>(C1, conv_w, QKV);
  gbeta_kernel<<<ROWS * NUMV / 256, 256, 0, stream>>>(C1, dt_bias, A_log, Gb, Bb);

  hipFuncSetAttribute((const void*)intra_kernel, hipFuncAttributeMaxDynamicSharedMemorySize,
                      INTRA_SMEM);
  intra_kernel<<<2048, 256, INTRA_SMEM, stream>>>(QKV, Gb, Bb, C1, ATTNb);

  hipFuncSetAttribute((const void*)seq_kernel, hipFuncAttributeMaxDynamicSharedMemorySize,
                      SEQ_SMEM);
  seq_kernel<<<512, 256, SEQ_SMEM, stream>>>(QKV, Gb, C1, ATTNb, COREb);

  gatenorm_kernel<<<ROWS * NUMV / 4, 256, 0, stream>>>(COREb, C1, norm_w, NRMb);
  gemm_ks_kernel<128, 256, 0><<<dim3(2048 / 256, ROWS / 128), 512, 4 * (128 + 256) * 64, stream>>>(
      NRMb, WoT, out, ROWS, 2048, 4096);
}

// Round 12
// 740.037 us; speedup vs baseline: 1.2287x; 1.1017x over previous
//
#include <hip/hip_runtime.h>
#include <cstdint>
#include <cstddef>

// ---------------------------------------------------------------------------
// GatedDeltaNet forward, MI355X/gfx950.
//  1. cast hs -> bf16 ; transpose weights -> bf16 [N][K] (16B stores)
//  2. GEMM1 = gemm_r5<256,256> (K-split, ring-5 regions, barrier per 2 phases)
//  3. causal conv(K=4)+SiLU (8-row sliding window) ; beta/g
//  4. INTRA: A build + register-resident concurrent dual solve -> w,u ; attn
//  5. SEQ: state recurrence, MFMA
//  6. gate + RMS-norm ; GEMM2 = gemm_ks<128,256> (ring-4, R10-proven)
// ---------------------------------------------------------------------------

#define ROWS  4096
#define SEQ   2048
#define HIDN  2048
#define CONVD 8192
#define NWP   12544     // 8192 qkv + 4096 z + 32 b + 32 a + 192 pad (49*256)
#define NUMV  32

using bf16x8 = __attribute__((ext_vector_type(8))) short;
using f32x4v = __attribute__((ext_vector_type(4))) float;

__device__ __forceinline__ float bf2f(unsigned short u) {
  union { unsigned int i; float f; } x; x.i = ((unsigned int)u) << 16; return x.f;
}
__device__ __forceinline__ unsigned short f2bf(float f) {
  union { float f; unsigned int u; } x; x.f = f;
  unsigned int u = x.u;
  unsigned int r = (u + 0x7FFFu + ((u >> 16) & 1u)) >> 16;  // RNE
  return (unsigned short)r;
}

typedef const __attribute__((address_space(1))) unsigned int GU32;
typedef __attribute__((address_space(3))) unsigned int LU32;
__device__ __forceinline__ void gld_lds16(const void* g, void* l) {
  GU32* gp = (GU32*)(unsigned long long)(uintptr_t)g;
  LU32* lp = (LU32*)(unsigned int)(uintptr_t)l;  // flat-LDS low32 = LDS offset
  __builtin_amdgcn_global_load_lds(gp, lp, 16, 0, 0);
}
// counted VMEM wait — asm with "memory" clobber (compiler-level fence)
template <int N>
__device__ __forceinline__ void waitcnt_vm() {
  asm volatile("s_waitcnt vmcnt(%0)" ::"i"(N) : "memory");
}

// ---------------------------------------------------------------- cast fp32->bf16
__global__ __launch_bounds__(256) void cast_kernel(const float* __restrict__ in,
                                                   unsigned short* __restrict__ out, int n4) {
  int i = blockIdx.x * 256 + threadIdx.x;
  if (i >= n4) return;
  float4 v = ((const float4*)in)[i];
  ushort4 o;
  o.x = f2bf(v.x); o.y = f2bf(v.y); o.z = f2bf(v.z); o.w = f2bf(v.w);
  ((ushort4*)out)[i] = o;
}

// ------------------------------------------------- transpose W[K][N] -> WT[roff+N][K] bf16
// store phase writes 16 bf16 per thread as 2x uint4 (was 16x 2B scattered stores).
__global__ __launch_bounds__(256) void transpose_kernel(const float* __restrict__ W,
                                                        unsigned short* __restrict__ WT,
                                                        int K, int N, int ld, int roff) {
  __shared__ float tile[64][65];
  const int t = threadIdx.x;
  const int kb = blockIdx.y * 64, nb = blockIdx.x * 64;
  const int r = t >> 2, c0 = (t & 3) * 16;
#pragma unroll
  for (int i = 0; i < 16; ++i) {
    int c = c0 + i;
    float v = 0.f;
    if (nb + c < N) v = W[(size_t)(kb + r) * N + nb + c];
    tile[r][c] = v;
  }
  __syncthreads();
  const int bn = t >> 2, seg = (t & 3) * 16;
  if (nb + bn < N) {
    unsigned short tmp[16];
#pragma unroll
    for (int i = 0; i < 16; ++i) tmp[i] = f2bf(tile[seg + i][bn]);
    unsigned short* dst = WT + (size_t)(roff + nb + bn) * ld + kb + seg;
    *(uint4*)dst = *(const uint4*)&tmp[0];
    *(uint4*)(dst + 8) = *(const uint4*)&tmp[8];
  }
}

// ---------------------------------------------------------------- ring-5 pair-barrier GEMM (GEMM1)
// 512 threads = 8 waves (2M x 4N). BK=64 split into 2 ks-halves; 5 LDS regions of
// (BM+BN)*64 B (160 KB total). Pair q = phases {2q, 2q+1}:
//   {reads rA; stage (2q+3)->tA; MFMA A; reads rB; stage (2q+4)->tB; MFMA B;
//    vmcnt(4); barrier}  -- ONE barrier per two phases.
// Ledger (wave-uniform): read regions {p0,p0+1}%5, stage targets {p0+3,p0+4}%5 —
// distances 2..4 mod 5, no collision; targets last read in pair q-1 (freed by its
// barrier); vmcnt(4) leaves only S(2q+4) outstanding => contents 2q+2, 2q+3 proven.
// Swizzle (64B rows): o ^= ((o>>7)&3)<<4 ; staging source pre-swizzled (rule #21).
template <int BM, int BN, int OUT_BF16>
__global__ __launch_bounds__(512) void gemm_r5_kernel(const unsigned short* __restrict__ Ag,
                                                      const unsigned short* __restrict__ Bg,
                                                      void* __restrict__ Cg, int M, int N, int K) {
  constexpr int PM = BM / 2, PN = BN / 4;
  constexpr int MT = PM / 16, NTF = PN / 16;
  constexpr int NA = BM / 128, NB = BN / 128;
  constexpr int LPS = NA + NB;              // loads per stage (4)
  constexpr int REG = (BM + BN) * 64;       // bytes per region (32 KB)
  extern __shared__ char lds[];
  const int t = threadIdx.x;
  const int lane = t & 63, wid = t >> 6;
  const int wm = wid >> 2, wn = wid & 3;
  const int rlo = lane & 15, khi = lane >> 4;

  const int gx = gridDim.x, nwg = gx * gridDim.y;
  int id = blockIdx.y * gx + blockIdx.x;
  int sid = (id & 7) * (nwg >> 3) + (id >> 3);
  const int m0 = (sid / gx) * BM, n0 = (sid % gx) * BN;

  const int NT = K >> 6;
  const int NPH = NT * 2;                   // even

  const int srow = t >> 2;
  const int scs = ((t & 3) * 16) ^ (((t >> 3) & 3) << 4);
  const char* Ap[NA];
  const char* Bp[NB];
#pragma unroll
  for (int i = 0; i < NA; ++i)
    Ap[i] = (const char*)Ag + (size_t)(m0 + i * 128 + srow) * K * 2 + scs;
#pragma unroll
  for (int i = 0; i < NB; ++i)
    Bp[i] = (const char*)Bg + (size_t)(n0 + i * 128 + srow) * K * 2 + scs;
  char* dst = lds + t * 16;

  int offA[MT], offB[NTF];
#pragma unroll
  for (int mi = 0; mi < MT; ++mi) {
    int o = (wm * PM + mi * 16 + rlo) * 64 + khi * 16;
    o ^= ((o >> 7) & 3) << 4;
    offA[mi] = o;
  }
#pragma unroll
  for (int ni = 0; ni < NTF; ++ni) {
    int o = (wn * PN + ni * 16 + rlo) * 64 + khi * 16;
    o ^= ((o >> 7) & 3) << 4;
    offB[ni] = o + BM * 64;
  }

  f32x4v acc[MT][NTF];
#pragma unroll
  for (int mi = 0; mi < MT; ++mi)
#pragma unroll
    for (int ni = 0; ni < NTF; ++ni) acc[mi][ni] = (f32x4v){0.f, 0.f, 0.f, 0.f};

#define STG(PS, R)                                                           \
  do {                                                                       \
    int kts_ = ((PS) >> 1 < NT) ? ((PS) >> 1) : NT - 1;                      \
    size_t co_ = (size_t)kts_ * 128 + (size_t)((PS) & 1) * 64;               \
    char* d_ = dst + (size_t)(R) * REG;                                      \
    _Pragma("unroll") for (int i_ = 0; i_ < NA; ++i_)                        \
        gld_lds16(Ap[i_] + co_, d_ + i_ * 8192);                             \
    _Pragma("unroll") for (int i_ = 0; i_ < NB; ++i_)                        \
        gld_lds16(Bp[i_] + co_, d_ + BM * 64 + i_ * 8192);                   \
  } while (0)

  // prologue: contents 0,1,2 -> regions 0,1,2 ; contents 0,1 proven
  STG(0, 0); STG(1, 1); STG(2, 2);
  waitcnt_vm<LPS>();
  __builtin_amdgcn_s_barrier();
  __builtin_amdgcn_sched_barrier(0);

  int rA = 0;
#pragma unroll 1
  for (int q = 0; q < NPH / 2; ++q) {
    const int p0 = q * 2;
    int rB = rA + 1; if (rB >= 5) rB -= 5;
    int tA = rA + 3; if (tA >= 5) tA -= 5;
    int tB = rA + 4; if (tB >= 5) tB -= 5;

    // phase A
    {
      const char* rb = lds + (size_t)rA * REG;
      bf16x8 af[MT], bv[NTF];
#pragma unroll
      for (int mi = 0; mi < MT; ++mi) af[mi] = *(const bf16x8*)(rb + offA[mi]);
#pragma unroll
      for (int ni = 0; ni < NTF; ++ni) bv[ni] = *(const bf16x8*)(rb + offB[ni]);
      STG(p0 + 3, tA);
      __builtin_amdgcn_s_setprio(1);
#pragma unroll
      for (int mi = 0; mi < MT; ++mi)
#pragma unroll
        for (int ni = 0; ni < NTF; ++ni)
          acc[mi][ni] = __builtin_amdgcn_mfma_f32_16x16x32_bf16(af[mi], bv[ni], acc[mi][ni], 0, 0, 0);
      __builtin_amdgcn_s_setprio(0);
    }
    // phase B
    {
      const char* rb = lds + (size_t)rB * REG;
      bf16x8 af[MT], bv[NTF];
#pragma unroll
      for (int mi = 0; mi < MT; ++mi) af[mi] = *(const bf16x8*)(rb + offA[mi]);
#pragma unroll
      for (int ni = 0; ni < NTF; ++ni) bv[ni] = *(const bf16x8*)(rb + offB[ni]);
      STG(p0 + 4, tB);
      __builtin_amdgcn_s_setprio(1);
#pragma unroll
      for (int mi = 0; mi < MT; ++mi)
#pragma unroll
        for (int ni = 0; ni < NTF; ++ni)
          acc[mi][ni] = __builtin_amdgcn_mfma_f32_16x16x32_bf16(af[mi], bv[ni], acc[mi][ni], 0, 0, 0);
      __builtin_amdgcn_s_setprio(0);
    }
    waitcnt_vm<LPS>();
    __builtin_amdgcn_s_barrier();
    __builtin_amdgcn_sched_barrier(0);
    rA += 2; if (rA >= 5) rA -= 5;
  }
#undef STG
  waitcnt_vm<0>();

  const int mrb = khi * 4;
#pragma unroll
  for (int mi = 0; mi < MT; ++mi)
#pragma unroll
    for (int ni = 0; ni < NTF; ++ni)
#pragma unroll
      for (int r = 0; r < 4; ++r) {
        int mm = m0 + wm * PM + mi * 16 + mrb + r;
        int nn = n0 + wn * PN + ni * 16 + rlo;
        float v = acc[mi][ni][r];
        if (OUT_BF16) ((unsigned short*)Cg)[(size_t)mm * N + nn] = f2bf(v);
        else          ((float*)Cg)[(size_t)mm * N + nn] = v;
      }
}

// ---------------------------------------------------------------- K-split ring-4 GEMM (GEMM2)
template <int BM, int BN, int OUT_BF16>
__global__ __launch_bounds__(512) void gemm_ks_kernel(const unsigned short* __restrict__ Ag,
                                                      const unsigned short* __restrict__ Bg,
                                                      void* __restrict__ Cg, int M, int N, int K) {
  constexpr int PM = BM / 2, PN = BN / 4;
  constexpr int MT = PM / 16, NTF = PN / 16;
  constexpr int NA = BM / 128, NB = BN / 128;
  constexpr int LPS = NA + NB;
  constexpr int REG = (BM + BN) * 64;
  extern __shared__ char lds[];
  const int t = threadIdx.x;
  const int lane = t & 63, wid = t >> 6;
  const int wm = wid >> 2, wn = wid & 3;
  const int rlo = lane & 15, khi = lane >> 4;

  const int gx = gridDim.x, nwg = gx * gridDim.y;
  int id = blockIdx.y * gx + blockIdx.x;
  int sid = (id & 7) * (nwg >> 3) + (id >> 3);
  const int m0 = (sid / gx) * BM, n0 = (sid % gx) * BN;

  const int NT = K >> 6;
  const int NPH = NT * 2;

  const int srow = t >> 2;
  const int scs = ((t & 3) * 16) ^ (((t >> 3) & 3) << 4);
  const char* Ap[NA];
  const char* Bp[NB];
#pragma unroll
  for (int i = 0; i < NA; ++i)
    Ap[i] = (const char*)Ag + (size_t)(m0 + i * 128 + srow) * K * 2 + scs;
#pragma unroll
  for (int i = 0; i < NB; ++i)
    Bp[i] = (const char*)Bg + (size_t)(n0 + i * 128 + srow) * K * 2 + scs;
  char* dst = lds + t * 16;

  int offA[MT], offB[NTF];
#pragma unroll
  for (int mi = 0; mi < MT; ++mi) {
    int o = (wm * PM + mi * 16 + rlo) * 64 + khi * 16;
    o ^= ((o >> 7) & 3) << 4;
    offA[mi] = o;
  }
#pragma unroll
  for (int ni = 0; ni < NTF; ++ni) {
    int o = (wn * PN + ni * 16 + rlo) * 64 + khi * 16;
    o ^= ((o >> 7) & 3) << 4;
    offB[ni] = o + BM * 64;
  }

  f32x4v acc[MT][NTF];
#pragma unroll
  for (int mi = 0; mi < MT; ++mi)
#pragma unroll
    for (int ni = 0; ni < NTF; ++ni) acc[mi][ni] = (f32x4v){0.f, 0.f, 0.f, 0.f};

#define STG(PS)                                                              \
  do {                                                                       \
    int kts_ = ((PS) >> 1 < NT) ? ((PS) >> 1) : NT - 1;                      \
    size_t co_ = (size_t)kts_ * 128 + (size_t)((PS) & 1) * 64;               \
    char* d_ = dst + (((PS) & 3) * REG);                                     \
    _Pragma("unroll") for (int i_ = 0; i_ < NA; ++i_)                        \
        gld_lds16(Ap[i_] + co_, d_ + i_ * 8192);                             \
    _Pragma("unroll") for (int i_ = 0; i_ < NB; ++i_)                        \
        gld_lds16(Bp[i_] + co_, d_ + BM * 64 + i_ * 8192);                   \
  } while (0)

  STG(0); STG(1); STG(2);
  waitcnt_vm<2 * LPS>();
  __builtin_amdgcn_s_barrier();
  __builtin_amdgcn_sched_barrier(0);

#pragma unroll 1
  for (int p = 0; p < NPH; ++p) {
    const char* rb = lds + (p & 3) * REG;
    bf16x8 af[MT], bv[NTF];
#pragma unroll
    for (int mi = 0; mi < MT; ++mi) af[mi] = *(const bf16x8*)(rb + offA[mi]);
#pragma unroll
    for (int ni = 0; ni < NTF; ++ni) bv[ni] = *(const bf16x8*)(rb + offB[ni]);
    STG(p + 3);
    __builtin_amdgcn_s_setprio(1);
#pragma unroll
    for (int mi = 0; mi < MT; ++mi)
#pragma unroll
      for (int ni = 0; ni < NTF; ++ni)
        acc[mi][ni] = __builtin_amdgcn_mfma_f32_16x16x32_bf16(af[mi], bv[ni], acc[mi][ni], 0, 0, 0);
    __builtin_amdgcn_s_setprio(0);
    waitcnt_vm<2 * LPS>();
    __builtin_amdgcn_s_barrier();
    __builtin_amdgcn_sched_barrier(0);
  }
#undef STG
  waitcnt_vm<0>();

  const int mrb = khi * 4;
#pragma unroll
  for (int mi = 0; mi < MT; ++mi)
#pragma unroll
    for (int ni = 0; ni < NTF; ++ni)
#pragma unroll
      for (int r = 0; r < 4; ++r) {
        int mm = m0 + wm * PM + mi * 16 + mrb + r;
        int nn = n0 + wn * PN + ni * 16 + rlo;
        float v = acc[mi][ni][r];
        if (OUT_BF16) ((unsigned short*)Cg)[(size_t)mm * N + nn] = f2bf(v);
        else          ((float*)Cg)[(size_t)mm * N + nn] = v;
      }
}

// ---------------------------------------------------------------- causal conv K=4 + SiLU
// 8-row sliding window per thread: 11 loads per 8 outputs (re-read 1.375x vs 4x).
__global__ __launch_bounds__(256) void conv_silu_kernel(const unsigned short* __restrict__ C1,
                                                        const float* __restrict__ conv_w,
                                                        unsigned short* __restrict__ QKV) {
  int idx = blockIdx.x * 256 + threadIdx.x;       // (ROWS/8) * 2048
  int nb = idx >> 11;
  int c4 = (idx & 2047) << 2;
  int row0 = nb * 8;
  int s0 = row0 & 2047;
  float4 w0 = *(const float4*)(conv_w + (size_t)(c4 + 0) * 4);
  float4 w1 = *(const float4*)(conv_w + (size_t)(c4 + 1) * 4);
  float4 w2 = *(const float4*)(conv_w + (size_t)(c4 + 2) * 4);
  float4 w3 = *(const float4*)(conv_w + (size_t)(c4 + 3) * 4);
  const float* pw0 = (const float*)&w0;
  const float* pw1 = (const float*)&w1;
  const float* pw2 = (const float*)&w2;
  const float* pw3 = (const float*)&w3;
  ushort4 rw[11];
#pragma unroll
  for (int i = 0; i < 11; ++i) {
    if (s0 + i >= 3) rw[i] = *(const ushort4*)(C1 + (size_t)(row0 - 3 + i) * NWP + c4);
    else { rw[i].x = 0; rw[i].y = 0; rw[i].z = 0; rw[i].w = 0; }
  }
#pragma unroll
  for (int j = 0; j < 8; ++j) {
    float a0 = 0.f, a1 = 0.f, a2 = 0.f, a3 = 0.f;
#pragma unroll
    for (int jj = 0; jj < 4; ++jj) {
      ushort4 mv = rw[j + jj];
      a0 += bf2f(mv.x) * pw0[jj];
      a1 += bf2f(mv.y) * pw1[jj];
      a2 += bf2f(mv.z) * pw2[jj];
      a3 += bf2f(mv.w) * pw3[jj];
    }
    ushort4 o;
    o.x = f2bf(a0 / (1.f + __expf(-a0)));
    o.y = f2bf(a1 / (1.f + __expf(-a1)));
    o.z = f2bf(a2 / (1.f + __expf(-a2)));
    o.w = f2bf(a3 / (1.f + __expf(-a3)));
    *(ushort4*)(QKV + (size_t)(row0 + j) * CONVD + c4) = o;
  }
}

// ---------------------------------------------------------------- beta / g
__global__ __launch_bounds__(256) void gbeta_kernel(const unsigned short* __restrict__ C1,
                                                    const float* __restrict__ dt_bias,
                                                    const float* __restrict__ A_log,
                                                    float* __restrict__ G, float* __restrict__ BETA) {
  int idx = blockIdx.x * 256 + threadIdx.x;
  int row = idx >> 5, h = idx & 31;
  float bp = bf2f(C1[(size_t)row * NWP + 12288 + h]);
  float ap = bf2f(C1[(size_t)row * NWP + 12320 + h]);
  BETA[idx] = 1.f / (1.f + __expf(-bp));
  float x = ap + dt_bias[h];
  float sp = (x > 15.f) ? x : log1pf(__expf(x));
  G[idx] = -__expf(A_log[h]) * sp;
}

// ---------------------------------------------------------------- INTRA: per-chunk solve
#define INTRA_SMEM 70144
__global__ __launch_bounds__(256) void intra_kernel(const unsigned short* __restrict__ QKV,
                                                    const float* __restrict__ G,
                                                    const float* __restrict__ BETA,
                                                    unsigned short* __restrict__ WU,
                                                    unsigned short* __restrict__ ATTN) {
  extern __shared__ char smem[];
  unsigned short* ktb = (unsigned short*)smem;        // [64][136]
  float* Amat = (float*)(smem + 17408);               // [64][68]
  float* Xt   = (float*)(smem + 34816);               // [128][68]
  unsigned short* qb = (unsigned short*)Xt;           // [64][136] alias
  float* gc  = (float*)(smem + 69632);                // [64]
  float* bet = gc + 64;                               // [64]

  const int t = threadIdx.x;
  const int lane = t & 63, w = t >> 6;
  const int rlo = lane & 15, khi = lane >> 4;
  const int cix = blockIdx.x & 31;
  const int h = (blockIdx.x >> 5) & 31;
  const int b = blockIdx.x >> 10;
  const int hq = h >> 1;
  const int row0 = cix * 64;
  const size_t rowbase = (size_t)b * SEQ;

  if (t < 64) {
    float gv = G[(rowbase + row0 + t) * NUMV + h];
    bet[t] = BETA[(rowbase + row0 + t) * NUMV + h];
#pragma unroll
    for (int off = 1; off < 64; off <<= 1) {
      float u = __shfl_up(gv, off, 64);
      if (t >= off) gv += u;
    }
    gc[t] = gv;
  }
  __syncthreads();

  const int r = t >> 2, q4 = t & 3;
  const size_t grow = (rowbase + row0 + r) * (size_t)CONVD;

  {
    const unsigned short* kp = QKV + grow + 2048 + hq * 128 + q4 * 32;
    float kv[32]; float ssk = 0.f;
#pragma unroll
    for (int j = 0; j < 32; j += 4) {
      ushort4 km = *(const ushort4*)(kp + j);
      kv[j] = bf2f(km.x); kv[j + 1] = bf2f(km.y); kv[j + 2] = bf2f(km.z); kv[j + 3] = bf2f(km.w);
      ssk += kv[j]*kv[j] + kv[j+1]*kv[j+1] + kv[j+2]*kv[j+2] + kv[j+3]*kv[j+3];
    }
    ssk += __shfl_xor(ssk, 1, 64);
    ssk += __shfl_xor(ssk, 2, 64);
    const float rk = rsqrtf(ssk + 1e-6f);
    const float ekr = __expf(gc[r]) * bet[r];
#pragma unroll
    for (int j = 0; j < 32; ++j) {
      float kn = kv[j] * rk;
      ktb[r * 136 + q4 * 32 + j] = f2bf(kn);
      Xt[(q4 * 32 + j) * 68 + r] = kn * ekr;
    }
  }
  __syncthreads();

  float xr[64];

  {
    static const signed char SJ[10][2] = {{0,0},{1,0},{1,1},{2,0},{2,1},{2,2},{3,0},{3,1},{3,2},{3,3}};
    static const signed char SB[5] = {0, 4, 7, 9, 10};
    for (int sj = SB[w]; sj < SB[w + 1]; ++sj) {
      const int mt = SJ[sj][0], nt = SJ[sj][1];
      f32x4v acc = (f32x4v){0.f, 0.f, 0.f, 0.f};
#pragma unroll
      for (int ks = 0; ks < 4; ++ks) {
        bf16x8 af = *(const bf16x8*)&ktb[(mt * 16 + rlo) * 136 + ks * 32 + khi * 8];
        bf16x8 bf_ = *(const bf16x8*)&ktb[(nt * 16 + rlo) * 136 + ks * 32 + khi * 8];
        acc = __builtin_amdgcn_mfma_f32_16x16x32_bf16(af, bf_, acc, 0, 0, 0);
      }
      const int j = nt * 16 + rlo;
#pragma unroll
      for (int r2 = 0; r2 < 4; ++r2) {
        const int i = mt * 16 + khi * 4 + r2;
        if (j < i) Amat[i * 68 + j] = -bet[i] * __expf(gc[i] - gc[j]) * acc[r2];
      }
    }
    if (t < 128) {
      const float* Xc = Xt + t * 68;
#pragma unroll
      for (int j = 0; j < 64; j += 4) {
        f32x4v xv = *(const f32x4v*)(Xc + j);
        xr[j] = xv[0]; xr[j + 1] = xv[1]; xr[j + 2] = xv[2]; xr[j + 3] = xv[3];
      }
    }
  }
  __syncthreads();

  {
    const unsigned short* vp = QKV + grow + 4096 + h * 128 + q4 * 32;
    const float brow = bet[r];
#pragma unroll
    for (int j = 0; j < 32; j += 4) {
      ushort4 vm = *(const ushort4*)(vp + j);
      Xt[(q4 * 32 + j + 0) * 68 + r] = bf2f(vm.x) * brow;
      Xt[(q4 * 32 + j + 1) * 68 + r] = bf2f(vm.y) * brow;
      Xt[(q4 * 32 + j + 2) * 68 + r] = bf2f(vm.z) * brow;
      Xt[(q4 * 32 + j + 3) * 68 + r] = bf2f(vm.w) * brow;
    }
  }
  __syncthreads();
  if (t >= 128) {
    const float* Xc = Xt + (t - 128) * 68;
#pragma unroll
    for (int j = 0; j < 64; j += 4) {
      f32x4v xv = *(const f32x4v*)(Xc + j);
      xr[j] = xv[0]; xr[j + 1] = xv[1]; xr[j + 2] = xv[2]; xr[j + 3] = xv[3];
    }
  }
  __syncthreads();

#pragma unroll
  for (int ib = 0; ib < 8; ++ib) {
    const int i0 = ib * 8;
    float p[8] = {0, 0, 0, 0, 0, 0, 0, 0};
#pragma unroll
    for (int j = 0; j < i0; j += 4) {
#pragma unroll
      for (int r2 = 0; r2 < 8; ++r2) {
        f32x4v ar = *(const f32x4v*)&Amat[(i0 + r2) * 68 + j];
        p[r2] += ar[0] * xr[j] + ar[1] * xr[j + 1] + ar[2] * xr[j + 2] + ar[3] * xr[j + 3];
      }
    }
#pragma unroll
    for (int r2 = 0; r2 < 8; ++r2) {
      float v = xr[i0 + r2] + p[r2];
#pragma unroll
      for (int r3 = 0; r3 < r2; ++r3) v += Amat[(i0 + r2) * 68 + i0 + r3] * xr[i0 + r3];
      xr[i0 + r2] = v;
    }
  }

  if (t < 128) {
    float* Xc = Xt + t * 68;
#pragma unroll
    for (int j = 0; j < 64; j += 4) {
      f32x4v xv = {xr[j], xr[j + 1], xr[j + 2], xr[j + 3]};
      *(f32x4v*)(Xc + j) = xv;
    }
  }
  __syncthreads();
  {
    unsigned short* wdst = WU + (rowbase + row0 + r) * (size_t)NWP + h * 128 + q4 * 32;
#pragma unroll
    for (int j = 0; j < 32; ++j) wdst[j] = f2bf(Xt[(q4 * 32 + j) * 68 + r]);
  }
  __syncthreads();
  if (t >= 128) {
    float* Xc = Xt + (t - 128) * 68;
#pragma unroll
    for (int j = 0; j < 64; j += 4) {
      f32x4v xv = {xr[j], xr[j + 1], xr[j + 2], xr[j + 3]};
      *(f32x4v*)(Xc + j) = xv;
    }
  }
  __syncthreads();
  {
    unsigned short* udst = WU + (rowbase + row0 + r) * (size_t)NWP + 4096 + h * 128 + q4 * 32;
#pragma unroll
    for (int j = 0; j < 32; ++j) udst[j] = f2bf(Xt[(q4 * 32 + j) * 68 + r]);
  }
  __syncthreads();

  {
    const unsigned short* qp = QKV + grow + hq * 128 + q4 * 32;
    float qv[32]; float ssq = 0.f;
#pragma unroll
    for (int j = 0; j < 32; j += 4) {
      ushort4 qm = *(const ushort4*)(qp + j);
      qv[j] = bf2f(qm.x); qv[j + 1] = bf2f(qm.y); qv[j + 2] = bf2f(qm.z); qv[j + 3] = bf2f(qm.w);
      ssq += qv[j]*qv[j] + qv[j+1]*qv[j+1] + qv[j+2]*qv[j+2] + qv[j+3]*qv[j+3];
    }
    ssq += __shfl_xor(ssq, 1, 64);
    ssq += __shfl_xor(ssq, 2, 64);
    const float rq = rsqrtf(ssq + 1e-6f) * 0.08838834764831845f;
#pragma unroll
    for (int j = 0; j < 32; ++j) qb[r * 136 + q4 * 32 + j] = f2bf(qv[j] * rq);
  }
  __syncthreads();

  {
    const size_t abase = (((size_t)b * 32 + h) * 32 + cix) * 4096;
#pragma unroll 1
    for (int nt = 0; nt < 4; ++nt) {
      const int j = nt * 16 + rlo;
      float vals[4] = {0.f, 0.f, 0.f, 0.f};
      if (nt <= w) {
        f32x4v acc = (f32x4v){0.f, 0.f, 0.f, 0.f};
#pragma unroll
        for (int ks = 0; ks < 4; ++ks) {
          bf16x8 af = *(const bf16x8*)&qb[(w * 16 + rlo) * 136 + ks * 32 + khi * 8];
          bf16x8 bf_ = *(const bf16x8*)&ktb[(nt * 16 + rlo) * 136 + ks * 32 + khi * 8];
          acc = __builtin_amdgcn_mfma_f32_16x16x32_bf16(af, bf_, acc, 0, 0, 0);
        }
#pragma unroll
        for (int r2 = 0; r2 < 4; ++r2) {
          const int i = w * 16 + khi * 4 + r2;
          if (j <= i) vals[r2] = __expf(gc[i] - gc[j]) * acc[r2];
        }
      }
#pragma unroll
      for (int r2 = 0; r2 < 4; ++r2)
        ATTN[abase + (w * 16 + khi * 4 + r2) * 64 + j] = f2bf(vals[r2]);
    }
  }
}

// ---------------------------------------------------------------- SEQ: state recurrence
#define SEQ_SMEM 70400
__global__ __launch_bounds__(256) void seq_kernel(const unsigned short* __restrict__ QKV,
                                                  const float* __restrict__ G,
                                                  const unsigned short* __restrict__ WU,
                                                  const unsigned short* __restrict__ ATTN,
                                                  unsigned short* __restrict__ CORE) {
  extern __shared__ char smem[];
  unsigned short* ktT    = (unsigned short*)smem;            // [128][88]
  unsigned short* wb     = (unsigned short*)(smem + 22528);  // [64][136]
  unsigned short* attnb  = (unsigned short*)(smem + 39936);  // [64][88]
  float* stateT          = (float*)(smem + 51200);           // [16][136]
  unsigned short* stateTb = (unsigned short*)(smem + 59904); // [16][136]
  unsigned short* vnTb   = (unsigned short*)(smem + 64256);  // [16][88]
  unsigned short* vdTb   = (unsigned short*)(smem + 67072);  // [16][88]
  float* gc   = (float*)(smem + 69888);                      // [64]
  float* edec = (float*)(smem + 70144);                      // [64]

  const int t = threadIdx.x;
  const int lane = t & 63, w = t >> 6;
  const int rlo = lane & 15, khi = lane >> 4;
  const int vq = blockIdx.x & 7;
  const int h = (blockIdx.x >> 3) & 31;
  const int b = blockIdx.x >> 8;
  const int hq = h >> 1;
  const size_t rowbase = (size_t)b * SEQ;
  const size_t ahead = ((size_t)b * 32 + h) * 32;

  for (int i = t; i < 16 * 136; i += 256) { stateT[i] = 0.f; stateTb[i] = 0; }
  __syncthreads();

  bf16x8 qf[4];

#pragma unroll 1
  for (int ncb = 0; ncb < 32; ++ncb) {
    const int row0 = ncb * 64;

    if (t < 64) {
      float gv = G[(rowbase + row0 + t) * NUMV + h];
#pragma unroll
      for (int off = 1; off < 64; off <<= 1) {
        float u = __shfl_up(gv, off, 64);
        if (t >= off) gv += u;
      }
      gc[t] = gv;
      float tot = __shfl(gv, 63, 64);
      edec[t] = __expf(tot - gv);
    }
    __syncthreads();

    {
      const int r = t >> 2, q4 = t & 3;
      const size_t grow = (rowbase + row0 + r) * (size_t)CONVD;
      const unsigned short* kp = QKV + grow + 2048 + hq * 128 + q4 * 32;
      float kv[32]; float ssk = 0.f;
#pragma unroll
      for (int j = 0; j < 32; j += 4) {
        ushort4 km = *(const ushort4*)(kp + j);
        kv[j] = bf2f(km.x); kv[j + 1] = bf2f(km.y); kv[j + 2] = bf2f(km.z); kv[j + 3] = bf2f(km.w);
        ssk += kv[j]*kv[j] + kv[j+1]*kv[j+1] + kv[j+2]*kv[j+2] + kv[j+3]*kv[j+3];
      }
      ssk += __shfl_xor(ssk, 1, 64);
      ssk += __shfl_xor(ssk, 2, 64);
      const float rk = rsqrtf(ssk + 1e-6f);
#pragma unroll
      for (int j = 0; j < 32; ++j) ktT[(q4 * 32 + j) * 88 + r] = f2bf(kv[j] * rk);
      const unsigned short* wsrc = WU + (rowbase + row0 + r) * (size_t)NWP + h * 128 + q4 * 32;
#pragma unroll
      for (int u2 = 0; u2 < 4; ++u2)
        *(uint4*)&wb[r * 136 + q4 * 32 + u2 * 8] = *(const uint4*)(wsrc + u2 * 8);
      const unsigned short* asrc = ATTN + (ahead + ncb) * 4096 + r * 64 + q4 * 16;
      *(uint4*)&attnb[r * 88 + q4 * 16] = *(const uint4*)(asrc);
      *(uint4*)&attnb[r * 88 + q4 * 16 + 8] = *(const uint4*)(asrc + 8);
      const unsigned short* qsrc = QKV + (rowbase + row0 + w * 16 + rlo) * (size_t)CONVD + hq * 128 + khi * 8;
      float qv[32]; float ssq = 0.f;
#pragma unroll
      for (int ks = 0; ks < 4; ++ks) {
        ushort4 qa = *(const ushort4*)(qsrc + ks * 32);
        ushort4 qb2 = *(const ushort4*)(qsrc + ks * 32 + 4);
        qv[ks*8+0] = bf2f(qa.x); qv[ks*8+1] = bf2f(qa.y); qv[ks*8+2] = bf2f(qa.z); qv[ks*8+3] = bf2f(qa.w);
        qv[ks*8+4] = bf2f(qb2.x); qv[ks*8+5] = bf2f(qb2.y); qv[ks*8+6] = bf2f(qb2.z); qv[ks*8+7] = bf2f(qb2.w);
#pragma unroll
        for (int e = 0; e < 8; ++e) ssq += qv[ks*8+e] * qv[ks*8+e];
      }
      ssq += __shfl_xor(ssq, 16, 64);
      ssq += __shfl_xor(ssq, 32, 64);
      const float rq = rsqrtf(ssq + 1e-6f) * 0.08838834764831845f;
#pragma unroll
      for (int ks = 0; ks < 4; ++ks) {
        bf16x8 tv;
#pragma unroll
        for (int e = 0; e < 8; ++e) tv[e] = (short)f2bf(qv[ks*8+e] * rq);
        qf[ks] = tv;
      }
    }
    __syncthreads();

    f32x4v oacc;
    {
      f32x4v pacc = (f32x4v){0.f, 0.f, 0.f, 0.f};
      oacc = (f32x4v){0.f, 0.f, 0.f, 0.f};
#pragma unroll
      for (int ks = 0; ks < 4; ++ks) {
        bf16x8 aw = *(const bf16x8*)&wb[(w * 16 + rlo) * 136 + ks * 32 + khi * 8];
        bf16x8 bs = *(const bf16x8*)&stateTb[rlo * 136 + ks * 32 + khi * 8];
        pacc = __builtin_amdgcn_mfma_f32_16x16x32_bf16(aw, bs, pacc, 0, 0, 0);
        oacc = __builtin_amdgcn_mfma_f32_16x16x32_bf16(qf[ks], bs, oacc, 0, 0, 0);
      }
#pragma unroll
      for (int r2 = 0; r2 < 4; ++r2) {
        const int i = w * 16 + khi * 4 + r2;
        float uv = bf2f(WU[(rowbase + row0 + i) * (size_t)NWP + 4096 + h * 128 + vq * 16 + rlo]);
        float vn = uv - pacc[r2];
        vnTb[rlo * 88 + i] = f2bf(vn);
        vdTb[rlo * 88 + i] = f2bf(vn * edec[i]);
        oacc[r2] *= __expf(gc[i]);
      }
    }
    __syncthreads();

    {
#pragma unroll
      for (int ks = 0; ks < 2; ++ks) {
        bf16x8 aa = *(const bf16x8*)&attnb[(w * 16 + rlo) * 88 + ks * 32 + khi * 8];
        bf16x8 bv = *(const bf16x8*)&vnTb[rlo * 88 + ks * 32 + khi * 8];
        oacc = __builtin_amdgcn_mfma_f32_16x16x32_bf16(aa, bv, oacc, 0, 0, 0);
      }
      const int col = h * 128 + vq * 16 + rlo;
#pragma unroll
      for (int r2 = 0; r2 < 4; ++r2) {
        const int i = w * 16 + khi * 4 + r2;
        CORE[(rowbase + row0 + i) * (size_t)4096 + col] = f2bf(oacc[r2]);
      }
      const float egl = __expf(gc[63]);
#pragma unroll
      for (int n2 = 0; n2 < 2; ++n2) {
        const int dt = w * 2 + n2;
        f32x4v sacc = (f32x4v){0.f, 0.f, 0.f, 0.f};
#pragma unroll
        for (int ks = 0; ks < 2; ++ks) {
          bf16x8 ak = *(const bf16x8*)&ktT[(dt * 16 + rlo) * 88 + ks * 32 + khi * 8];
          bf16x8 bv2 = *(const bf16x8*)&vdTb[rlo * 88 + ks * 32 + khi * 8];
          sacc = __builtin_amdgcn_mfma_f32_16x16x32_bf16(ak, bv2, sacc, 0, 0, 0);
        }
#pragma unroll
        for (int r2 = 0; r2 < 4; ++r2) {
          const int d = dt * 16 + khi * 4 + r2;
          float ns = stateT[rlo * 136 + d] * egl + sacc[r2];
          stateT[rlo * 136 + d] = ns;
          stateTb[rlo * 136 + d] = f2bf(ns);
        }
      }
    }
    __syncthreads();
  }
}

// ---------------------------------------------------------------- gate * silu(z) + RMS-norm
__global__ __launch_bounds__(256) void gatenorm_kernel(const unsigned short* __restrict__ CORE,
                                                       const unsigned short* __restrict__ C1,
                                                       const float* __restrict__ norm_w,
                                                       unsigned short* __restrict__ NRM) {
  const int wid = blockIdx.x * 4 + (threadIdx.x >> 6);
  const int lane = threadIdx.x & 63;
  const int row = wid >> 5, h = wid & 31;
  const int c = lane * 2;
  const size_t cidx = (size_t)row * 4096 + h * 128 + c;
  const size_t zidx = (size_t)row * NWP + 8192 + h * 128 + c;
  float g0 = bf2f(CORE[cidx]), g1 = bf2f(CORE[cidx + 1]);
  float z0 = bf2f(C1[zidx]), z1 = bf2f(C1[zidx + 1]);
  g0 *= z0 / (1.f + __expf(-z0));
  g1 *= z1 / (1.f + __expf(-z1));
  float ss = g0 * g0 + g1 * g1;
#pragma unroll
  for (int m = 1; m < 64; m <<= 1) ss += __shfl_xor(ss, m, 64);
  const float rr = rsqrtf(ss * (1.f / 128.f) + 1e-6f);
  unsigned int o = ((unsigned int)f2bf(g1 * rr * norm_w[c + 1]) << 16) | (unsigned int)f2bf(g0 * rr * norm_w[c]);
  *(unsigned int*)(NRM + cidx) = o;
}

// ---------------------------------------------------------------------------
extern "C" void kernel_launch(void* const* d_in, const int* in_sizes, int n_in,
                              void* d_out, int out_size, void* d_ws, size_t ws_size,
                              hipStream_t stream) {
  const float* hs      = (const float*)d_in[0];
  const float* W_qkv   = (const float*)d_in[1];
  const float* W_z     = (const float*)d_in[2];
  const float* W_b     = (const float*)d_in[3];
  const float* W_a     = (const float*)d_in[4];
  const float* conv_w  = (const float*)d_in[5];
  const float* dt_bias = (const float*)d_in[6];
  const float* A_log   = (const float*)d_in[7];
  const float* norm_w  = (const float*)d_in[8];
  const float* W_out   = (const float*)d_in[9];
  float* out = (float*)d_out;
  char* ws = (char*)d_ws;

  const size_t OFF_HSB = 0;                                     // hs bf16; later ATTN
  const size_t OFF_WT  = OFF_HSB + (size_t)ROWS * HIDN * 2;     // WT; later CORE
  const size_t OFF_WOT = OFF_WT + (size_t)NWP * HIDN * 2;
  const size_t OFF_C1  = OFF_WOT + (size_t)HIDN * 4096 * 2;     // C1; cols [0,8192) -> w,u after conv
  const size_t OFF_QKV = OFF_C1 + (size_t)ROWS * NWP * 2;       // QKV; later NRM
  const size_t OFF_G   = OFF_QKV + (size_t)ROWS * CONVD * 2;
  const size_t OFF_B   = OFF_G + (size_t)ROWS * NUMV * 4;

  unsigned short* hsb = (unsigned short*)(ws + OFF_HSB);
  unsigned short* WT  = (unsigned short*)(ws + OFF_WT);
  unsigned short* WoT = (unsigned short*)(ws + OFF_WOT);
  unsigned short* C1  = (unsigned short*)(ws + OFF_C1);
  unsigned short* QKV = (unsigned short*)(ws + OFF_QKV);
  float* Gb = (float*)(ws + OFF_G);
  float* Bb = (float*)(ws + OFF_B);
  unsigned short* ATTNb = (unsigned short*)(ws + OFF_HSB);
  unsigned short* COREb = (unsigned short*)(ws + OFF_WT);
  unsigned short* NRMb  = (unsigned short*)(ws + OFF_QKV);

  cast_kernel<<<ROWS * HIDN / 4 / 256, 256, 0, stream>>>(hs, hsb, ROWS * HIDN / 4);
  transpose_kernel<<<dim3(8192 / 64, 2048 / 64), 256, 0, stream>>>(W_qkv, WT, 2048, 8192, HIDN, 0);
  transpose_kernel<<<dim3(4096 / 64, 2048 / 64), 256, 0, stream>>>(W_z, WT, 2048, 4096, HIDN, 8192);
  transpose_kernel<<<dim3(1, 2048 / 64), 256, 0, stream>>>(W_b, WT, 2048, 32, HIDN, 12288);
  transpose_kernel<<<dim3(1, 2048 / 64), 256, 0, stream>>>(W_a, WT, 2048, 32, HIDN, 12320);
  hipMemsetAsync(ws + OFF_WT + (size_t)12352 * HIDN * 2, 0, (size_t)192 * HIDN * 2, stream);
  transpose_kernel<<<dim3(2048 / 64, 4096 / 64), 256, 0, stream>>>(W_out, WoT, 4096, 2048, 4096, 0);

  void (*g1p)(const unsigned short*, const unsigned short*, void*, int, int, int) = gemm_r5_kernel<256, 256, 1>;
  void (*g0p)(const unsigned short*, const unsigned short*, void*, int, int, int) = gemm_ks_kernel<128, 256, 0>;
  hipFuncSetAttribute((const void*)g1p, hipFuncAttributeMaxDynamicSharedMemorySize, 5 * (256 + 256) * 64);
  hipFuncSetAttribute((const void*)g0p, hipFuncAttributeMaxDynamicSharedMemorySize, 4 * (128 + 256) * 64);

  gemm_r5_kernel<256, 256, 1><<<dim3(NWP / 256, ROWS / 256), 512, 5 * (256 + 256) * 64, stream>>>(
      hsb, WT, C1, ROWS, NWP, HIDN);
  conv_silu_kernel<<<(ROWS / 8) * 2048 / 256, 256, 0, stream>>>(C1, conv_w, QKV);
  gbeta_kernel<<<ROWS * NUMV / 256, 256, 0, stream>>>(C1, dt_bias, A_log, Gb, Bb);

  hipFuncSetAttribute((const void*)intra_kernel, hipFuncAttributeMaxDynamicSharedMemorySize,
                      INTRA_SMEM);
  intra_kernel<<<2048, 256, INTRA_SMEM, stream>>>(QKV, Gb, Bb, C1, ATTNb);

  hipFuncSetAttribute((const void*)seq_kernel, hipFuncAttributeMaxDynamicSharedMemorySize,
                      SEQ_SMEM);
  seq_kernel<<<512, 256, SEQ_SMEM, stream>>>(QKV, Gb, C1, ATTNb, COREb);

  gatenorm_kernel<<<ROWS * NUMV / 4, 256, 0, stream>>>(COREb, C1, norm_w, NRMb);
  gemm_ks_kernel<128, 256, 0><<<dim3(2048 / 256, ROWS / 128), 512, 4 * (128 + 256) * 64, stream>>>(
      NRMb, WoT, out, ROWS, 2048, 4096);
}

// Round 13
// 739.495 us; speedup vs baseline: 1.2296x; 1.0007x over previous
//
#include <hip/hip_runtime.h>
#include <cstdint>
#include <cstddef>

// ---------------------------------------------------------------------------
// GatedDeltaNet forward, MI355X/gfx950.
//  1. cast hs -> bf16 ; transpose weights -> bf16 [N][K] (16B stores)
//  2. GEMM1 = gemm_r5<256,256> (K-split, ring-5 regions, barrier per 2 phases)
//  3. causal conv(K=4)+SiLU (8-row sliding window) ; beta/g
//  4. INTRA: A build + register dual solve; wave-balanced {3,3,2,2} MFMA jobs
//  5. SEQ: state recurrence, MFMA, wave-local g-scan (3 barriers/chunk)
//  6. gate + RMS-norm ; GEMM2 = gemm_r5<128,256> (pair-barrier)
// ---------------------------------------------------------------------------

#define ROWS  4096
#define SEQ   2048
#define HIDN  2048
#define CONVD 8192
#define NWP   12544     // 8192 qkv + 4096 z + 32 b + 32 a + 192 pad (49*256)
#define NUMV  32

using bf16x8 = __attribute__((ext_vector_type(8))) short;
using f32x4v = __attribute__((ext_vector_type(4))) float;

__device__ __forceinline__ float bf2f(unsigned short u) {
  union { unsigned int i; float f; } x; x.i = ((unsigned int)u) << 16; return x.f;
}
__device__ __forceinline__ unsigned short f2bf(float f) {
  union { float f; unsigned int u; } x; x.f = f;
  unsigned int u = x.u;
  unsigned int r = (u + 0x7FFFu + ((u >> 16) & 1u)) >> 16;  // RNE
  return (unsigned short)r;
}

typedef const __attribute__((address_space(1))) unsigned int GU32;
typedef __attribute__((address_space(3))) unsigned int LU32;
__device__ __forceinline__ void gld_lds16(const void* g, void* l) {
  GU32* gp = (GU32*)(unsigned long long)(uintptr_t)g;
  LU32* lp = (LU32*)(unsigned int)(uintptr_t)l;  // flat-LDS low32 = LDS offset
  __builtin_amdgcn_global_load_lds(gp, lp, 16, 0, 0);
}
// counted VMEM wait — asm with "memory" clobber (compiler-level fence)
template <int N>
__device__ __forceinline__ void waitcnt_vm() {
  asm volatile("s_waitcnt vmcnt(%0)" ::"i"(N) : "memory");
}

// ---------------------------------------------------------------- cast fp32->bf16
__global__ __launch_bounds__(256) void cast_kernel(const float* __restrict__ in,
                                                   unsigned short* __restrict__ out, int n4) {
  int i = blockIdx.x * 256 + threadIdx.x;
  if (i >= n4) return;
  float4 v = ((const float4*)in)[i];
  ushort4 o;
  o.x = f2bf(v.x); o.y = f2bf(v.y); o.z = f2bf(v.z); o.w = f2bf(v.w);
  ((ushort4*)out)[i] = o;
}

// ------------------------------------------------- transpose W[K][N] -> WT[roff+N][K] bf16
__global__ __launch_bounds__(256) void transpose_kernel(const float* __restrict__ W,
                                                        unsigned short* __restrict__ WT,
                                                        int K, int N, int ld, int roff) {
  __shared__ float tile[64][65];
  const int t = threadIdx.x;
  const int kb = blockIdx.y * 64, nb = blockIdx.x * 64;
  const int r = t >> 2, c0 = (t & 3) * 16;
#pragma unroll
  for (int i = 0; i < 16; ++i) {
    int c = c0 + i;
    float v = 0.f;
    if (nb + c < N) v = W[(size_t)(kb + r) * N + nb + c];
    tile[r][c] = v;
  }
  __syncthreads();
  const int bn = t >> 2, seg = (t & 3) * 16;
  if (nb + bn < N) {
    unsigned short tmp[16];
#pragma unroll
    for (int i = 0; i < 16; ++i) tmp[i] = f2bf(tile[seg + i][bn]);
    unsigned short* dst = WT + (size_t)(roff + nb + bn) * ld + kb + seg;
    *(uint4*)dst = *(const uint4*)&tmp[0];
    *(uint4*)(dst + 8) = *(const uint4*)&tmp[8];
  }
}

// ---------------------------------------------------------------- ring-5 pair-barrier GEMM
// 512 threads = 8 waves (2M x 4N). BK=64 split into 2 ks-halves; 5 LDS regions of
// (BM+BN)*64 B. Pair q = phases {2q,2q+1}: {reads rA; stage 2q+3->tA; MFMA A;
// reads rB; stage 2q+4->tB; MFMA B; vmcnt(LPS); barrier}. Wave-uniform ledger
// (R10/R12-proven). Swizzle (64B rows): o ^= ((o>>7)&3)<<4, src pre-swizzled.
template <int BM, int BN, int OUT_BF16>
__global__ __launch_bounds__(512) void gemm_r5_kernel(const unsigned short* __restrict__ Ag,
                                                      const unsigned short* __restrict__ Bg,
                                                      void* __restrict__ Cg, int M, int N, int K) {
  constexpr int PM = BM / 2, PN = BN / 4;
  constexpr int MT = PM / 16, NTF = PN / 16;
  constexpr int NA = BM / 128, NB = BN / 128;
  constexpr int LPS = NA + NB;
  constexpr int REG = (BM + BN) * 64;
  extern __shared__ char lds[];
  const int t = threadIdx.x;
  const int lane = t & 63, wid = t >> 6;
  const int wm = wid >> 2, wn = wid & 3;
  const int rlo = lane & 15, khi = lane >> 4;

  const int gx = gridDim.x, nwg = gx * gridDim.y;
  int id = blockIdx.y * gx + blockIdx.x;
  int sid = (id & 7) * (nwg >> 3) + (id >> 3);
  const int m0 = (sid / gx) * BM, n0 = (sid % gx) * BN;

  const int NT = K >> 6;
  const int NPH = NT * 2;

  const int srow = t >> 2;
  const int scs = ((t & 3) * 16) ^ (((t >> 3) & 3) << 4);
  const char* Ap[NA];
  const char* Bp[NB];
#pragma unroll
  for (int i = 0; i < NA; ++i)
    Ap[i] = (const char*)Ag + (size_t)(m0 + i * 128 + srow) * K * 2 + scs;
#pragma unroll
  for (int i = 0; i < NB; ++i)
    Bp[i] = (const char*)Bg + (size_t)(n0 + i * 128 + srow) * K * 2 + scs;
  char* dst = lds + t * 16;

  int offA[MT], offB[NTF];
#pragma unroll
  for (int mi = 0; mi < MT; ++mi) {
    int o = (wm * PM + mi * 16 + rlo) * 64 + khi * 16;
    o ^= ((o >> 7) & 3) << 4;
    offA[mi] = o;
  }
#pragma unroll
  for (int ni = 0; ni < NTF; ++ni) {
    int o = (wn * PN + ni * 16 + rlo) * 64 + khi * 16;
    o ^= ((o >> 7) & 3) << 4;
    offB[ni] = o + BM * 64;
  }

  f32x4v acc[MT][NTF];
#pragma unroll
  for (int mi = 0; mi < MT; ++mi)
#pragma unroll
    for (int ni = 0; ni < NTF; ++ni) acc[mi][ni] = (f32x4v){0.f, 0.f, 0.f, 0.f};

#define STG(PS, R)                                                           \
  do {                                                                       \
    int kts_ = ((PS) >> 1 < NT) ? ((PS) >> 1) : NT - 1;                      \
    size_t co_ = (size_t)kts_ * 128 + (size_t)((PS) & 1) * 64;               \
    char* d_ = dst + (size_t)(R) * REG;                                      \
    _Pragma("unroll") for (int i_ = 0; i_ < NA; ++i_)                        \
        gld_lds16(Ap[i_] + co_, d_ + i_ * 8192);                             \
    _Pragma("unroll") for (int i_ = 0; i_ < NB; ++i_)                        \
        gld_lds16(Bp[i_] + co_, d_ + BM * 64 + i_ * 8192);                   \
  } while (0)

  STG(0, 0); STG(1, 1); STG(2, 2);
  waitcnt_vm<LPS>();
  __builtin_amdgcn_s_barrier();
  __builtin_amdgcn_sched_barrier(0);

  int rA = 0;
#pragma unroll 1
  for (int q = 0; q < NPH / 2; ++q) {
    const int p0 = q * 2;
    int rB = rA + 1; if (rB >= 5) rB -= 5;
    int tA = rA + 3; if (tA >= 5) tA -= 5;
    int tB = rA + 4; if (tB >= 5) tB -= 5;

    {
      const char* rb = lds + (size_t)rA * REG;
      bf16x8 af[MT], bv[NTF];
#pragma unroll
      for (int mi = 0; mi < MT; ++mi) af[mi] = *(const bf16x8*)(rb + offA[mi]);
#pragma unroll
      for (int ni = 0; ni < NTF; ++ni) bv[ni] = *(const bf16x8*)(rb + offB[ni]);
      STG(p0 + 3, tA);
      __builtin_amdgcn_s_setprio(1);
#pragma unroll
      for (int mi = 0; mi < MT; ++mi)
#pragma unroll
        for (int ni = 0; ni < NTF; ++ni)
          acc[mi][ni] = __builtin_amdgcn_mfma_f32_16x16x32_bf16(af[mi], bv[ni], acc[mi][ni], 0, 0, 0);
      __builtin_amdgcn_s_setprio(0);
    }
    {
      const char* rb = lds + (size_t)rB * REG;
      bf16x8 af[MT], bv[NTF];
#pragma unroll
      for (int mi = 0; mi < MT; ++mi) af[mi] = *(const bf16x8*)(rb + offA[mi]);
#pragma unroll
      for (int ni = 0; ni < NTF; ++ni) bv[ni] = *(const bf16x8*)(rb + offB[ni]);
      STG(p0 + 4, tB);
      __builtin_amdgcn_s_setprio(1);
#pragma unroll
      for (int mi = 0; mi < MT; ++mi)
#pragma unroll
        for (int ni = 0; ni < NTF; ++ni)
          acc[mi][ni] = __builtin_amdgcn_mfma_f32_16x16x32_bf16(af[mi], bv[ni], acc[mi][ni], 0, 0, 0);
      __builtin_amdgcn_s_setprio(0);
    }
    waitcnt_vm<LPS>();
    __builtin_amdgcn_s_barrier();
    __builtin_amdgcn_sched_barrier(0);
    rA += 2; if (rA >= 5) rA -= 5;
  }
#undef STG
  waitcnt_vm<0>();

  const int mrb = khi * 4;
#pragma unroll
  for (int mi = 0; mi < MT; ++mi)
#pragma unroll
    for (int ni = 0; ni < NTF; ++ni)
#pragma unroll
      for (int r = 0; r < 4; ++r) {
        int mm = m0 + wm * PM + mi * 16 + mrb + r;
        int nn = n0 + wn * PN + ni * 16 + rlo;
        float v = acc[mi][ni][r];
        if (OUT_BF16) ((unsigned short*)Cg)[(size_t)mm * N + nn] = f2bf(v);
        else          ((float*)Cg)[(size_t)mm * N + nn] = v;
      }
}

// ---------------------------------------------------------------- causal conv K=4 + SiLU
__global__ __launch_bounds__(256) void conv_silu_kernel(const unsigned short* __restrict__ C1,
                                                        const float* __restrict__ conv_w,
                                                        unsigned short* __restrict__ QKV) {
  int idx = blockIdx.x * 256 + threadIdx.x;       // (ROWS/8) * 2048
  int nb = idx >> 11;
  int c4 = (idx & 2047) << 2;
  int row0 = nb * 8;
  int s0 = row0 & 2047;
  float4 w0 = *(const float4*)(conv_w + (size_t)(c4 + 0) * 4);
  float4 w1 = *(const float4*)(conv_w + (size_t)(c4 + 1) * 4);
  float4 w2 = *(const float4*)(conv_w + (size_t)(c4 + 2) * 4);
  float4 w3 = *(const float4*)(conv_w + (size_t)(c4 + 3) * 4);
  const float* pw0 = (const float*)&w0;
  const float* pw1 = (const float*)&w1;
  const float* pw2 = (const float*)&w2;
  const float* pw3 = (const float*)&w3;
  ushort4 rw[11];
#pragma unroll
  for (int i = 0; i < 11; ++i) {
    if (s0 + i >= 3) rw[i] = *(const ushort4*)(C1 + (size_t)(row0 - 3 + i) * NWP + c4);
    else { rw[i].x = 0; rw[i].y = 0; rw[i].z = 0; rw[i].w = 0; }
  }
#pragma unroll
  for (int j = 0; j < 8; ++j) {
    float a0 = 0.f, a1 = 0.f, a2 = 0.f, a3 = 0.f;
#pragma unroll
    for (int jj = 0; jj < 4; ++jj) {
      ushort4 mv = rw[j + jj];
      a0 += bf2f(mv.x) * pw0[jj];
      a1 += bf2f(mv.y) * pw1[jj];
      a2 += bf2f(mv.z) * pw2[jj];
      a3 += bf2f(mv.w) * pw3[jj];
    }
    ushort4 o;
    o.x = f2bf(a0 / (1.f + __expf(-a0)));
    o.y = f2bf(a1 / (1.f + __expf(-a1)));
    o.z = f2bf(a2 / (1.f + __expf(-a2)));
    o.w = f2bf(a3 / (1.f + __expf(-a3)));
    *(ushort4*)(QKV + (size_t)(row0 + j) * CONVD + c4) = o;
  }
}

// ---------------------------------------------------------------- beta / g
__global__ __launch_bounds__(256) void gbeta_kernel(const unsigned short* __restrict__ C1,
                                                    const float* __restrict__ dt_bias,
                                                    const float* __restrict__ A_log,
                                                    float* __restrict__ G, float* __restrict__ BETA) {
  int idx = blockIdx.x * 256 + threadIdx.x;
  int row = idx >> 5, h = idx & 31;
  float bp = bf2f(C1[(size_t)row * NWP + 12288 + h]);
  float ap = bf2f(C1[(size_t)row * NWP + 12320 + h]);
  BETA[idx] = 1.f / (1.f + __expf(-bp));
  float x = ap + dt_bias[h];
  float sp = (x > 15.f) ? x : log1pf(__expf(x));
  G[idx] = -__expf(A_log[h]) * sp;
}

// ---------------------------------------------------------------- INTRA: per-chunk solve
// Wave-balanced {3,3,2,2} MFMA jobs for A-build AND attn (zero-tiles = store jobs).
#define INTRA_SMEM 70144
__global__ __launch_bounds__(256) void intra_kernel(const unsigned short* __restrict__ QKV,
                                                    const float* __restrict__ G,
                                                    const float* __restrict__ BETA,
                                                    unsigned short* __restrict__ WU,
                                                    unsigned short* __restrict__ ATTN) {
  extern __shared__ char smem[];
  unsigned short* ktb = (unsigned short*)smem;        // [64][136]
  float* Amat = (float*)(smem + 17408);               // [64][68]
  float* Xt   = (float*)(smem + 34816);               // [128][68]
  unsigned short* qb = (unsigned short*)Xt;           // [64][136] alias
  float* gc  = (float*)(smem + 69632);                // [64]
  float* bet = gc + 64;                               // [64]

  const int t = threadIdx.x;
  const int lane = t & 63, w = t >> 6;
  const int rlo = lane & 15, khi = lane >> 4;
  const int cix = blockIdx.x & 31;
  const int h = (blockIdx.x >> 5) & 31;
  const int b = blockIdx.x >> 10;
  const int hq = h >> 1;
  const int row0 = cix * 64;
  const size_t rowbase = (size_t)b * SEQ;

  if (t < 64) {
    float gv = G[(rowbase + row0 + t) * NUMV + h];
    bet[t] = BETA[(rowbase + row0 + t) * NUMV + h];
#pragma unroll
    for (int off = 1; off < 64; off <<= 1) {
      float u = __shfl_up(gv, off, 64);
      if (t >= off) gv += u;
    }
    gc[t] = gv;
  }
  __syncthreads();

  const int r = t >> 2, q4 = t & 3;
  const size_t grow = (rowbase + row0 + r) * (size_t)CONVD;

  {
    const unsigned short* kp = QKV + grow + 2048 + hq * 128 + q4 * 32;
    float kv[32]; float ssk = 0.f;
#pragma unroll
    for (int j = 0; j < 32; j += 4) {
      ushort4 km = *(const ushort4*)(kp + j);
      kv[j] = bf2f(km.x); kv[j + 1] = bf2f(km.y); kv[j + 2] = bf2f(km.z); kv[j + 3] = bf2f(km.w);
      ssk += kv[j]*kv[j] + kv[j+1]*kv[j+1] + kv[j+2]*kv[j+2] + kv[j+3]*kv[j+3];
    }
    ssk += __shfl_xor(ssk, 1, 64);
    ssk += __shfl_xor(ssk, 2, 64);
    const float rk = rsqrtf(ssk + 1e-6f);
    const float ekr = __expf(gc[r]) * bet[r];
#pragma unroll
    for (int j = 0; j < 32; ++j) {
      float kn = kv[j] * rk;
      ktb[r * 136 + q4 * 32 + j] = f2bf(kn);
      Xt[(q4 * 32 + j) * 68 + r] = kn * ekr;
    }
  }
  __syncthreads();

  float xr[64];

  // A-build (balanced {3,3,2,2}) ; t<128 captures kcd column to regs
  {
    static const signed char SJ[10][2] = {{0,0},{1,0},{1,1},{2,0},{2,1},{2,2},{3,0},{3,1},{3,2},{3,3}};
    static const signed char SB[5] = {0, 3, 6, 8, 10};
    for (int sj = SB[w]; sj < SB[w + 1]; ++sj) {
      const int mt = SJ[sj][0], nt = SJ[sj][1];
      f32x4v acc = (f32x4v){0.f, 0.f, 0.f, 0.f};
#pragma unroll
      for (int ks = 0; ks < 4; ++ks) {
        bf16x8 af = *(const bf16x8*)&ktb[(mt * 16 + rlo) * 136 + ks * 32 + khi * 8];
        bf16x8 bf_ = *(const bf16x8*)&ktb[(nt * 16 + rlo) * 136 + ks * 32 + khi * 8];
        acc = __builtin_amdgcn_mfma_f32_16x16x32_bf16(af, bf_, acc, 0, 0, 0);
      }
      const int j = nt * 16 + rlo;
#pragma unroll
      for (int r2 = 0; r2 < 4; ++r2) {
        const int i = mt * 16 + khi * 4 + r2;
        if (j < i) Amat[i * 68 + j] = -bet[i] * __expf(gc[i] - gc[j]) * acc[r2];
      }
    }
    if (t < 128) {
      const float* Xc = Xt + t * 68;
#pragma unroll
      for (int j = 0; j < 64; j += 4) {
        f32x4v xv = *(const f32x4v*)(Xc + j);
        xr[j] = xv[0]; xr[j + 1] = xv[1]; xr[j + 2] = xv[2]; xr[j + 3] = xv[3];
      }
    }
  }
  __syncthreads();

  {
    const unsigned short* vp = QKV + grow + 4096 + h * 128 + q4 * 32;
    const float brow = bet[r];
#pragma unroll
    for (int j = 0; j < 32; j += 4) {
      ushort4 vm = *(const ushort4*)(vp + j);
      Xt[(q4 * 32 + j + 0) * 68 + r] = bf2f(vm.x) * brow;
      Xt[(q4 * 32 + j + 1) * 68 + r] = bf2f(vm.y) * brow;
      Xt[(q4 * 32 + j + 2) * 68 + r] = bf2f(vm.z) * brow;
      Xt[(q4 * 32 + j + 3) * 68 + r] = bf2f(vm.w) * brow;
    }
  }
  __syncthreads();
  if (t >= 128) {
    const float* Xc = Xt + (t - 128) * 68;
#pragma unroll
    for (int j = 0; j < 64; j += 4) {
      f32x4v xv = *(const f32x4v*)(Xc + j);
      xr[j] = xv[0]; xr[j + 1] = xv[1]; xr[j + 2] = xv[2]; xr[j + 3] = xv[3];
    }
  }
  __syncthreads();

  // SOLVE (I-A)x = rhs in registers, all 256 threads, no barriers.
#pragma unroll
  for (int ib = 0; ib < 8; ++ib) {
    const int i0 = ib * 8;
    float p[8] = {0, 0, 0, 0, 0, 0, 0, 0};
#pragma unroll
    for (int j = 0; j < i0; j += 4) {
#pragma unroll
      for (int r2 = 0; r2 < 8; ++r2) {
        f32x4v ar = *(const f32x4v*)&Amat[(i0 + r2) * 68 + j];
        p[r2] += ar[0] * xr[j] + ar[1] * xr[j + 1] + ar[2] * xr[j + 2] + ar[3] * xr[j + 3];
      }
    }
#pragma unroll
    for (int r2 = 0; r2 < 8; ++r2) {
      float v = xr[i0 + r2] + p[r2];
#pragma unroll
      for (int r3 = 0; r3 < r2; ++r3) v += Amat[(i0 + r2) * 68 + i0 + r3] * xr[i0 + r3];
      xr[i0 + r2] = v;
    }
  }

  if (t < 128) {
    float* Xc = Xt + t * 68;
#pragma unroll
    for (int j = 0; j < 64; j += 4) {
      f32x4v xv = {xr[j], xr[j + 1], xr[j + 2], xr[j + 3]};
      *(f32x4v*)(Xc + j) = xv;
    }
  }
  __syncthreads();
  {
    unsigned short* wdst = WU + (rowbase + row0 + r) * (size_t)NWP + h * 128 + q4 * 32;
#pragma unroll
    for (int j = 0; j < 32; ++j) wdst[j] = f2bf(Xt[(q4 * 32 + j) * 68 + r]);
  }
  __syncthreads();
  if (t >= 128) {
    float* Xc = Xt + (t - 128) * 68;
#pragma unroll
    for (int j = 0; j < 64; j += 4) {
      f32x4v xv = {xr[j], xr[j + 1], xr[j + 2], xr[j + 3]};
      *(f32x4v*)(Xc + j) = xv;
    }
  }
  __syncthreads();
  {
    unsigned short* udst = WU + (rowbase + row0 + r) * (size_t)NWP + 4096 + h * 128 + q4 * 32;
#pragma unroll
    for (int j = 0; j < 32; ++j) udst[j] = f2bf(Xt[(q4 * 32 + j) * 68 + r]);
  }
  __syncthreads();

  {
    const unsigned short* qp = QKV + grow + hq * 128 + q4 * 32;
    float qv[32]; float ssq = 0.f;
#pragma unroll
    for (int j = 0; j < 32; j += 4) {
      ushort4 qm = *(const ushort4*)(qp + j);
      qv[j] = bf2f(qm.x); qv[j + 1] = bf2f(qm.y); qv[j + 2] = bf2f(qm.z); qv[j + 3] = bf2f(qm.w);
      ssq += qv[j]*qv[j] + qv[j+1]*qv[j+1] + qv[j+2]*qv[j+2] + qv[j+3]*qv[j+3];
    }
    ssq += __shfl_xor(ssq, 1, 64);
    ssq += __shfl_xor(ssq, 2, 64);
    const float rq = rsqrtf(ssq + 1e-6f) * 0.08838834764831845f;
#pragma unroll
    for (int j = 0; j < 32; ++j) qb[r * 136 + q4 * 32 + j] = f2bf(qv[j] * rq);
  }
  __syncthreads();

  // attn: balanced compute jobs {3,3,2,2} + store-only zero tiles on waves 2,3
  {
    const size_t abase = (((size_t)b * 32 + h) * 32 + cix) * 4096;
    static const signed char CJ[10][2] = {{0,0},{1,0},{1,1},{2,0},{2,1},{2,2},{3,0},{3,1},{3,2},{3,3}};
    static const signed char CB[5] = {0, 3, 6, 8, 10};
    static const signed char ZJ[6][2] = {{0,1},{0,2},{0,3},{1,2},{1,3},{2,3}};
    static const signed char ZB[5] = {0, 0, 0, 3, 6};
#pragma unroll 1
    for (int cj = CB[w]; cj < CB[w + 1]; ++cj) {
      const int bi = CJ[cj][0], nt = CJ[cj][1];
      const int j = nt * 16 + rlo;
      f32x4v acc = (f32x4v){0.f, 0.f, 0.f, 0.f};
#pragma unroll
      for (int ks = 0; ks < 4; ++ks) {
        bf16x8 af = *(const bf16x8*)&qb[(bi * 16 + rlo) * 136 + ks * 32 + khi * 8];
        bf16x8 bf_ = *(const bf16x8*)&ktb[(nt * 16 + rlo) * 136 + ks * 32 + khi * 8];
        acc = __builtin_amdgcn_mfma_f32_16x16x32_bf16(af, bf_, acc, 0, 0, 0);
      }
#pragma unroll
      for (int r2 = 0; r2 < 4; ++r2) {
        const int i = bi * 16 + khi * 4 + r2;
        float v = (j <= i) ? __expf(gc[i] - gc[j]) * acc[r2] : 0.f;
        ATTN[abase + i * 64 + j] = f2bf(v);
      }
    }
#pragma unroll 1
    for (int zj = ZB[w]; zj < ZB[w + 1]; ++zj) {
      const int bi = ZJ[zj][0], nt = ZJ[zj][1];
#pragma unroll
      for (int r2 = 0; r2 < 4; ++r2)
        ATTN[abase + (bi * 16 + khi * 4 + r2) * 64 + nt * 16 + rlo] = 0;
    }
  }
}

// ---------------------------------------------------------------- SEQ: state recurrence
// Wave-local g-scan (identical across waves; gc[i]/edec/egl via __shfl+exp at use):
// P0 phase + 1 barrier removed -> 3 barriers/chunk.
#define SEQ_SMEM 70400
__global__ __launch_bounds__(256) void seq_kernel(const unsigned short* __restrict__ QKV,
                                                  const float* __restrict__ G,
                                                  const unsigned short* __restrict__ WU,
                                                  const unsigned short* __restrict__ ATTN,
                                                  unsigned short* __restrict__ CORE) {
  extern __shared__ char smem[];
  unsigned short* ktT    = (unsigned short*)smem;            // [128][88]
  unsigned short* wb     = (unsigned short*)(smem + 22528);  // [64][136]
  unsigned short* attnb  = (unsigned short*)(smem + 39936);  // [64][88]
  float* stateT          = (float*)(smem + 51200);           // [16][136]
  unsigned short* stateTb = (unsigned short*)(smem + 59904); // [16][136]
  unsigned short* vnTb   = (unsigned short*)(smem + 64256);  // [16][88]
  unsigned short* vdTb   = (unsigned short*)(smem + 67072);  // [16][88]

  const int t = threadIdx.x;
  const int lane = t & 63, w = t >> 6;
  const int rlo = lane & 15, khi = lane >> 4;
  const int vq = blockIdx.x & 7;
  const int h = (blockIdx.x >> 3) & 31;
  const int b = blockIdx.x >> 8;
  const int hq = h >> 1;
  const size_t rowbase = (size_t)b * SEQ;
  const size_t ahead = ((size_t)b * 32 + h) * 32;

  for (int i = t; i < 16 * 136; i += 256) { stateT[i] = 0.f; stateTb[i] = 0; }
  __syncthreads();

  bf16x8 qf[4];

#pragma unroll 1
  for (int ncb = 0; ncb < 32; ++ncb) {
    const int row0 = ncb * 64;

    // wave-local g scan (lane = row; identical result in every wave)
    float gv = G[(rowbase + row0 + lane) * NUMV + h];
#pragma unroll
    for (int off = 1; off < 64; off <<= 1) {
      float uph = __shfl_up(gv, off, 64);
      if (lane >= off) gv += uph;
    }
    const float gtot = __shfl(gv, 63, 64);

    {
      const int r = t >> 2, q4 = t & 3;
      const size_t grow = (rowbase + row0 + r) * (size_t)CONVD;
      const unsigned short* kp = QKV + grow + 2048 + hq * 128 + q4 * 32;
      float kv[32]; float ssk = 0.f;
#pragma unroll
      for (int j = 0; j < 32; j += 4) {
        ushort4 km = *(const ushort4*)(kp + j);
        kv[j] = bf2f(km.x); kv[j + 1] = bf2f(km.y); kv[j + 2] = bf2f(km.z); kv[j + 3] = bf2f(km.w);
        ssk += kv[j]*kv[j] + kv[j+1]*kv[j+1] + kv[j+2]*kv[j+2] + kv[j+3]*kv[j+3];
      }
      ssk += __shfl_xor(ssk, 1, 64);
      ssk += __shfl_xor(ssk, 2, 64);
      const float rk = rsqrtf(ssk + 1e-6f);
#pragma unroll
      for (int j = 0; j < 32; ++j) ktT[(q4 * 32 + j) * 88 + r] = f2bf(kv[j] * rk);
      const unsigned short* wsrc = WU + (rowbase + row0 + r) * (size_t)NWP + h * 128 + q4 * 32;
#pragma unroll
      for (int u2 = 0; u2 < 4; ++u2)
        *(uint4*)&wb[r * 136 + q4 * 32 + u2 * 8] = *(const uint4*)(wsrc + u2 * 8);
      const unsigned short* asrc = ATTN + (ahead + ncb) * 4096 + r * 64 + q4 * 16;
      *(uint4*)&attnb[r * 88 + q4 * 16] = *(const uint4*)(asrc);
      *(uint4*)&attnb[r * 88 + q4 * 16 + 8] = *(const uint4*)(asrc + 8);
      const unsigned short* qsrc = QKV + (rowbase + row0 + w * 16 + rlo) * (size_t)CONVD + hq * 128 + khi * 8;
      float qv[32]; float ssq = 0.f;
#pragma unroll
      for (int ks = 0; ks < 4; ++ks) {
        ushort4 qa = *(const ushort4*)(qsrc + ks * 32);
        ushort4 qb2 = *(const ushort4*)(qsrc + ks * 32 + 4);
        qv[ks*8+0] = bf2f(qa.x); qv[ks*8+1] = bf2f(qa.y); qv[ks*8+2] = bf2f(qa.z); qv[ks*8+3] = bf2f(qa.w);
        qv[ks*8+4] = bf2f(qb2.x); qv[ks*8+5] = bf2f(qb2.y); qv[ks*8+6] = bf2f(qb2.z); qv[ks*8+7] = bf2f(qb2.w);
#pragma unroll
        for (int e = 0; e < 8; ++e) ssq += qv[ks*8+e] * qv[ks*8+e];
      }
      ssq += __shfl_xor(ssq, 16, 64);
      ssq += __shfl_xor(ssq, 32, 64);
      const float rq = rsqrtf(ssq + 1e-6f) * 0.08838834764831845f;
#pragma unroll
      for (int ks = 0; ks < 4; ++ks) {
        bf16x8 tv;
#pragma unroll
        for (int e = 0; e < 8; ++e) tv[e] = (short)f2bf(qv[ks*8+e] * rq);
        qf[ks] = tv;
      }
    }
    __syncthreads();

    f32x4v oacc;
    {
      f32x4v pacc = (f32x4v){0.f, 0.f, 0.f, 0.f};
      oacc = (f32x4v){0.f, 0.f, 0.f, 0.f};
#pragma unroll
      for (int ks = 0; ks < 4; ++ks) {
        bf16x8 aw = *(const bf16x8*)&wb[(w * 16 + rlo) * 136 + ks * 32 + khi * 8];
        bf16x8 bs = *(const bf16x8*)&stateTb[rlo * 136 + ks * 32 + khi * 8];
        pacc = __builtin_amdgcn_mfma_f32_16x16x32_bf16(aw, bs, pacc, 0, 0, 0);
        oacc = __builtin_amdgcn_mfma_f32_16x16x32_bf16(qf[ks], bs, oacc, 0, 0, 0);
      }
#pragma unroll
      for (int r2 = 0; r2 < 4; ++r2) {
        const int i = w * 16 + khi * 4 + r2;
        const float gci = __shfl(gv, i, 64);
        float uv = bf2f(WU[(rowbase + row0 + i) * (size_t)NWP + 4096 + h * 128 + vq * 16 + rlo]);
        float vn = uv - pacc[r2];
        vnTb[rlo * 88 + i] = f2bf(vn);
        vdTb[rlo * 88 + i] = f2bf(vn * __expf(gtot - gci));
        oacc[r2] *= __expf(gci);
      }
    }
    __syncthreads();

    {
#pragma unroll
      for (int ks = 0; ks < 2; ++ks) {
        bf16x8 aa = *(const bf16x8*)&attnb[(w * 16 + rlo) * 88 + ks * 32 + khi * 8];
        bf16x8 bv = *(const bf16x8*)&vnTb[rlo * 88 + ks * 32 + khi * 8];
        oacc = __builtin_amdgcn_mfma_f32_16x16x32_bf16(aa, bv, oacc, 0, 0, 0);
      }
      const int col = h * 128 + vq * 16 + rlo;
#pragma unroll
      for (int r2 = 0; r2 < 4; ++r2) {
        const int i = w * 16 + khi * 4 + r2;
        CORE[(rowbase + row0 + i) * (size_t)4096 + col] = f2bf(oacc[r2]);
      }
      const float egl = __expf(gtot);
#pragma unroll
      for (int n2 = 0; n2 < 2; ++n2) {
        const int dt = w * 2 + n2;
        f32x4v sacc = (f32x4v){0.f, 0.f, 0.f, 0.f};
#pragma unroll
        for (int ks = 0; ks < 2; ++ks) {
          bf16x8 ak = *(const bf16x8*)&ktT[(dt * 16 + rlo) * 88 + ks * 32 + khi * 8];
          bf16x8 bv2 = *(const bf16x8*)&vdTb[rlo * 88 + ks * 32 + khi * 8];
          sacc = __builtin_amdgcn_mfma_f32_16x16x32_bf16(ak, bv2, sacc, 0, 0, 0);
        }
#pragma unroll
        for (int r2 = 0; r2 < 4; ++r2) {
          const int d = dt * 16 + khi * 4 + r2;
          float ns = stateT[rlo * 136 + d] * egl + sacc[r2];
          stateT[rlo * 136 + d] = ns;
          stateTb[rlo * 136 + d] = f2bf(ns);
        }
      }
    }
    __syncthreads();
  }
}

// ---------------------------------------------------------------- gate * silu(z) + RMS-norm
__global__ __launch_bounds__(256) void gatenorm_kernel(const unsigned short* __restrict__ CORE,
                                                       const unsigned short* __restrict__ C1,
                                                       const float* __restrict__ norm_w,
                                                       unsigned short* __restrict__ NRM) {
  const int wid = blockIdx.x * 4 + (threadIdx.x >> 6);
  const int lane = threadIdx.x & 63;
  const int row = wid >> 5, h = wid & 31;
  const int c = lane * 2;
  const size_t cidx = (size_t)row * 4096 + h * 128 + c;
  const size_t zidx = (size_t)row * NWP + 8192 + h * 128 + c;
  float g0 = bf2f(CORE[cidx]), g1 = bf2f(CORE[cidx + 1]);
  float z0 = bf2f(C1[zidx]), z1 = bf2f(C1[zidx + 1]);
  g0 *= z0 / (1.f + __expf(-z0));
  g1 *= z1 / (1.f + __expf(-z1));
  float ss = g0 * g0 + g1 * g1;
#pragma unroll
  for (int m = 1; m < 64; m <<= 1) ss += __shfl_xor(ss, m, 64);
  const float rr = rsqrtf(ss * (1.f / 128.f) + 1e-6f);
  unsigned int o = ((unsigned int)f2bf(g1 * rr * norm_w[c + 1]) << 16) | (unsigned int)f2bf(g0 * rr * norm_w[c]);
  *(unsigned int*)(NRM + cidx) = o;
}

// ---------------------------------------------------------------------------
extern "C" void kernel_launch(void* const* d_in, const int* in_sizes, int n_in,
                              void* d_out, int out_size, void* d_ws, size_t ws_size,
                              hipStream_t stream) {
  const float* hs      = (const float*)d_in[0];
  const float* W_qkv   = (const float*)d_in[1];
  const float* W_z     = (const float*)d_in[2];
  const float* W_b     = (const float*)d_in[3];
  const float* W_a     = (const float*)d_in[4];
  const float* conv_w  = (const float*)d_in[5];
  const float* dt_bias = (const float*)d_in[6];
  const float* A_log   = (const float*)d_in[7];
  const float* norm_w  = (const float*)d_in[8];
  const float* W_out   = (const float*)d_in[9];
  float* out = (float*)d_out;
  char* ws = (char*)d_ws;

  const size_t OFF_HSB = 0;                                     // hs bf16; later ATTN
  const size_t OFF_WT  = OFF_HSB + (size_t)ROWS * HIDN * 2;     // WT; later CORE
  const size_t OFF_WOT = OFF_WT + (size_t)NWP * HIDN * 2;
  const size_t OFF_C1  = OFF_WOT + (size_t)HIDN * 4096 * 2;     // C1; cols [0,8192) -> w,u after conv
  const size_t OFF_QKV = OFF_C1 + (size_t)ROWS * NWP * 2;       // QKV; later NRM
  const size_t OFF_G   = OFF_QKV + (size_t)ROWS * CONVD * 2;
  const size_t OFF_B   = OFF_G + (size_t)ROWS * NUMV * 4;

  unsigned short* hsb = (unsigned short*)(ws + OFF_HSB);
  unsigned short* WT  = (unsigned short*)(ws + OFF_WT);
  unsigned short* WoT = (unsigned short*)(ws + OFF_WOT);
  unsigned short* C1  = (unsigned short*)(ws + OFF_C1);
  unsigned short* QKV = (unsigned short*)(ws + OFF_QKV);
  float* Gb = (float*)(ws + OFF_G);
  float* Bb = (float*)(ws + OFF_B);
  unsigned short* ATTNb = (unsigned short*)(ws + OFF_HSB);
  unsigned short* COREb = (unsigned short*)(ws + OFF_WT);
  unsigned short* NRMb  = (unsigned short*)(ws + OFF_QKV);

  cast_kernel<<<ROWS * HIDN / 4 / 256, 256, 0, stream>>>(hs, hsb, ROWS * HIDN / 4);
  transpose_kernel<<<dim3(8192 / 64, 2048 / 64), 256, 0, stream>>>(W_qkv, WT, 2048, 8192, HIDN, 0);
  transpose_kernel<<<dim3(4096 / 64, 2048 / 64), 256, 0, stream>>>(W_z, WT, 2048, 4096, HIDN, 8192);
  transpose_kernel<<<dim3(1, 2048 / 64), 256, 0, stream>>>(W_b, WT, 2048, 32, HIDN, 12288);
  transpose_kernel<<<dim3(1, 2048 / 64), 256, 0, stream>>>(W_a, WT, 2048, 32, HIDN, 12320);
  hipMemsetAsync(ws + OFF_WT + (size_t)12352 * HIDN * 2, 0, (size_t)192 * HIDN * 2, stream);
  transpose_kernel<<<dim3(2048 / 64, 4096 / 64), 256, 0, stream>>>(W_out, WoT, 4096, 2048, 4096, 0);

  void (*g1p)(const unsigned short*, const unsigned short*, void*, int, int, int) = gemm_r5_kernel<256, 256, 1>;
  void (*g0p)(const unsigned short*, const unsigned short*, void*, int, int, int) = gemm_r5_kernel<128, 256, 0>;
  hipFuncSetAttribute((const void*)g1p, hipFuncAttributeMaxDynamicSharedMemorySize, 5 * (256 + 256) * 64);
  hipFuncSetAttribute((const void*)g0p, hipFuncAttributeMaxDynamicSharedMemorySize, 5 * (128 + 256) * 64);

  gemm_r5_kernel<256, 256, 1><<<dim3(NWP / 256, ROWS / 256), 512, 5 * (256 + 256) * 64, stream>>>(
      hsb, WT, C1, ROWS, NWP, HIDN);
  conv_silu_kernel<<<(ROWS / 8) * 2048 / 256, 256, 0, stream>>>(C1, conv_w, QKV);
  gbeta_kernel<<<ROWS * NUMV / 256, 256, 0, stream>>>(C1, dt_bias, A_log, Gb, Bb);

  hipFuncSetAttribute((const void*)intra_kernel, hipFuncAttributeMaxDynamicSharedMemorySize,
                      INTRA_SMEM);
  intra_kernel<<<2048, 256, INTRA_SMEM, stream>>>(QKV, Gb, Bb, C1, ATTNb);

  hipFuncSetAttribute((const void*)seq_kernel, hipFuncAttributeMaxDynamicSharedMemorySize,
                      SEQ_SMEM);
  seq_kernel<<<512, 256, SEQ_SMEM, stream>>>(QKV, Gb, C1, ATTNb, COREb);

  gatenorm_kernel<<<ROWS * NUMV / 4, 256, 0, stream>>>(COREb, C1, norm_w, NRMb);
  gemm_r5_kernel<128, 256, 0><<<dim3(2048 / 256, ROWS / 128), 512, 5 * (128 + 256) * 64, stream>>>(
      NRMb, WoT, out, ROWS, 2048, 4096);
}